// Round 5
// baseline (1544.885 us; speedup 1.0000x reference)
//
#include <hip/hip_runtime.h>

// Problem constants (from reference)
constexpr int DIM      = 64;
constexpr int N_USERS  = 100000;
constexpr int N_ITEMS  = 50000;
constexpr int N_CATS   = 1000;
constexpr int NE_UI    = 2000000;
constexpr int NE_UU    = 1000000;
constexpr int NE_IC    = 150000;
constexpr int N_LAYERS = 3;

constexpr int CHUNK = 8192;  // edges per bucket_scatter chunk

// ---------------- CSR build ----------------

// Fused: per-row histogram (global atomics, 100K bins, L2-served) +
// per-bucket histogram (LDS-staged 256 bins, flushed once per block).
__global__ __launch_bounds__(256) void hist_kernel(const int* __restrict__ rows,
                                                   int* __restrict__ counts,
                                                   int* __restrict__ bcnt,
                                                   int shift, int ne) {
    __shared__ int lb[256];
    lb[threadIdx.x] = 0;
    __syncthreads();
    int i = blockIdx.x * blockDim.x + threadIdx.x;
    int st = gridDim.x * blockDim.x;
    for (; i < ne; i += st) {
        int r = rows[i];
        atomicAdd(&counts[r], 1);
        atomicAdd(&lb[r >> shift], 1);
    }
    __syncthreads();
    if (lb[threadIdx.x]) atomicAdd(&bcnt[threadIdx.x], lb[threadIdx.x]);
}

constexpr int SCAN_BLK   = 256;
constexpr int SCAN_ELEMS = 8;
constexpr int SCAN_TILE  = SCAN_BLK * SCAN_ELEMS;  // 2048

__global__ void scan_pass1(const int* __restrict__ in, int* __restrict__ out,
                           int* __restrict__ tile_sums, int n) {
    __shared__ int lds[SCAN_BLK];
    int base = blockIdx.x * SCAN_TILE + threadIdx.x * SCAN_ELEMS;
    int v[SCAN_ELEMS];
    int s = 0;
#pragma unroll
    for (int k = 0; k < SCAN_ELEMS; ++k) {
        int idx = base + k;
        v[k] = (idx < n) ? in[idx] : 0;
        s += v[k];
    }
    lds[threadIdx.x] = s;
    __syncthreads();
    for (int off = 1; off < SCAN_BLK; off <<= 1) {
        int t = (threadIdx.x >= (unsigned)off) ? lds[threadIdx.x - off] : 0;
        __syncthreads();
        lds[threadIdx.x] += t;
        __syncthreads();
    }
    if (threadIdx.x == SCAN_BLK - 1) tile_sums[blockIdx.x] = lds[SCAN_BLK - 1];
    int run = (threadIdx.x == 0) ? 0 : lds[threadIdx.x - 1];
#pragma unroll
    for (int k = 0; k < SCAN_ELEMS; ++k) {
        int idx = base + k;
        if (idx < n) out[idx] = run;
        run += v[k];
    }
}

__global__ void scan_pass2(int* __restrict__ tile_sums, int m, int* __restrict__ total_out) {
    __shared__ int lds[256];
    int tid = threadIdx.x;
    int v = (tid < m) ? tile_sums[tid] : 0;
    lds[tid] = v;
    __syncthreads();
    for (int off = 1; off < 256; off <<= 1) {
        int t = (tid >= off) ? lds[tid - off] : 0;
        __syncthreads();
        lds[tid] += t;
        __syncthreads();
    }
    if (tid < m) tile_sums[tid] = lds[tid] - v;  // exclusive
    if (tid == 255 && total_out) *total_out = lds[255];
}

__global__ void scan_pass3(int* __restrict__ out, const int* __restrict__ tile_sums, int n) {
    int add = tile_sums[blockIdx.x];
#pragma unroll
    for (int k = 0; k < SCAN_ELEMS; ++k) {
        int idx = blockIdx.x * SCAN_TILE + k * SCAN_BLK + threadIdx.x;
        if (idx < n) out[idx] += add;
    }
}

// exclusive scan of 256 bucket counts -> boffs[0..256], cursor = boffs
__global__ void bucket_scan(const int* __restrict__ bcnt, int* __restrict__ boffs,
                            int* __restrict__ cursor) {
    __shared__ int lds[256];
    int tid = threadIdx.x;
    int v = bcnt[tid];
    lds[tid] = v;
    __syncthreads();
    for (int off = 1; off < 256; off <<= 1) {
        int t = (tid >= off) ? lds[tid - off] : 0;
        __syncthreads();
        lds[tid] += t;
        __syncthreads();
    }
    int excl = lds[tid] - v;
    boffs[tid] = excl;
    cursor[tid] = excl;
    if (tid == 255) boffs[256] = lds[255];
}

// Level 1: LDS-staged multisplit into <=256 coarse buckets.
// Packs (local_row << 17) | col into .x (shift <= 9, col < 2^17), val bits in .y.
__global__ __launch_bounds__(256) void bucket_scatter(const int* __restrict__ rows,
                                                      const int* __restrict__ cols,
                                                      const float* __restrict__ vals,
                                                      int ne, int shift,
                                                      int* __restrict__ cursor,
                                                      int2* __restrict__ out) {
    __shared__ int2 stage[CHUNK];
    __shared__ unsigned char sb[CHUNK];
    __shared__ int hist[256], lbase[256], gbase[256], cnt[256];
    int tid = threadIdx.x;
    int nchunks = (ne + CHUNK - 1) / CHUNK;
    for (int ch = blockIdx.x; ch < nchunks; ch += gridDim.x) {
        int base = ch * CHUNK;
        int nedge = min(CHUNK, ne - base);
        hist[tid] = 0;
        __syncthreads();
        for (int k = tid; k < nedge; k += 256)
            atomicAdd(&hist[rows[base + k] >> shift], 1);
        __syncthreads();
        // inclusive scan of hist
        lbase[tid] = hist[tid];
        __syncthreads();
        for (int off = 1; off < 256; off <<= 1) {
            int t = (tid >= off) ? lbase[tid - off] : 0;
            __syncthreads();
            lbase[tid] += t;
            __syncthreads();
        }
        int excl = lbase[tid] - hist[tid];
        cnt[tid] = excl;
        gbase[tid] = hist[tid] ? atomicAdd(&cursor[tid], hist[tid]) : 0;
        lbase[tid] = excl;  // own-slot rewrite, safe (each thread touches only [tid])
        __syncthreads();
        for (int k = tid; k < nedge; k += 256) {
            int r = rows[base + k];
            int b = r >> shift;
            int slot = atomicAdd(&cnt[b], 1);
            int lr = r - (b << shift);
            stage[slot] = make_int2((lr << 17) | cols[base + k], __float_as_int(vals[base + k]));
            sb[slot] = (unsigned char)b;
        }
        __syncthreads();
        // stream out in bucket order: coalesced runs within each bucket segment
        for (int j = tid; j < nedge; j += 256) {
            int b = sb[j];
            out[gbase[b] + (j - lbase[b])] = stage[j];
        }
        __syncthreads();
    }
}

// Level 2: one block per bucket; final scatter window (~64-80KB) stays L2-local.
__global__ __launch_bounds__(256) void final_scatter(const int2* __restrict__ bucketed,
                                                     const int* __restrict__ boffs, int shift,
                                                     int* __restrict__ offs,
                                                     int2* __restrict__ edges) {
    int b = blockIdx.x;
    int s = boffs[b], e = boffs[b + 1];
    int base_row = b << shift;
    for (int j = s + threadIdx.x; j < e; j += blockDim.x) {
        int2 w = bucketed[j];
        int r = base_row + ((unsigned)w.x >> 17);
        int pos = atomicAdd(&offs[r], 1);
        edges[pos] = make_int2(w.x & 0x1FFFF, w.y);
    }
}

// ---------------- pull-style fused layer kernels ----------------
// Wave layout: 4 edge-groups (grp = lane>>4) x 16 lanes (sub = lane&15) x float4.

__device__ __forceinline__ void gather4(const int* __restrict__ ptr,
                                        const int2* __restrict__ edges,
                                        const float* __restrict__ H,
                                        int r, int grp, int sub, float4& acc) {
    int s = ptr[r], e = ptr[r + 1];
    for (int j = s + grp; j < e; j += 4) {
        int2 ed = edges[j];
        float4 hv = *reinterpret_cast<const float4*>(H + (size_t)ed.x * DIM + sub * 4);
        float w = __int_as_float(ed.y);
        acc.x = fmaf(w, hv.x, acc.x);
        acc.y = fmaf(w, hv.y, acc.y);
        acc.z = fmaf(w, hv.z, acc.z);
        acc.w = fmaf(w, hv.w, acc.w);
    }
}

__device__ __forceinline__ void xgroup_reduce(float4& a) {
#pragma unroll
    for (int m = 16; m <= 32; m <<= 1) {
        a.x += __shfl_xor(a.x, m);
        a.y += __shfl_xor(a.y, m);
        a.z += __shfl_xor(a.z, m);
        a.w += __shfl_xor(a.w, m);
    }
}

__global__ void layer_two(const int* __restrict__ pA, const int2* __restrict__ eA, const float* __restrict__ HA,
                          const int* __restrict__ pB, const int2* __restrict__ eB, const float* __restrict__ HB,
                          float* __restrict__ h_out, float* __restrict__ sum,
                          int nrows, float scale, int last) {
    int wid  = (blockIdx.x * blockDim.x + threadIdx.x) >> 6;
    int lane = threadIdx.x & 63;
    if (wid >= nrows) return;
    int grp = lane >> 4, sub = lane & 15;
    float4 acc = make_float4(0.f, 0.f, 0.f, 0.f);
    gather4(pA, eA, HA, wid, grp, sub, acc);
    gather4(pB, eB, HB, wid, grp, sub, acc);
    xgroup_reduce(acc);  // all lanes hold final acc for dims [sub*4, sub*4+4)
    size_t o = (size_t)wid * DIM + sub * 4;
    if (last) {
        if (grp == 0) {
            float4 sv = *reinterpret_cast<const float4*>(sum + o);
            sv.x = (sv.x + acc.x) * scale;
            sv.y = (sv.y + acc.y) * scale;
            sv.z = (sv.z + acc.z) * scale;
            sv.w = (sv.w + acc.w) * scale;
            *reinterpret_cast<float4*>(sum + o) = sv;
        }
    } else {
        if (grp == 0) {
            *reinterpret_cast<float4*>(h_out + o) = acc;
        } else if (grp == 1) {
            float4 sv = *reinterpret_cast<const float4*>(sum + o);
            sv.x += acc.x; sv.y += acc.y; sv.z += acc.z; sv.w += acc.w;
            *reinterpret_cast<float4*>(sum + o) = sv;
        }
    }
}

__global__ void layer_one(const int* __restrict__ p, const int2* __restrict__ e,
                          const float* __restrict__ H, float* __restrict__ out, int nrows) {
    int wid  = (blockIdx.x * blockDim.x + threadIdx.x) >> 6;
    int lane = threadIdx.x & 63;
    if (wid >= nrows) return;
    int grp = lane >> 4, sub = lane & 15;
    float4 acc = make_float4(0.f, 0.f, 0.f, 0.f);
    gather4(p, e, H, wid, grp, sub, acc);
    xgroup_reduce(acc);
    if (grp == 0)
        *reinterpret_cast<float4*>(out + (size_t)wid * DIM + sub * 4) = acc;
}

// ---------------- fallback (push-atomic path) ----------------

__global__ void spmm_edges(const int* __restrict__ rows, const int* __restrict__ cols,
                           const float* __restrict__ vals, const float* __restrict__ H,
                           float* __restrict__ out, int ne) {
    int tid  = blockIdx.x * blockDim.x + threadIdx.x;
    int e    = tid >> 6;
    int lane = threadIdx.x & 63;
    if (e >= ne) return;
    float x = vals[e] * H[(size_t)cols[e] * DIM + lane];
    unsafeAtomicAdd(&out[(size_t)rows[e] * DIM + lane], x);
}

__global__ void accum_kernel(float* __restrict__ sum, const float* __restrict__ h, int n) {
    int i = blockIdx.x * blockDim.x + threadIdx.x;
    int st = gridDim.x * blockDim.x;
    for (; i < n; i += st) sum[i] += h[i];
}

__global__ void scale_kernel(float* __restrict__ p, int n, float s) {
    int i = blockIdx.x * blockDim.x + threadIdx.x;
    int st = gridDim.x * blockDim.x;
    for (; i < n; i += st) p[i] *= s;
}

// ---------------- host ----------------

static int bshift(int n_out) {   // smallest shift with (n_out >> shift) < 256
    int s = 0;
    while ((n_out >> s) >= 256) ++s;
    return s;
}

static void build_csr(const int* rows, const int* cols, const float* vals, int ne, int n_out,
                      int* ptr, int2* edges, int* offs, int* tile_sums,
                      int* bcnt, int* boffs, int* cursor, int2* bucketed,
                      hipStream_t stream) {
    int shift = bshift(n_out);
    hipMemsetAsync(ptr, 0, (size_t)(n_out + 1) * sizeof(int), stream);
    hipMemsetAsync(bcnt, 0, 256 * sizeof(int), stream);
    int g = (ne + 255) / 256;
    if (g > 2048) g = 2048;
    hist_kernel<<<g, 256, 0, stream>>>(rows, ptr, bcnt, shift, ne);
    int tiles = (n_out + SCAN_TILE - 1) / SCAN_TILE;
    scan_pass1<<<tiles, SCAN_BLK, 0, stream>>>(ptr, ptr, tile_sums, n_out);
    scan_pass2<<<1, 256, 0, stream>>>(tile_sums, tiles, ptr + n_out);
    scan_pass3<<<tiles, SCAN_BLK, 0, stream>>>(ptr, tile_sums, n_out);
    hipMemcpyAsync(offs, ptr, (size_t)n_out * sizeof(int), hipMemcpyDeviceToDevice, stream);
    bucket_scan<<<1, 256, 0, stream>>>(bcnt, boffs, cursor);
    int nchunks = (ne + CHUNK - 1) / CHUNK;
    bucket_scatter<<<nchunks, 256, 0, stream>>>(rows, cols, vals, ne, shift, cursor, bucketed);
    final_scatter<<<256, 256, 0, stream>>>(bucketed, boffs, shift, offs, edges);
    // restore offs for nothing further (edges complete); offs reused next call
}

extern "C" void kernel_launch(void* const* d_in, const int* in_sizes, int n_in,
                              void* d_out, int out_size, void* d_ws, size_t ws_size,
                              hipStream_t stream) {
    const float* user_emb = (const float*)d_in[0];
    const float* item_emb = (const float*)d_in[1];
    const float* cat_emb  = (const float*)d_in[2];
    const float* ui_vals  = (const float*)d_in[3];
    const float* iu_vals  = (const float*)d_in[4];
    const float* uu_vals  = (const float*)d_in[5];
    const float* ic_vals  = (const float*)d_in[6];
    const float* ci_vals  = (const float*)d_in[7];
    const int*   ui_rows  = (const int*)d_in[8];
    const int*   ui_cols  = (const int*)d_in[9];
    const int*   iu_rows  = (const int*)d_in[10];
    const int*   iu_cols  = (const int*)d_in[11];
    const int*   uu_rows  = (const int*)d_in[12];
    const int*   uu_cols  = (const int*)d_in[13];
    const int*   ic_rows  = (const int*)d_in[14];
    const int*   ic_cols  = (const int*)d_in[15];
    const int*   ci_rows  = (const int*)d_in[16];
    const int*   ci_cols  = (const int*)d_in[17];

    constexpr size_t NU = (size_t)N_USERS * DIM;  // 6,400,000
    constexpr size_t NI = (size_t)N_ITEMS * DIM;  // 3,200,000
    constexpr size_t NC = (size_t)N_CATS  * DIM;  //    64,000

    float* ws = (float*)d_ws;
    float* h_u[2] = { ws,               ws + NU };
    float* h_i[2] = { ws + 2 * NU,      ws + 2 * NU + NI };
    float* h_c[2] = { ws + 2 * NU + 2 * NI, ws + 2 * NU + 2 * NI + NC };

    // bucketed scratch (16 MB) overlays h_u[1]: builds finish before layer 0 writes it
    int2* bucketed = (int2*)h_u[1];

    float* sum_u = (float*)d_out;
    float* sum_i = sum_u + NU;
    float* out_c = sum_i + NI;

    const int blk = 256;
    const float inv = 1.0f / (N_LAYERS + 1);

    // ---- CSR workspace layout: explicit bump allocator (int units) ----
    constexpr size_t P = 2 * NU + 2 * NI + 2 * NC;  // 19,328,000 ints
    int* ib = (int*)d_ws;
    size_t off = P;
    int* ui_ptr = ib + off;  off += (size_t)N_USERS + 1;
    int* iu_ptr = ib + off;  off += (size_t)N_ITEMS + 1;
    int* uu_ptr = ib + off;  off += (size_t)N_USERS + 1;
    int* ic_ptr = ib + off;  off += (size_t)N_ITEMS + 1;
    int* ci_ptr = ib + off;  off += (size_t)N_CATS  + 1;
    off = (off + 1) & ~(size_t)1;                   // even-align for int2
    int2* ui_e = (int2*)(ib + off);  off += 2 * (size_t)NE_UI;
    int2* iu_e = (int2*)(ib + off);  off += 2 * (size_t)NE_UI;
    int2* uu_e = (int2*)(ib + off);  off += 2 * (size_t)NE_UU;
    int2* ic_e = (int2*)(ib + off);  off += 2 * (size_t)NE_IC;
    int2* ci_e = (int2*)(ib + off);  off += 2 * (size_t)NE_IC;
    int* offs      = ib + off;  off += (size_t)N_USERS + 1;
    int* tile_sums = ib + off;  off += 256;
    int* bcnt      = ib + off;  off += 256;
    int* boffs     = ib + off;  off += 257;
    int* cursor    = ib + off;  off += 256;
    size_t needed_bytes = off * sizeof(int);  // ~121.3 MB

    // init: h = emb; sum = emb (layer-0 contribution)
    hipMemcpyAsync(h_u[0], user_emb, NU * sizeof(float), hipMemcpyDeviceToDevice, stream);
    hipMemcpyAsync(h_i[0], item_emb, NI * sizeof(float), hipMemcpyDeviceToDevice, stream);
    hipMemcpyAsync(h_c[0], cat_emb,  NC * sizeof(float), hipMemcpyDeviceToDevice, stream);
    hipMemcpyAsync(sum_u,  user_emb, NU * sizeof(float), hipMemcpyDeviceToDevice, stream);
    hipMemcpyAsync(sum_i,  item_emb, NI * sizeof(float), hipMemcpyDeviceToDevice, stream);

    if (ws_size >= needed_bytes) {
        // ---- pull path: build CSR once per launch (two-level coalesced scatter) ----
        build_csr(ui_rows, ui_cols, ui_vals, NE_UI, N_USERS, ui_ptr, ui_e, offs, tile_sums,
                  bcnt, boffs, cursor, bucketed, stream);
        build_csr(iu_rows, iu_cols, iu_vals, NE_UI, N_ITEMS, iu_ptr, iu_e, offs, tile_sums,
                  bcnt, boffs, cursor, bucketed, stream);
        build_csr(uu_rows, uu_cols, uu_vals, NE_UU, N_USERS, uu_ptr, uu_e, offs, tile_sums,
                  bcnt, boffs, cursor, bucketed, stream);
        build_csr(ic_rows, ic_cols, ic_vals, NE_IC, N_ITEMS, ic_ptr, ic_e, offs, tile_sums,
                  bcnt, boffs, cursor, bucketed, stream);
        build_csr(ci_rows, ci_cols, ci_vals, NE_IC, N_CATS,  ci_ptr, ci_e, offs, tile_sums,
                  bcnt, boffs, cursor, bucketed, stream);

        int gu = (N_USERS * 64 + blk - 1) / blk;  // 4 rows (waves) per block
        int gi = (N_ITEMS * 64 + blk - 1) / blk;
        int gc = (N_CATS  * 64 + blk - 1) / blk;

        int cur = 0;
        for (int l = 0; l < N_LAYERS; ++l) {
            int nxt = cur ^ 1;
            int last = (l == N_LAYERS - 1);
            layer_two<<<gu, blk, 0, stream>>>(ui_ptr, ui_e, h_i[cur], uu_ptr, uu_e, h_u[cur],
                                              h_u[nxt], sum_u, N_USERS, inv, last);
            layer_two<<<gi, blk, 0, stream>>>(iu_ptr, iu_e, h_u[cur], ic_ptr, ic_e, h_c[cur],
                                              h_i[nxt], sum_i, N_ITEMS, inv, last);
            layer_one<<<gc, blk, 0, stream>>>(ci_ptr, ci_e, h_i[cur],
                                              last ? out_c : h_c[nxt], N_CATS);
            cur = nxt;
        }
    } else {
        // ---- fallback: push-atomic path ----
        const int ew_grid = 2048;
        int cur = 0;
        for (int l = 0; l < N_LAYERS; ++l) {
            int nxt = cur ^ 1;
            hipMemsetAsync(h_u[nxt], 0, NU * sizeof(float), stream);
            hipMemsetAsync(h_i[nxt], 0, NI * sizeof(float), stream);
            hipMemsetAsync(h_c[nxt], 0, NC * sizeof(float), stream);
            spmm_edges<<<(NE_UI + 3) / 4, blk, 0, stream>>>(ui_rows, ui_cols, ui_vals, h_i[cur], h_u[nxt], NE_UI);
            spmm_edges<<<(NE_UU + 3) / 4, blk, 0, stream>>>(uu_rows, uu_cols, uu_vals, h_u[cur], h_u[nxt], NE_UU);
            spmm_edges<<<(NE_UI + 3) / 4, blk, 0, stream>>>(iu_rows, iu_cols, iu_vals, h_u[cur], h_i[nxt], NE_UI);
            spmm_edges<<<(NE_IC + 3) / 4, blk, 0, stream>>>(ic_rows, ic_cols, ic_vals, h_c[cur], h_i[nxt], NE_IC);
            spmm_edges<<<(NE_IC + 3) / 4, blk, 0, stream>>>(ci_rows, ci_cols, ci_vals, h_i[cur], h_c[nxt], NE_IC);
            accum_kernel<<<ew_grid, blk, 0, stream>>>(sum_u, h_u[nxt], (int)NU);
            accum_kernel<<<ew_grid, blk, 0, stream>>>(sum_i, h_i[nxt], (int)NI);
            cur = nxt;
        }
        scale_kernel<<<ew_grid, blk, 0, stream>>>(sum_u, (int)NU, inv);
        scale_kernel<<<ew_grid, blk, 0, stream>>>(sum_i, (int)NI, inv);
        hipMemcpyAsync(out_c, h_c[cur], NC * sizeof(float), hipMemcpyDeviceToDevice, stream);
    }
}

// Round 6
// 1371.327 us; speedup vs baseline: 1.1266x; 1.1266x over previous
//
#include <hip/hip_runtime.h>

// Problem constants (from reference)
constexpr int DIM      = 64;
constexpr int N_USERS  = 100000;
constexpr int N_ITEMS  = 50000;
constexpr int N_CATS   = 1000;
constexpr int NE_UI    = 2000000;
constexpr int NE_UU    = 1000000;
constexpr int NE_IC    = 150000;
constexpr int N_LAYERS = 3;

constexpr int CHUNK = 8192;  // edges per bucket_scatter chunk

// ---------------- CSR build (bucket-local, no per-row global atomics) ----------------

// 256-bin bucket histogram, LDS-staged; one global atomic per bin per block.
__global__ __launch_bounds__(256) void bucket_hist(const int* __restrict__ rows,
                                                   int* __restrict__ bcnt,
                                                   int shift, int ne) {
    __shared__ int lb[256];
    lb[threadIdx.x] = 0;
    __syncthreads();
    int i = blockIdx.x * blockDim.x + threadIdx.x;
    int st = gridDim.x * blockDim.x;
    for (; i < ne; i += st) atomicAdd(&lb[rows[i] >> shift], 1);
    __syncthreads();
    if (lb[threadIdx.x]) atomicAdd(&bcnt[threadIdx.x], lb[threadIdx.x]);
}

// exclusive scan of 256 bucket counts -> boffs[0..256], cursor = boffs
__global__ void bucket_scan(const int* __restrict__ bcnt, int* __restrict__ boffs,
                            int* __restrict__ cursor) {
    __shared__ int lds[256];
    int tid = threadIdx.x;
    int v = bcnt[tid];
    lds[tid] = v;
    __syncthreads();
    for (int off = 1; off < 256; off <<= 1) {
        int t = (tid >= off) ? lds[tid - off] : 0;
        __syncthreads();
        lds[tid] += t;
        __syncthreads();
    }
    int excl = lds[tid] - v;
    boffs[tid] = excl;
    cursor[tid] = excl;
    if (tid == 255) boffs[256] = lds[255];
}

// Level 1: LDS-staged multisplit into <=256 coarse buckets.
// Packs (local_row << 17) | col into .x (shift <= 9, col < 2^17), val bits in .y.
__global__ __launch_bounds__(256) void bucket_scatter(const int* __restrict__ rows,
                                                      const int* __restrict__ cols,
                                                      const float* __restrict__ vals,
                                                      int ne, int shift,
                                                      int* __restrict__ cursor,
                                                      int2* __restrict__ out) {
    __shared__ int2 stage[CHUNK];
    __shared__ unsigned char sb[CHUNK];
    __shared__ int hist[256], lbase[256], gbase[256], cnt[256];
    int tid = threadIdx.x;
    int nchunks = (ne + CHUNK - 1) / CHUNK;
    for (int ch = blockIdx.x; ch < nchunks; ch += gridDim.x) {
        int base = ch * CHUNK;
        int nedge = min(CHUNK, ne - base);
        hist[tid] = 0;
        __syncthreads();
        for (int k = tid; k < nedge; k += 256)
            atomicAdd(&hist[rows[base + k] >> shift], 1);
        __syncthreads();
        lbase[tid] = hist[tid];
        __syncthreads();
        for (int off = 1; off < 256; off <<= 1) {
            int t = (tid >= off) ? lbase[tid - off] : 0;
            __syncthreads();
            lbase[tid] += t;
            __syncthreads();
        }
        int excl = lbase[tid] - hist[tid];
        cnt[tid] = excl;
        gbase[tid] = hist[tid] ? atomicAdd(&cursor[tid], hist[tid]) : 0;
        lbase[tid] = excl;  // own-slot rewrite, safe
        __syncthreads();
        for (int k = tid; k < nedge; k += 256) {
            int r = rows[base + k];
            int b = r >> shift;
            int slot = atomicAdd(&cnt[b], 1);
            int lr = r - (b << shift);
            stage[slot] = make_int2((lr << 17) | cols[base + k], __float_as_int(vals[base + k]));
            sb[slot] = (unsigned char)b;
        }
        __syncthreads();
        for (int j = tid; j < nedge; j += 256) {
            int b = sb[j];
            out[gbase[b] + (j - lbase[b])] = stage[j];
        }
        __syncthreads();
    }
}

// Level 2: one block per bucket. Fuses per-row hist (LDS, <=512 bins), local
// exclusive scan, coalesced ptr-segment write, and cursor-scatter into the
// bucket's contiguous edges window [boffs[b], boffs[b+1]) — all L2-local.
__global__ __launch_bounds__(256) void bucket_finalize(const int2* __restrict__ bucketed,
                                                       const int* __restrict__ boffs,
                                                       int shift, int n_out,
                                                       int* __restrict__ ptr,
                                                       int2* __restrict__ edges) {
    __shared__ int h[512], psum[256], cur[512];
    int tid = threadIdx.x, b = blockIdx.x;
    int s = boffs[b], e = boffs[b + 1];
    int base_row = b << shift;
    int nrows_b = min(1 << shift, n_out - base_row);
    h[tid] = 0; h[tid + 256] = 0;
    __syncthreads();
    for (int j = s + tid; j < e; j += 256)
        atomicAdd(&h[(unsigned)bucketed[j].x >> 17], 1);
    __syncthreads();
    int a0 = h[2 * tid], a1 = h[2 * tid + 1];
    psum[tid] = a0 + a1;
    __syncthreads();
    for (int off = 1; off < 256; off <<= 1) {
        int t = (tid >= off) ? psum[tid - off] : 0;
        __syncthreads();
        psum[tid] += t;
        __syncthreads();
    }
    int pex = (tid == 0) ? 0 : psum[tid - 1];
    cur[2 * tid] = pex;
    cur[2 * tid + 1] = pex + a0;
    if (2 * tid < nrows_b)     ptr[base_row + 2 * tid]     = s + pex;
    if (2 * tid + 1 < nrows_b) ptr[base_row + 2 * tid + 1] = s + pex + a0;
    if (b == gridDim.x - 1 && tid == 0) ptr[n_out] = boffs[gridDim.x];
    __syncthreads();
    for (int j = s + tid; j < e; j += 256) {
        int2 w = bucketed[j];
        int lr = (unsigned)w.x >> 17;
        int slot = atomicAdd(&cur[lr], 1);
        edges[s + slot] = make_int2(w.x & 0x1FFFF, w.y);
    }
}

// ---------------- pull-style fused layer kernels ----------------
// Wave layout: 4 edge-groups (grp = lane>>4) x 16 lanes (sub = lane&15) x float4.

__device__ __forceinline__ void gather4(const int* __restrict__ ptr,
                                        const int2* __restrict__ edges,
                                        const float* __restrict__ H,
                                        int r, int grp, int sub, float4& acc) {
    int s = ptr[r], e = ptr[r + 1];
    for (int j = s + grp; j < e; j += 4) {
        int2 ed = edges[j];
        float4 hv = *reinterpret_cast<const float4*>(H + (size_t)ed.x * DIM + sub * 4);
        float w = __int_as_float(ed.y);
        acc.x = fmaf(w, hv.x, acc.x);
        acc.y = fmaf(w, hv.y, acc.y);
        acc.z = fmaf(w, hv.z, acc.z);
        acc.w = fmaf(w, hv.w, acc.w);
    }
}

__device__ __forceinline__ void xgroup_reduce(float4& a) {
#pragma unroll
    for (int m = 16; m <= 32; m <<= 1) {
        a.x += __shfl_xor(a.x, m);
        a.y += __shfl_xor(a.y, m);
        a.z += __shfl_xor(a.z, m);
        a.w += __shfl_xor(a.w, m);
    }
}

__global__ void layer_two(const int* __restrict__ pA, const int2* __restrict__ eA, const float* __restrict__ HA,
                          const int* __restrict__ pB, const int2* __restrict__ eB, const float* __restrict__ HB,
                          float* __restrict__ h_out, float* __restrict__ sum,
                          int nrows, float scale, int last) {
    int wid  = (blockIdx.x * blockDim.x + threadIdx.x) >> 6;
    int lane = threadIdx.x & 63;
    if (wid >= nrows) return;
    int grp = lane >> 4, sub = lane & 15;
    float4 acc = make_float4(0.f, 0.f, 0.f, 0.f);
    gather4(pA, eA, HA, wid, grp, sub, acc);
    gather4(pB, eB, HB, wid, grp, sub, acc);
    xgroup_reduce(acc);  // all lanes hold final acc for dims [sub*4, sub*4+4)
    size_t o = (size_t)wid * DIM + sub * 4;
    if (last) {
        if (grp == 0) {
            float4 sv = *reinterpret_cast<const float4*>(sum + o);
            sv.x = (sv.x + acc.x) * scale;
            sv.y = (sv.y + acc.y) * scale;
            sv.z = (sv.z + acc.z) * scale;
            sv.w = (sv.w + acc.w) * scale;
            *reinterpret_cast<float4*>(sum + o) = sv;
        }
    } else {
        if (grp == 0) {
            *reinterpret_cast<float4*>(h_out + o) = acc;
        } else if (grp == 1) {
            float4 sv = *reinterpret_cast<const float4*>(sum + o);
            sv.x += acc.x; sv.y += acc.y; sv.z += acc.z; sv.w += acc.w;
            *reinterpret_cast<float4*>(sum + o) = sv;
        }
    }
}

__global__ void layer_one(const int* __restrict__ p, const int2* __restrict__ e,
                          const float* __restrict__ H, float* __restrict__ out, int nrows) {
    int wid  = (blockIdx.x * blockDim.x + threadIdx.x) >> 6;
    int lane = threadIdx.x & 63;
    if (wid >= nrows) return;
    int grp = lane >> 4, sub = lane & 15;
    float4 acc = make_float4(0.f, 0.f, 0.f, 0.f);
    gather4(p, e, H, wid, grp, sub, acc);
    xgroup_reduce(acc);
    if (grp == 0)
        *reinterpret_cast<float4*>(out + (size_t)wid * DIM + sub * 4) = acc;
}

// ---------------- fallback (push-atomic path) ----------------

__global__ void spmm_edges(const int* __restrict__ rows, const int* __restrict__ cols,
                           const float* __restrict__ vals, const float* __restrict__ H,
                           float* __restrict__ out, int ne) {
    int tid  = blockIdx.x * blockDim.x + threadIdx.x;
    int e    = tid >> 6;
    int lane = threadIdx.x & 63;
    if (e >= ne) return;
    float x = vals[e] * H[(size_t)cols[e] * DIM + lane];
    unsafeAtomicAdd(&out[(size_t)rows[e] * DIM + lane], x);
}

__global__ void accum_kernel(float* __restrict__ sum, const float* __restrict__ h, int n) {
    int i = blockIdx.x * blockDim.x + threadIdx.x;
    int st = gridDim.x * blockDim.x;
    for (; i < n; i += st) sum[i] += h[i];
}

__global__ void scale_kernel(float* __restrict__ p, int n, float s) {
    int i = blockIdx.x * blockDim.x + threadIdx.x;
    int st = gridDim.x * blockDim.x;
    for (; i < n; i += st) p[i] *= s;
}

// ---------------- host ----------------

static int bshift(int n_out) {   // smallest shift with (n_out >> shift) < 256
    int s = 0;
    while ((n_out >> s) >= 256) ++s;
    return s;
}

static void build_csr(const int* rows, const int* cols, const float* vals, int ne, int n_out,
                      int* ptr, int2* edges,
                      int* bcnt, int* boffs, int* cursor, int2* bucketed,
                      hipStream_t stream) {
    int shift = bshift(n_out);
    hipMemsetAsync(bcnt, 0, 256 * sizeof(int), stream);
    int g = (ne + 255) / 256;
    if (g > 4096) g = 4096;
    bucket_hist<<<g, 256, 0, stream>>>(rows, bcnt, shift, ne);
    bucket_scan<<<1, 256, 0, stream>>>(bcnt, boffs, cursor);
    int nchunks = (ne + CHUNK - 1) / CHUNK;
    bucket_scatter<<<nchunks, 256, 0, stream>>>(rows, cols, vals, ne, shift, cursor, bucketed);
    int nb = (n_out + (1 << shift) - 1) >> shift;
    bucket_finalize<<<nb, 256, 0, stream>>>(bucketed, boffs, shift, n_out, ptr, edges);
}

extern "C" void kernel_launch(void* const* d_in, const int* in_sizes, int n_in,
                              void* d_out, int out_size, void* d_ws, size_t ws_size,
                              hipStream_t stream) {
    const float* user_emb = (const float*)d_in[0];
    const float* item_emb = (const float*)d_in[1];
    const float* cat_emb  = (const float*)d_in[2];
    const float* ui_vals  = (const float*)d_in[3];
    const float* iu_vals  = (const float*)d_in[4];
    const float* uu_vals  = (const float*)d_in[5];
    const float* ic_vals  = (const float*)d_in[6];
    const float* ci_vals  = (const float*)d_in[7];
    const int*   ui_rows  = (const int*)d_in[8];
    const int*   ui_cols  = (const int*)d_in[9];
    const int*   iu_rows  = (const int*)d_in[10];
    const int*   iu_cols  = (const int*)d_in[11];
    const int*   uu_rows  = (const int*)d_in[12];
    const int*   uu_cols  = (const int*)d_in[13];
    const int*   ic_rows  = (const int*)d_in[14];
    const int*   ic_cols  = (const int*)d_in[15];
    const int*   ci_rows  = (const int*)d_in[16];
    const int*   ci_cols  = (const int*)d_in[17];

    constexpr size_t NU = (size_t)N_USERS * DIM;  // 6,400,000
    constexpr size_t NI = (size_t)N_ITEMS * DIM;  // 3,200,000
    constexpr size_t NC = (size_t)N_CATS  * DIM;  //    64,000

    float* ws = (float*)d_ws;
    float* h_u[2] = { ws,               ws + NU };
    float* h_i[2] = { ws + 2 * NU,      ws + 2 * NU + NI };
    float* h_c[2] = { ws + 2 * NU + 2 * NI, ws + 2 * NU + 2 * NI + NC };

    // bucketed scratch (16 MB) overlays h_u[1]: builds finish before layer 0 writes it
    int2* bucketed = (int2*)h_u[1];

    float* sum_u = (float*)d_out;
    float* sum_i = sum_u + NU;
    float* out_c = sum_i + NI;

    const int blk = 256;
    const float inv = 1.0f / (N_LAYERS + 1);

    // ---- CSR workspace layout: explicit bump allocator (int units) ----
    constexpr size_t P = 2 * NU + 2 * NI + 2 * NC;  // 19,328,000 ints
    int* ib = (int*)d_ws;
    size_t off = P;
    int* ui_ptr = ib + off;  off += (size_t)N_USERS + 1;
    int* iu_ptr = ib + off;  off += (size_t)N_ITEMS + 1;
    int* uu_ptr = ib + off;  off += (size_t)N_USERS + 1;
    int* ic_ptr = ib + off;  off += (size_t)N_ITEMS + 1;
    int* ci_ptr = ib + off;  off += (size_t)N_CATS  + 1;
    off = (off + 1) & ~(size_t)1;                   // even-align for int2
    int2* ui_e = (int2*)(ib + off);  off += 2 * (size_t)NE_UI;
    int2* iu_e = (int2*)(ib + off);  off += 2 * (size_t)NE_UI;
    int2* uu_e = (int2*)(ib + off);  off += 2 * (size_t)NE_UU;
    int2* ic_e = (int2*)(ib + off);  off += 2 * (size_t)NE_IC;
    int2* ci_e = (int2*)(ib + off);  off += 2 * (size_t)NE_IC;
    int* bcnt      = ib + off;  off += 256;
    int* boffs     = ib + off;  off += 257;
    int* cursor    = ib + off;  off += 256;
    size_t needed_bytes = off * sizeof(int);  // ~120.9 MB

    // init: h = emb; sum = emb (layer-0 contribution)
    hipMemcpyAsync(h_u[0], user_emb, NU * sizeof(float), hipMemcpyDeviceToDevice, stream);
    hipMemcpyAsync(h_i[0], item_emb, NI * sizeof(float), hipMemcpyDeviceToDevice, stream);
    hipMemcpyAsync(h_c[0], cat_emb,  NC * sizeof(float), hipMemcpyDeviceToDevice, stream);
    hipMemcpyAsync(sum_u,  user_emb, NU * sizeof(float), hipMemcpyDeviceToDevice, stream);
    hipMemcpyAsync(sum_i,  item_emb, NI * sizeof(float), hipMemcpyDeviceToDevice, stream);

    if (ws_size >= needed_bytes) {
        // ---- pull path: build CSR once per launch (bucket-local build) ----
        build_csr(ui_rows, ui_cols, ui_vals, NE_UI, N_USERS, ui_ptr, ui_e,
                  bcnt, boffs, cursor, bucketed, stream);
        build_csr(iu_rows, iu_cols, iu_vals, NE_UI, N_ITEMS, iu_ptr, iu_e,
                  bcnt, boffs, cursor, bucketed, stream);
        build_csr(uu_rows, uu_cols, uu_vals, NE_UU, N_USERS, uu_ptr, uu_e,
                  bcnt, boffs, cursor, bucketed, stream);
        build_csr(ic_rows, ic_cols, ic_vals, NE_IC, N_ITEMS, ic_ptr, ic_e,
                  bcnt, boffs, cursor, bucketed, stream);
        build_csr(ci_rows, ci_cols, ci_vals, NE_IC, N_CATS,  ci_ptr, ci_e,
                  bcnt, boffs, cursor, bucketed, stream);

        int gu = (N_USERS * 64 + blk - 1) / blk;  // 4 rows (waves) per block
        int gi = (N_ITEMS * 64 + blk - 1) / blk;
        int gc = (N_CATS  * 64 + blk - 1) / blk;

        int cur = 0;
        for (int l = 0; l < N_LAYERS; ++l) {
            int nxt = cur ^ 1;
            int last = (l == N_LAYERS - 1);
            layer_two<<<gu, blk, 0, stream>>>(ui_ptr, ui_e, h_i[cur], uu_ptr, uu_e, h_u[cur],
                                              h_u[nxt], sum_u, N_USERS, inv, last);
            layer_two<<<gi, blk, 0, stream>>>(iu_ptr, iu_e, h_u[cur], ic_ptr, ic_e, h_c[cur],
                                              h_i[nxt], sum_i, N_ITEMS, inv, last);
            layer_one<<<gc, blk, 0, stream>>>(ci_ptr, ci_e, h_i[cur],
                                              last ? out_c : h_c[nxt], N_CATS);
            cur = nxt;
        }
    } else {
        // ---- fallback: push-atomic path ----
        const int ew_grid = 2048;
        int cur = 0;
        for (int l = 0; l < N_LAYERS; ++l) {
            int nxt = cur ^ 1;
            hipMemsetAsync(h_u[nxt], 0, NU * sizeof(float), stream);
            hipMemsetAsync(h_i[nxt], 0, NI * sizeof(float), stream);
            hipMemsetAsync(h_c[nxt], 0, NC * sizeof(float), stream);
            spmm_edges<<<(NE_UI + 3) / 4, blk, 0, stream>>>(ui_rows, ui_cols, ui_vals, h_i[cur], h_u[nxt], NE_UI);
            spmm_edges<<<(NE_UU + 3) / 4, blk, 0, stream>>>(uu_rows, uu_cols, uu_vals, h_u[cur], h_u[nxt], NE_UU);
            spmm_edges<<<(NE_UI + 3) / 4, blk, 0, stream>>>(iu_rows, iu_cols, iu_vals, h_u[cur], h_i[nxt], NE_UI);
            spmm_edges<<<(NE_IC + 3) / 4, blk, 0, stream>>>(ic_rows, ic_cols, ic_vals, h_c[cur], h_i[nxt], NE_IC);
            spmm_edges<<<(NE_IC + 3) / 4, blk, 0, stream>>>(ci_rows, ci_cols, ci_vals, h_i[cur], h_c[nxt], NE_IC);
            accum_kernel<<<ew_grid, blk, 0, stream>>>(sum_u, h_u[nxt], (int)NU);
            accum_kernel<<<ew_grid, blk, 0, stream>>>(sum_i, h_i[nxt], (int)NI);
            cur = nxt;
        }
        scale_kernel<<<ew_grid, blk, 0, stream>>>(sum_u, (int)NU, inv);
        scale_kernel<<<ew_grid, blk, 0, stream>>>(sum_i, (int)NI, inv);
        hipMemcpyAsync(out_c, h_c[cur], NC * sizeof(float), hipMemcpyDeviceToDevice, stream);
    }
}

// Round 7
// 1100.063 us; speedup vs baseline: 1.4044x; 1.2466x over previous
//
#include <hip/hip_runtime.h>

typedef unsigned int uint;
typedef unsigned short ushort;

// Problem constants (from reference)
constexpr int DIM      = 64;
constexpr int N_USERS  = 100000;
constexpr int N_ITEMS  = 50000;
constexpr int N_CATS   = 1000;
constexpr int NE_UI    = 2000000;
constexpr int NE_UU    = 1000000;
constexpr int NE_IC    = 150000;
constexpr int N_LAYERS = 3;

constexpr int CHUNK = 8192;  // edges per bucket_scatter chunk

// ---------------- bf16 helpers ----------------

__device__ __forceinline__ ushort f2bf(float f) {  // round-to-nearest-even
    uint u = __float_as_uint(f);
    u += 0x7FFFu + ((u >> 16) & 1u);
    return (ushort)(u >> 16);
}
__device__ __forceinline__ float bfl(uint u) { return __uint_as_float(u << 16); }
__device__ __forceinline__ float bfh(uint u) { return __uint_as_float(u & 0xFFFF0000u); }

__global__ void cast_to_bf16(const float* __restrict__ in, ushort* __restrict__ out, int n8) {
    int i = blockIdx.x * blockDim.x + threadIdx.x;
    int st = gridDim.x * blockDim.x;
    for (; i < n8; i += st) {
        float4 a = reinterpret_cast<const float4*>(in)[2 * i];
        float4 b = reinterpret_cast<const float4*>(in)[2 * i + 1];
        uint4 v;
        v.x = (uint)f2bf(a.x) | ((uint)f2bf(a.y) << 16);
        v.y = (uint)f2bf(a.z) | ((uint)f2bf(a.w) << 16);
        v.z = (uint)f2bf(b.x) | ((uint)f2bf(b.y) << 16);
        v.w = (uint)f2bf(b.z) | ((uint)f2bf(b.w) << 16);
        reinterpret_cast<uint4*>(out)[i] = v;
    }
}

// ---------------- CSR build (bucket-local, no per-row global atomics) ----------------

__global__ __launch_bounds__(256) void bucket_hist(const int* __restrict__ rows,
                                                   int* __restrict__ bcnt,
                                                   int shift, int ne) {
    __shared__ int lb[256];
    lb[threadIdx.x] = 0;
    __syncthreads();
    int i = blockIdx.x * blockDim.x + threadIdx.x;
    int st = gridDim.x * blockDim.x;
    for (; i < ne; i += st) atomicAdd(&lb[rows[i] >> shift], 1);
    __syncthreads();
    if (lb[threadIdx.x]) atomicAdd(&bcnt[threadIdx.x], lb[threadIdx.x]);
}

__global__ void bucket_scan(const int* __restrict__ bcnt, int* __restrict__ boffs,
                            int* __restrict__ cursor) {
    __shared__ int lds[256];
    int tid = threadIdx.x;
    int v = bcnt[tid];
    lds[tid] = v;
    __syncthreads();
    for (int off = 1; off < 256; off <<= 1) {
        int t = (tid >= off) ? lds[tid - off] : 0;
        __syncthreads();
        lds[tid] += t;
        __syncthreads();
    }
    int excl = lds[tid] - v;
    boffs[tid] = excl;
    cursor[tid] = excl;
    if (tid == 255) boffs[256] = lds[255];
}

// Level 1: LDS-staged multisplit into <=256 coarse buckets.
// Packs (local_row << 17) | col into .x (shift <= 9, col < 2^17), val bits in .y.
__global__ __launch_bounds__(256) void bucket_scatter(const int* __restrict__ rows,
                                                      const int* __restrict__ cols,
                                                      const float* __restrict__ vals,
                                                      int ne, int shift,
                                                      int* __restrict__ cursor,
                                                      int2* __restrict__ out) {
    __shared__ int2 stage[CHUNK];
    __shared__ unsigned char sb[CHUNK];
    __shared__ int hist[256], lbase[256], gbase[256], cnt[256];
    int tid = threadIdx.x;
    int nchunks = (ne + CHUNK - 1) / CHUNK;
    for (int ch = blockIdx.x; ch < nchunks; ch += gridDim.x) {
        int base = ch * CHUNK;
        int nedge = min(CHUNK, ne - base);
        hist[tid] = 0;
        __syncthreads();
        for (int k = tid; k < nedge; k += 256)
            atomicAdd(&hist[rows[base + k] >> shift], 1);
        __syncthreads();
        lbase[tid] = hist[tid];
        __syncthreads();
        for (int off = 1; off < 256; off <<= 1) {
            int t = (tid >= off) ? lbase[tid - off] : 0;
            __syncthreads();
            lbase[tid] += t;
            __syncthreads();
        }
        int excl = lbase[tid] - hist[tid];
        cnt[tid] = excl;
        gbase[tid] = hist[tid] ? atomicAdd(&cursor[tid], hist[tid]) : 0;
        lbase[tid] = excl;  // own-slot rewrite, safe
        __syncthreads();
        for (int k = tid; k < nedge; k += 256) {
            int r = rows[base + k];
            int b = r >> shift;
            int slot = atomicAdd(&cnt[b], 1);
            int lr = r - (b << shift);
            stage[slot] = make_int2((lr << 17) | cols[base + k], __float_as_int(vals[base + k]));
            sb[slot] = (unsigned char)b;
        }
        __syncthreads();
        for (int j = tid; j < nedge; j += 256) {
            int b = sb[j];
            out[gbase[b] + (j - lbase[b])] = stage[j];
        }
        __syncthreads();
    }
}

// Level 2: one block per bucket; hist + scan + ptr write + scatter, all L2-local.
__global__ __launch_bounds__(256) void bucket_finalize(const int2* __restrict__ bucketed,
                                                       const int* __restrict__ boffs,
                                                       int shift, int n_out,
                                                       int* __restrict__ ptr,
                                                       int2* __restrict__ edges) {
    __shared__ int h[512], psum[256], cur[512];
    int tid = threadIdx.x, b = blockIdx.x;
    int s = boffs[b], e = boffs[b + 1];
    int base_row = b << shift;
    int nrows_b = min(1 << shift, n_out - base_row);
    h[tid] = 0; h[tid + 256] = 0;
    __syncthreads();
    for (int j = s + tid; j < e; j += 256)
        atomicAdd(&h[(unsigned)bucketed[j].x >> 17], 1);
    __syncthreads();
    int a0 = h[2 * tid], a1 = h[2 * tid + 1];
    psum[tid] = a0 + a1;
    __syncthreads();
    for (int off = 1; off < 256; off <<= 1) {
        int t = (tid >= off) ? psum[tid - off] : 0;
        __syncthreads();
        psum[tid] += t;
        __syncthreads();
    }
    int pex = (tid == 0) ? 0 : psum[tid - 1];
    cur[2 * tid] = pex;
    cur[2 * tid + 1] = pex + a0;
    if (2 * tid < nrows_b)     ptr[base_row + 2 * tid]     = s + pex;
    if (2 * tid + 1 < nrows_b) ptr[base_row + 2 * tid + 1] = s + pex + a0;
    if (b == gridDim.x - 1 && tid == 0) ptr[n_out] = boffs[gridDim.x];
    __syncthreads();
    for (int j = s + tid; j < e; j += 256) {
        int2 w = bucketed[j];
        int lr = (unsigned)w.x >> 17;
        int slot = atomicAdd(&cur[lr], 1);
        edges[s + slot] = make_int2(w.x & 0x1FFFF, w.y);
    }
}

// ---------------- pull-style fused layer kernels (bf16 H) ----------------
// Wave: 8 edge-groups (grp=lane>>3) x 8 lanes (sub=lane&7) x 16B (8 bf16).
// Each lane covers dims [sub*8, sub*8+8); each group reads a full 128B row.

__device__ __forceinline__ void gather8(const int* __restrict__ ptr,
                                        const int2* __restrict__ edges,
                                        const ushort* __restrict__ H,
                                        int r, int grp, int sub, float* acc) {
    int s = ptr[r], e = ptr[r + 1];
    for (int j = s + grp; j < e; j += 8) {
        int2 ed = edges[j];
        uint4 hv = *reinterpret_cast<const uint4*>(H + (size_t)ed.x * DIM + sub * 8);
        float w = __int_as_float(ed.y);
        acc[0] = fmaf(w, bfl(hv.x), acc[0]);
        acc[1] = fmaf(w, bfh(hv.x), acc[1]);
        acc[2] = fmaf(w, bfl(hv.y), acc[2]);
        acc[3] = fmaf(w, bfh(hv.y), acc[3]);
        acc[4] = fmaf(w, bfl(hv.z), acc[4]);
        acc[5] = fmaf(w, bfh(hv.z), acc[5]);
        acc[6] = fmaf(w, bfl(hv.w), acc[6]);
        acc[7] = fmaf(w, bfh(hv.w), acc[7]);
    }
}

__device__ __forceinline__ void xreduce8(float* a) {
#pragma unroll
    for (int m = 8; m <= 32; m <<= 1)
#pragma unroll
        for (int k = 0; k < 8; ++k)
            a[k] += __shfl_xor(a[k], m);
}

__device__ __forceinline__ uint4 pack_bf8(const float* a) {
    uint4 v;
    v.x = (uint)f2bf(a[0]) | ((uint)f2bf(a[1]) << 16);
    v.y = (uint)f2bf(a[2]) | ((uint)f2bf(a[3]) << 16);
    v.z = (uint)f2bf(a[4]) | ((uint)f2bf(a[5]) << 16);
    v.w = (uint)f2bf(a[6]) | ((uint)f2bf(a[7]) << 16);
    return v;
}

__global__ void layer_two(const int* __restrict__ pA, const int2* __restrict__ eA, const ushort* __restrict__ HA,
                          const int* __restrict__ pB, const int2* __restrict__ eB, const ushort* __restrict__ HB,
                          ushort* __restrict__ h_out, float* __restrict__ sum,
                          int nrows, float scale, int last) {
    int wid  = (blockIdx.x * blockDim.x + threadIdx.x) >> 6;
    int lane = threadIdx.x & 63;
    if (wid >= nrows) return;
    int grp = lane >> 3, sub = lane & 7;
    float acc[8] = {0.f, 0.f, 0.f, 0.f, 0.f, 0.f, 0.f, 0.f};
    gather8(pA, eA, HA, wid, grp, sub, acc);
    gather8(pB, eB, HB, wid, grp, sub, acc);
    xreduce8(acc);  // all lanes hold final acc for their 8 dims
    size_t o = (size_t)wid * DIM + sub * 8;
    if (last) {
        if (grp == 0) {
            float4* sp = reinterpret_cast<float4*>(sum + o);
            float4 s0 = sp[0], s1 = sp[1];
            s0.x = (s0.x + acc[0]) * scale; s0.y = (s0.y + acc[1]) * scale;
            s0.z = (s0.z + acc[2]) * scale; s0.w = (s0.w + acc[3]) * scale;
            s1.x = (s1.x + acc[4]) * scale; s1.y = (s1.y + acc[5]) * scale;
            s1.z = (s1.z + acc[6]) * scale; s1.w = (s1.w + acc[7]) * scale;
            sp[0] = s0; sp[1] = s1;
        }
    } else {
        if (grp == 0) {
            *reinterpret_cast<uint4*>(h_out + o) = pack_bf8(acc);
        } else if (grp == 1) {
            float4* sp = reinterpret_cast<float4*>(sum + o);
            float4 s0 = sp[0], s1 = sp[1];
            s0.x += acc[0]; s0.y += acc[1]; s0.z += acc[2]; s0.w += acc[3];
            s1.x += acc[4]; s1.y += acc[5]; s1.z += acc[6]; s1.w += acc[7];
            sp[0] = s0; sp[1] = s1;
        }
    }
}

__global__ void layer_one(const int* __restrict__ p, const int2* __restrict__ e,
                          const ushort* __restrict__ H,
                          ushort* __restrict__ out_bf, float* __restrict__ out_f32,
                          int nrows, int last) {
    int wid  = (blockIdx.x * blockDim.x + threadIdx.x) >> 6;
    int lane = threadIdx.x & 63;
    if (wid >= nrows) return;
    int grp = lane >> 3, sub = lane & 7;
    float acc[8] = {0.f, 0.f, 0.f, 0.f, 0.f, 0.f, 0.f, 0.f};
    gather8(p, e, H, wid, grp, sub, acc);
    xreduce8(acc);
    if (grp != 0) return;
    size_t o = (size_t)wid * DIM + sub * 8;
    if (last) {
        float4* op = reinterpret_cast<float4*>(out_f32 + o);
        op[0] = make_float4(acc[0], acc[1], acc[2], acc[3]);
        op[1] = make_float4(acc[4], acc[5], acc[6], acc[7]);
    } else {
        *reinterpret_cast<uint4*>(out_bf + o) = pack_bf8(acc);
    }
}

// ---------------- fallback (push-atomic fp32 path) ----------------

__global__ void spmm_edges(const int* __restrict__ rows, const int* __restrict__ cols,
                           const float* __restrict__ vals, const float* __restrict__ H,
                           float* __restrict__ out, int ne) {
    int tid  = blockIdx.x * blockDim.x + threadIdx.x;
    int e    = tid >> 6;
    int lane = threadIdx.x & 63;
    if (e >= ne) return;
    float x = vals[e] * H[(size_t)cols[e] * DIM + lane];
    unsafeAtomicAdd(&out[(size_t)rows[e] * DIM + lane], x);
}

__global__ void accum_kernel(float* __restrict__ sum, const float* __restrict__ h, int n) {
    int i = blockIdx.x * blockDim.x + threadIdx.x;
    int st = gridDim.x * blockDim.x;
    for (; i < n; i += st) sum[i] += h[i];
}

__global__ void scale_kernel(float* __restrict__ p, int n, float s) {
    int i = blockIdx.x * blockDim.x + threadIdx.x;
    int st = gridDim.x * blockDim.x;
    for (; i < n; i += st) p[i] *= s;
}

// ---------------- host ----------------

static int bshift(int n_out) {   // smallest shift with (n_out >> shift) < 256
    int s = 0;
    while ((n_out >> s) >= 256) ++s;
    return s;
}

static void build_csr(const int* rows, const int* cols, const float* vals, int ne, int n_out,
                      int* ptr, int2* edges,
                      int* bcnt, int* boffs, int* cursor, int2* bucketed,
                      hipStream_t stream) {
    int shift = bshift(n_out);
    hipMemsetAsync(bcnt, 0, 256 * sizeof(int), stream);
    int g = (ne + 255) / 256;
    if (g > 4096) g = 4096;
    bucket_hist<<<g, 256, 0, stream>>>(rows, bcnt, shift, ne);
    bucket_scan<<<1, 256, 0, stream>>>(bcnt, boffs, cursor);
    int nchunks = (ne + CHUNK - 1) / CHUNK;
    bucket_scatter<<<nchunks, 256, 0, stream>>>(rows, cols, vals, ne, shift, cursor, bucketed);
    int nb = (n_out + (1 << shift) - 1) >> shift;
    bucket_finalize<<<nb, 256, 0, stream>>>(bucketed, boffs, shift, n_out, ptr, edges);
}

extern "C" void kernel_launch(void* const* d_in, const int* in_sizes, int n_in,
                              void* d_out, int out_size, void* d_ws, size_t ws_size,
                              hipStream_t stream) {
    const float* user_emb = (const float*)d_in[0];
    const float* item_emb = (const float*)d_in[1];
    const float* cat_emb  = (const float*)d_in[2];
    const float* ui_vals  = (const float*)d_in[3];
    const float* iu_vals  = (const float*)d_in[4];
    const float* uu_vals  = (const float*)d_in[5];
    const float* ic_vals  = (const float*)d_in[6];
    const float* ci_vals  = (const float*)d_in[7];
    const int*   ui_rows  = (const int*)d_in[8];
    const int*   ui_cols  = (const int*)d_in[9];
    const int*   iu_rows  = (const int*)d_in[10];
    const int*   iu_cols  = (const int*)d_in[11];
    const int*   uu_rows  = (const int*)d_in[12];
    const int*   uu_cols  = (const int*)d_in[13];
    const int*   ic_rows  = (const int*)d_in[14];
    const int*   ic_cols  = (const int*)d_in[15];
    const int*   ci_rows  = (const int*)d_in[16];
    const int*   ci_cols  = (const int*)d_in[17];

    constexpr size_t NU = (size_t)N_USERS * DIM;  // 6,400,000
    constexpr size_t NI = (size_t)N_ITEMS * DIM;  // 3,200,000
    constexpr size_t NC = (size_t)N_CATS  * DIM;  //    64,000

    float* sum_u = (float*)d_out;
    float* sum_i = sum_u + NU;
    float* out_c = sum_i + NI;

    const int blk = 256;
    const float inv = 1.0f / (N_LAYERS + 1);

    // ---- workspace bump allocator (bytes, 16B-aligned) ----
    unsigned char* wb = (unsigned char*)d_ws;
    size_t woff = 0;
    auto take = [&](size_t bytes) -> void* {
        void* p = wb + woff;
        woff = (woff + bytes + 15) & ~(size_t)15;
        return p;
    };
    ushort* h_u[2] = { (ushort*)take(NU * 2), (ushort*)take(NU * 2) };
    ushort* h_i[2] = { (ushort*)take(NI * 2), (ushort*)take(NI * 2) };
    ushort* h_c[2] = { (ushort*)take(NC * 2), (ushort*)take(NC * 2) };
    int* ui_ptr = (int*)take(((size_t)N_USERS + 1) * 4);
    int* iu_ptr = (int*)take(((size_t)N_ITEMS + 1) * 4);
    int* uu_ptr = (int*)take(((size_t)N_USERS + 1) * 4);
    int* ic_ptr = (int*)take(((size_t)N_ITEMS + 1) * 4);
    int* ci_ptr = (int*)take(((size_t)N_CATS  + 1) * 4);
    int2* ui_e = (int2*)take((size_t)NE_UI * 8);
    int2* iu_e = (int2*)take((size_t)NE_UI * 8);
    int2* uu_e = (int2*)take((size_t)NE_UU * 8);
    int2* ic_e = (int2*)take((size_t)NE_IC * 8);
    int2* ci_e = (int2*)take((size_t)NE_IC * 8);
    int2* bucketed = (int2*)take((size_t)NE_UI * 8);  // 16 MB scratch
    int* bcnt   = (int*)take(256 * 4);
    int* boffs  = (int*)take(257 * 4);
    int* cursor = (int*)take(256 * 4);
    size_t needed_bytes = woff;  // ~98 MB

    if (ws_size >= needed_bytes) {
        // init: h0 = bf16(emb); sum = emb (layer-0 contribution, fp32)
        cast_to_bf16<<<1024, blk, 0, stream>>>(user_emb, h_u[0], (int)(NU / 8));
        cast_to_bf16<<<1024, blk, 0, stream>>>(item_emb, h_i[0], (int)(NI / 8));
        cast_to_bf16<<<64,   blk, 0, stream>>>(cat_emb,  h_c[0], (int)(NC / 8));
        hipMemcpyAsync(sum_u, user_emb, NU * sizeof(float), hipMemcpyDeviceToDevice, stream);
        hipMemcpyAsync(sum_i, item_emb, NI * sizeof(float), hipMemcpyDeviceToDevice, stream);

        // ---- build CSR once per launch (bucket-local build) ----
        build_csr(ui_rows, ui_cols, ui_vals, NE_UI, N_USERS, ui_ptr, ui_e, bcnt, boffs, cursor, bucketed, stream);
        build_csr(iu_rows, iu_cols, iu_vals, NE_UI, N_ITEMS, iu_ptr, iu_e, bcnt, boffs, cursor, bucketed, stream);
        build_csr(uu_rows, uu_cols, uu_vals, NE_UU, N_USERS, uu_ptr, uu_e, bcnt, boffs, cursor, bucketed, stream);
        build_csr(ic_rows, ic_cols, ic_vals, NE_IC, N_ITEMS, ic_ptr, ic_e, bcnt, boffs, cursor, bucketed, stream);
        build_csr(ci_rows, ci_cols, ci_vals, NE_IC, N_CATS,  ci_ptr, ci_e, bcnt, boffs, cursor, bucketed, stream);

        int gu = (N_USERS * 64 + blk - 1) / blk;  // 4 rows (waves) per block
        int gi = (N_ITEMS * 64 + blk - 1) / blk;
        int gc = (N_CATS  * 64 + blk - 1) / blk;

        int cur = 0;
        for (int l = 0; l < N_LAYERS; ++l) {
            int nxt = cur ^ 1;
            int last = (l == N_LAYERS - 1);
            layer_two<<<gu, blk, 0, stream>>>(ui_ptr, ui_e, h_i[cur], uu_ptr, uu_e, h_u[cur],
                                              h_u[nxt], sum_u, N_USERS, inv, last);
            layer_two<<<gi, blk, 0, stream>>>(iu_ptr, iu_e, h_u[cur], ic_ptr, ic_e, h_c[cur],
                                              h_i[nxt], sum_i, N_ITEMS, inv, last);
            layer_one<<<gc, blk, 0, stream>>>(ci_ptr, ci_e, h_i[cur],
                                              h_c[nxt], out_c, N_CATS, last);
            cur = nxt;
        }
    } else {
        // ---- fallback: push-atomic fp32 path (own layout at front of ws) ----
        float* ws = (float*)d_ws;
        float* f_u[2] = { ws,               ws + NU };
        float* f_i[2] = { ws + 2 * NU,      ws + 2 * NU + NI };
        float* f_c[2] = { ws + 2 * NU + 2 * NI, ws + 2 * NU + 2 * NI + NC };
        hipMemcpyAsync(f_u[0], user_emb, NU * sizeof(float), hipMemcpyDeviceToDevice, stream);
        hipMemcpyAsync(f_i[0], item_emb, NI * sizeof(float), hipMemcpyDeviceToDevice, stream);
        hipMemcpyAsync(f_c[0], cat_emb,  NC * sizeof(float), hipMemcpyDeviceToDevice, stream);
        hipMemcpyAsync(sum_u,  user_emb, NU * sizeof(float), hipMemcpyDeviceToDevice, stream);
        hipMemcpyAsync(sum_i,  item_emb, NI * sizeof(float), hipMemcpyDeviceToDevice, stream);
        const int ew_grid = 2048;
        int cur = 0;
        for (int l = 0; l < N_LAYERS; ++l) {
            int nxt = cur ^ 1;
            hipMemsetAsync(f_u[nxt], 0, NU * sizeof(float), stream);
            hipMemsetAsync(f_i[nxt], 0, NI * sizeof(float), stream);
            hipMemsetAsync(f_c[nxt], 0, NC * sizeof(float), stream);
            spmm_edges<<<(NE_UI + 3) / 4, blk, 0, stream>>>(ui_rows, ui_cols, ui_vals, f_i[cur], f_u[nxt], NE_UI);
            spmm_edges<<<(NE_UU + 3) / 4, blk, 0, stream>>>(uu_rows, uu_cols, uu_vals, f_u[cur], f_u[nxt], NE_UU);
            spmm_edges<<<(NE_UI + 3) / 4, blk, 0, stream>>>(iu_rows, iu_cols, iu_vals, f_u[cur], f_i[nxt], NE_UI);
            spmm_edges<<<(NE_IC + 3) / 4, blk, 0, stream>>>(ic_rows, ic_cols, ic_vals, f_c[cur], f_i[nxt], NE_IC);
            spmm_edges<<<(NE_IC + 3) / 4, blk, 0, stream>>>(ci_rows, ci_cols, ci_vals, f_i[cur], f_c[nxt], NE_IC);
            accum_kernel<<<ew_grid, blk, 0, stream>>>(sum_u, f_u[nxt], (int)NU);
            accum_kernel<<<ew_grid, blk, 0, stream>>>(sum_i, f_i[nxt], (int)NI);
            cur = nxt;
        }
        scale_kernel<<<ew_grid, blk, 0, stream>>>(sum_u, (int)NU, inv);
        scale_kernel<<<ew_grid, blk, 0, stream>>>(sum_i, (int)NI, inv);
        hipMemcpyAsync(out_c, f_c[cur], NC * sizeof(float), hipMemcpyDeviceToDevice, stream);
    }
}

// Round 8
// 756.214 us; speedup vs baseline: 2.0429x; 1.4547x over previous
//
#include <hip/hip_runtime.h>

typedef unsigned int uint;
typedef unsigned short ushort;

// Problem constants (from reference)
constexpr int DIM      = 64;
constexpr int N_USERS  = 100000;
constexpr int N_ITEMS  = 50000;
constexpr int N_CATS   = 1000;
constexpr int NE_UI    = 2000000;
constexpr int NE_UU    = 1000000;
constexpr int NE_IC    = 150000;
constexpr int N_LAYERS = 3;

constexpr int CHUNK = 8192;  // edges per bucket_scatter chunk

// ---------------- bf16 helpers ----------------

__device__ __forceinline__ ushort f2bf(float f) {  // round-to-nearest-even
    uint u = __float_as_uint(f);
    u += 0x7FFFu + ((u >> 16) & 1u);
    return (ushort)(u >> 16);
}
__device__ __forceinline__ float bfl(uint u) { return __uint_as_float(u << 16); }
__device__ __forceinline__ float bfh(uint u) { return __uint_as_float(u & 0xFFFF0000u); }

__global__ void cast_to_bf16(const float* __restrict__ in, ushort* __restrict__ out, int n8) {
    int i = blockIdx.x * blockDim.x + threadIdx.x;
    int st = gridDim.x * blockDim.x;
    for (; i < n8; i += st) {
        float4 a = reinterpret_cast<const float4*>(in)[2 * i];
        float4 b = reinterpret_cast<const float4*>(in)[2 * i + 1];
        uint4 v;
        v.x = (uint)f2bf(a.x) | ((uint)f2bf(a.y) << 16);
        v.y = (uint)f2bf(a.z) | ((uint)f2bf(a.w) << 16);
        v.z = (uint)f2bf(b.x) | ((uint)f2bf(b.y) << 16);
        v.w = (uint)f2bf(b.z) | ((uint)f2bf(b.w) << 16);
        reinterpret_cast<uint4*>(out)[i] = v;
    }
}

// ---------------- CSR build (bucket-local, no per-row global atomics) ----------------

// 256 blocks only: the bcnt flush is ~240 atomics/address total (was 3000 at g=4096,
// which serialized to 110us at the L2 coherence point).
__global__ __launch_bounds__(256) void bucket_hist(const int* __restrict__ rows,
                                                   int* __restrict__ bcnt,
                                                   int shift, int ne) {
    __shared__ int lb[256];
    lb[threadIdx.x] = 0;
    __syncthreads();
    int i = blockIdx.x * blockDim.x + threadIdx.x;
    int st = gridDim.x * blockDim.x;
    for (; i < ne; i += st) atomicAdd(&lb[rows[i] >> shift], 1);
    __syncthreads();
    if (lb[threadIdx.x]) atomicAdd(&bcnt[threadIdx.x], lb[threadIdx.x]);
}

__global__ void bucket_scan(const int* __restrict__ bcnt, int* __restrict__ boffs,
                            int* __restrict__ cursor) {
    __shared__ int lds[256];
    int tid = threadIdx.x;
    int v = bcnt[tid];
    lds[tid] = v;
    __syncthreads();
    for (int off = 1; off < 256; off <<= 1) {
        int t = (tid >= off) ? lds[tid - off] : 0;
        __syncthreads();
        lds[tid] += t;
        __syncthreads();
    }
    int excl = lds[tid] - v;
    boffs[tid] = excl;
    cursor[tid] = excl;
    if (tid == 255) boffs[256] = lds[255];
}

// Level 1: LDS-staged multisplit into <=256 coarse buckets.
// Packs (local_row << 17) | col into .x (shift <= 9, col < 2^17), val bits in .y.
__global__ __launch_bounds__(256) void bucket_scatter(const int* __restrict__ rows,
                                                      const int* __restrict__ cols,
                                                      const float* __restrict__ vals,
                                                      int ne, int shift,
                                                      int* __restrict__ cursor,
                                                      int2* __restrict__ out) {
    __shared__ int2 stage[CHUNK];
    __shared__ unsigned char sb[CHUNK];
    __shared__ int hist[256], lbase[256], gbase[256], cnt[256];
    int tid = threadIdx.x;
    int nchunks = (ne + CHUNK - 1) / CHUNK;
    for (int ch = blockIdx.x; ch < nchunks; ch += gridDim.x) {
        int base = ch * CHUNK;
        int nedge = min(CHUNK, ne - base);
        hist[tid] = 0;
        __syncthreads();
        for (int k = tid; k < nedge; k += 256)
            atomicAdd(&hist[rows[base + k] >> shift], 1);
        __syncthreads();
        lbase[tid] = hist[tid];
        __syncthreads();
        for (int off = 1; off < 256; off <<= 1) {
            int t = (tid >= off) ? lbase[tid - off] : 0;
            __syncthreads();
            lbase[tid] += t;
            __syncthreads();
        }
        int excl = lbase[tid] - hist[tid];
        cnt[tid] = excl;
        gbase[tid] = hist[tid] ? atomicAdd(&cursor[tid], hist[tid]) : 0;
        lbase[tid] = excl;  // own-slot rewrite, safe
        __syncthreads();
        for (int k = tid; k < nedge; k += 256) {
            int r = rows[base + k];
            int b = r >> shift;
            int slot = atomicAdd(&cnt[b], 1);
            int lr = r - (b << shift);
            stage[slot] = make_int2((lr << 17) | cols[base + k], __float_as_int(vals[base + k]));
            sb[slot] = (unsigned char)b;
        }
        __syncthreads();
        for (int j = tid; j < nedge; j += 256) {
            int b = sb[j];
            out[gbase[b] + (j - lbase[b])] = stage[j];
        }
        __syncthreads();
    }
}

// Level 2: one block per bucket; hist + scan + ptr write + scatter, all L2-local.
__global__ __launch_bounds__(256) void bucket_finalize(const int2* __restrict__ bucketed,
                                                       const int* __restrict__ boffs,
                                                       int shift, int n_out,
                                                       int* __restrict__ ptr,
                                                       int2* __restrict__ edges) {
    __shared__ int h[512], psum[256], cur[512];
    int tid = threadIdx.x, b = blockIdx.x;
    int s = boffs[b], e = boffs[b + 1];
    int base_row = b << shift;
    int nrows_b = min(1 << shift, n_out - base_row);
    h[tid] = 0; h[tid + 256] = 0;
    __syncthreads();
    for (int j = s + tid; j < e; j += 256)
        atomicAdd(&h[(unsigned)bucketed[j].x >> 17], 1);
    __syncthreads();
    int a0 = h[2 * tid], a1 = h[2 * tid + 1];
    psum[tid] = a0 + a1;
    __syncthreads();
    for (int off = 1; off < 256; off <<= 1) {
        int t = (tid >= off) ? psum[tid - off] : 0;
        __syncthreads();
        psum[tid] += t;
        __syncthreads();
    }
    int pex = (tid == 0) ? 0 : psum[tid - 1];
    cur[2 * tid] = pex;
    cur[2 * tid + 1] = pex + a0;
    if (2 * tid < nrows_b)     ptr[base_row + 2 * tid]     = s + pex;
    if (2 * tid + 1 < nrows_b) ptr[base_row + 2 * tid + 1] = s + pex + a0;
    if (b == gridDim.x - 1 && tid == 0) ptr[n_out] = boffs[gridDim.x];
    __syncthreads();
    for (int j = s + tid; j < e; j += 256) {
        int2 w = bucketed[j];
        int lr = (unsigned)w.x >> 17;
        int slot = atomicAdd(&cur[lr], 1);
        edges[s + slot] = make_int2(w.x & 0x1FFFF, w.y);
    }
}

// ---------------- pull-style fused layer kernels (bf16 H) ----------------
// Wave: 8 edge-groups (grp=lane>>3) x 8 lanes (sub=lane&7) x 16B (8 bf16).

__device__ __forceinline__ void gather8(const int* __restrict__ ptr,
                                        const int2* __restrict__ edges,
                                        const ushort* __restrict__ H,
                                        int r, int grp, int sub, float* acc) {
    int s = ptr[r], e = ptr[r + 1];
    for (int j = s + grp; j < e; j += 8) {
        int2 ed = edges[j];
        uint4 hv = *reinterpret_cast<const uint4*>(H + (size_t)ed.x * DIM + sub * 8);
        float w = __int_as_float(ed.y);
        acc[0] = fmaf(w, bfl(hv.x), acc[0]);
        acc[1] = fmaf(w, bfh(hv.x), acc[1]);
        acc[2] = fmaf(w, bfl(hv.y), acc[2]);
        acc[3] = fmaf(w, bfh(hv.y), acc[3]);
        acc[4] = fmaf(w, bfl(hv.z), acc[4]);
        acc[5] = fmaf(w, bfh(hv.z), acc[5]);
        acc[6] = fmaf(w, bfl(hv.w), acc[6]);
        acc[7] = fmaf(w, bfh(hv.w), acc[7]);
    }
}

__device__ __forceinline__ void xreduce8(float* a) {
#pragma unroll
    for (int m = 8; m <= 32; m <<= 1)
#pragma unroll
        for (int k = 0; k < 8; ++k)
            a[k] += __shfl_xor(a[k], m);
}

__device__ __forceinline__ uint4 pack_bf8(const float* a) {
    uint4 v;
    v.x = (uint)f2bf(a[0]) | ((uint)f2bf(a[1]) << 16);
    v.y = (uint)f2bf(a[2]) | ((uint)f2bf(a[3]) << 16);
    v.z = (uint)f2bf(a[4]) | ((uint)f2bf(a[5]) << 16);
    v.w = (uint)f2bf(a[6]) | ((uint)f2bf(a[7]) << 16);
    return v;
}

// first: sum base is emb0 (fp32) instead of sum (folds the sum=emb init memcpy)
__global__ void layer_two(const int* __restrict__ pA, const int2* __restrict__ eA, const ushort* __restrict__ HA,
                          const int* __restrict__ pB, const int2* __restrict__ eB, const ushort* __restrict__ HB,
                          ushort* __restrict__ h_out, float* __restrict__ sum,
                          const float* __restrict__ emb0,
                          int nrows, float scale, int first, int last) {
    int wid  = (blockIdx.x * blockDim.x + threadIdx.x) >> 6;
    int lane = threadIdx.x & 63;
    if (wid >= nrows) return;
    int grp = lane >> 3, sub = lane & 7;
    float acc[8] = {0.f, 0.f, 0.f, 0.f, 0.f, 0.f, 0.f, 0.f};
    gather8(pA, eA, HA, wid, grp, sub, acc);
    gather8(pB, eB, HB, wid, grp, sub, acc);
    xreduce8(acc);  // all lanes hold final acc for their 8 dims
    size_t o = (size_t)wid * DIM + sub * 8;
    const float4* bp = reinterpret_cast<const float4*>((first ? emb0 : (const float*)sum) + o);
    if (last) {
        if (grp == 0) {
            float4 s0 = bp[0], s1 = bp[1];
            s0.x = (s0.x + acc[0]) * scale; s0.y = (s0.y + acc[1]) * scale;
            s0.z = (s0.z + acc[2]) * scale; s0.w = (s0.w + acc[3]) * scale;
            s1.x = (s1.x + acc[4]) * scale; s1.y = (s1.y + acc[5]) * scale;
            s1.z = (s1.z + acc[6]) * scale; s1.w = (s1.w + acc[7]) * scale;
            float4* sp = reinterpret_cast<float4*>(sum + o);
            sp[0] = s0; sp[1] = s1;
        }
    } else {
        if (grp == 0) {
            *reinterpret_cast<uint4*>(h_out + o) = pack_bf8(acc);
        } else if (grp == 1) {
            float4 s0 = bp[0], s1 = bp[1];
            s0.x += acc[0]; s0.y += acc[1]; s0.z += acc[2]; s0.w += acc[3];
            s1.x += acc[4]; s1.y += acc[5]; s1.z += acc[6]; s1.w += acc[7];
            float4* sp = reinterpret_cast<float4*>(sum + o);
            sp[0] = s0; sp[1] = s1;
        }
    }
}

__global__ void layer_one(const int* __restrict__ p, const int2* __restrict__ e,
                          const ushort* __restrict__ H,
                          ushort* __restrict__ out_bf, float* __restrict__ out_f32,
                          int nrows, int last) {
    int wid  = (blockIdx.x * blockDim.x + threadIdx.x) >> 6;
    int lane = threadIdx.x & 63;
    if (wid >= nrows) return;
    int grp = lane >> 3, sub = lane & 7;
    float acc[8] = {0.f, 0.f, 0.f, 0.f, 0.f, 0.f, 0.f, 0.f};
    gather8(p, e, H, wid, grp, sub, acc);
    xreduce8(acc);
    if (grp != 0) return;
    size_t o = (size_t)wid * DIM + sub * 8;
    if (last) {
        float4* op = reinterpret_cast<float4*>(out_f32 + o);
        op[0] = make_float4(acc[0], acc[1], acc[2], acc[3]);
        op[1] = make_float4(acc[4], acc[5], acc[6], acc[7]);
    } else {
        *reinterpret_cast<uint4*>(out_bf + o) = pack_bf8(acc);
    }
}

// ---------------- fallback (push-atomic fp32 path) ----------------

__global__ void spmm_edges(const int* __restrict__ rows, const int* __restrict__ cols,
                           const float* __restrict__ vals, const float* __restrict__ H,
                           float* __restrict__ out, int ne) {
    int tid  = blockIdx.x * blockDim.x + threadIdx.x;
    int e    = tid >> 6;
    int lane = threadIdx.x & 63;
    if (e >= ne) return;
    float x = vals[e] * H[(size_t)cols[e] * DIM + lane];
    unsafeAtomicAdd(&out[(size_t)rows[e] * DIM + lane], x);
}

__global__ void accum_kernel(float* __restrict__ sum, const float* __restrict__ h, int n) {
    int i = blockIdx.x * blockDim.x + threadIdx.x;
    int st = gridDim.x * blockDim.x;
    for (; i < n; i += st) sum[i] += h[i];
}

__global__ void scale_kernel(float* __restrict__ p, int n, float s) {
    int i = blockIdx.x * blockDim.x + threadIdx.x;
    int st = gridDim.x * blockDim.x;
    for (; i < n; i += st) p[i] *= s;
}

// ---------------- host ----------------

static int bshift(int n_out) {   // smallest shift with (n_out >> shift) < 256
    int s = 0;
    while ((n_out >> s) >= 256) ++s;
    return s;
}

static void build_csr(const int* rows, const int* cols, const float* vals, int ne, int n_out,
                      int* ptr, int2* edges,
                      int* bcnt, int* boffs, int* cursor, int2* bucketed,
                      hipStream_t stream) {
    int shift = bshift(n_out);
    hipMemsetAsync(bcnt, 0, 256 * sizeof(int), stream);
    int g = (ne + 255) / 256;
    if (g > 256) g = 256;  // cap: bcnt-flush atomics scale with g (round-7 lesson)
    bucket_hist<<<g, 256, 0, stream>>>(rows, bcnt, shift, ne);
    bucket_scan<<<1, 256, 0, stream>>>(bcnt, boffs, cursor);
    int nchunks = (ne + CHUNK - 1) / CHUNK;
    bucket_scatter<<<nchunks, 256, 0, stream>>>(rows, cols, vals, ne, shift, cursor, bucketed);
    int nb = (n_out + (1 << shift) - 1) >> shift;
    bucket_finalize<<<nb, 256, 0, stream>>>(bucketed, boffs, shift, n_out, ptr, edges);
}

extern "C" void kernel_launch(void* const* d_in, const int* in_sizes, int n_in,
                              void* d_out, int out_size, void* d_ws, size_t ws_size,
                              hipStream_t stream) {
    const float* user_emb = (const float*)d_in[0];
    const float* item_emb = (const float*)d_in[1];
    const float* cat_emb  = (const float*)d_in[2];
    const float* ui_vals  = (const float*)d_in[3];
    const float* iu_vals  = (const float*)d_in[4];
    const float* uu_vals  = (const float*)d_in[5];
    const float* ic_vals  = (const float*)d_in[6];
    const float* ci_vals  = (const float*)d_in[7];
    const int*   ui_rows  = (const int*)d_in[8];
    const int*   ui_cols  = (const int*)d_in[9];
    const int*   iu_rows  = (const int*)d_in[10];
    const int*   iu_cols  = (const int*)d_in[11];
    const int*   uu_rows  = (const int*)d_in[12];
    const int*   uu_cols  = (const int*)d_in[13];
    const int*   ic_rows  = (const int*)d_in[14];
    const int*   ic_cols  = (const int*)d_in[15];
    const int*   ci_rows  = (const int*)d_in[16];
    const int*   ci_cols  = (const int*)d_in[17];

    constexpr size_t NU = (size_t)N_USERS * DIM;  // 6,400,000
    constexpr size_t NI = (size_t)N_ITEMS * DIM;  // 3,200,000
    constexpr size_t NC = (size_t)N_CATS  * DIM;  //    64,000

    float* sum_u = (float*)d_out;
    float* sum_i = sum_u + NU;
    float* out_c = sum_i + NI;

    const int blk = 256;
    const float inv = 1.0f / (N_LAYERS + 1);

    // ---- workspace bump allocator (bytes, 16B-aligned) ----
    unsigned char* wb = (unsigned char*)d_ws;
    size_t woff = 0;
    auto take = [&](size_t bytes) -> void* {
        void* p = wb + woff;
        woff = (woff + bytes + 15) & ~(size_t)15;
        return p;
    };
    ushort* h_u[2] = { (ushort*)take(NU * 2), (ushort*)take(NU * 2) };
    ushort* h_i[2] = { (ushort*)take(NI * 2), (ushort*)take(NI * 2) };
    ushort* h_c[2] = { (ushort*)take(NC * 2), (ushort*)take(NC * 2) };
    int* ui_ptr = (int*)take(((size_t)N_USERS + 1) * 4);
    int* iu_ptr = (int*)take(((size_t)N_ITEMS + 1) * 4);
    int* uu_ptr = (int*)take(((size_t)N_USERS + 1) * 4);
    int* ic_ptr = (int*)take(((size_t)N_ITEMS + 1) * 4);
    int* ci_ptr = (int*)take(((size_t)N_CATS  + 1) * 4);
    int2* ui_e = (int2*)take((size_t)NE_UI * 8);
    int2* iu_e = (int2*)take((size_t)NE_UI * 8);
    int2* uu_e = (int2*)take((size_t)NE_UU * 8);
    int2* ic_e = (int2*)take((size_t)NE_IC * 8);
    int2* ci_e = (int2*)take((size_t)NE_IC * 8);
    int2* bucketed = (int2*)take((size_t)NE_UI * 8);  // 16 MB scratch
    int* bcnt   = (int*)take(256 * 4);
    int* boffs  = (int*)take(257 * 4);
    int* cursor = (int*)take(256 * 4);
    size_t needed_bytes = woff;  // ~98 MB

    if (ws_size >= needed_bytes) {
        // init: h0 = bf16(emb); sum-init is folded into the first layer kernels
        cast_to_bf16<<<1024, blk, 0, stream>>>(user_emb, h_u[0], (int)(NU / 8));
        cast_to_bf16<<<1024, blk, 0, stream>>>(item_emb, h_i[0], (int)(NI / 8));
        cast_to_bf16<<<64,   blk, 0, stream>>>(cat_emb,  h_c[0], (int)(NC / 8));

        // ---- build CSR once per launch (bucket-local build) ----
        build_csr(ui_rows, ui_cols, ui_vals, NE_UI, N_USERS, ui_ptr, ui_e, bcnt, boffs, cursor, bucketed, stream);
        build_csr(iu_rows, iu_cols, iu_vals, NE_UI, N_ITEMS, iu_ptr, iu_e, bcnt, boffs, cursor, bucketed, stream);
        build_csr(uu_rows, uu_cols, uu_vals, NE_UU, N_USERS, uu_ptr, uu_e, bcnt, boffs, cursor, bucketed, stream);
        build_csr(ic_rows, ic_cols, ic_vals, NE_IC, N_ITEMS, ic_ptr, ic_e, bcnt, boffs, cursor, bucketed, stream);
        build_csr(ci_rows, ci_cols, ci_vals, NE_IC, N_CATS,  ci_ptr, ci_e, bcnt, boffs, cursor, bucketed, stream);

        int gu = (N_USERS * 64 + blk - 1) / blk;  // 4 rows (waves) per block
        int gi = (N_ITEMS * 64 + blk - 1) / blk;
        int gc = (N_CATS  * 64 + blk - 1) / blk;

        int cur = 0;
        for (int l = 0; l < N_LAYERS; ++l) {
            int nxt = cur ^ 1;
            int first = (l == 0);
            int last  = (l == N_LAYERS - 1);
            layer_two<<<gu, blk, 0, stream>>>(ui_ptr, ui_e, h_i[cur], uu_ptr, uu_e, h_u[cur],
                                              h_u[nxt], sum_u, user_emb, N_USERS, inv, first, last);
            layer_two<<<gi, blk, 0, stream>>>(iu_ptr, iu_e, h_u[cur], ic_ptr, ic_e, h_c[cur],
                                              h_i[nxt], sum_i, item_emb, N_ITEMS, inv, first, last);
            layer_one<<<gc, blk, 0, stream>>>(ci_ptr, ci_e, h_i[cur],
                                              h_c[nxt], out_c, N_CATS, last);
            cur = nxt;
        }
    } else {
        // ---- fallback: push-atomic fp32 path (own layout at front of ws) ----
        float* ws = (float*)d_ws;
        float* f_u[2] = { ws,               ws + NU };
        float* f_i[2] = { ws + 2 * NU,      ws + 2 * NU + NI };
        float* f_c[2] = { ws + 2 * NU + 2 * NI, ws + 2 * NU + 2 * NI + NC };
        hipMemcpyAsync(f_u[0], user_emb, NU * sizeof(float), hipMemcpyDeviceToDevice, stream);
        hipMemcpyAsync(f_i[0], item_emb, NI * sizeof(float), hipMemcpyDeviceToDevice, stream);
        hipMemcpyAsync(f_c[0], cat_emb,  NC * sizeof(float), hipMemcpyDeviceToDevice, stream);
        hipMemcpyAsync(sum_u,  user_emb, NU * sizeof(float), hipMemcpyDeviceToDevice, stream);
        hipMemcpyAsync(sum_i,  item_emb, NI * sizeof(float), hipMemcpyDeviceToDevice, stream);
        const int ew_grid = 2048;
        int cur = 0;
        for (int l = 0; l < N_LAYERS; ++l) {
            int nxt = cur ^ 1;
            hipMemsetAsync(f_u[nxt], 0, NU * sizeof(float), stream);
            hipMemsetAsync(f_i[nxt], 0, NI * sizeof(float), stream);
            hipMemsetAsync(f_c[nxt], 0, NC * sizeof(float), stream);
            spmm_edges<<<(NE_UI + 3) / 4, blk, 0, stream>>>(ui_rows, ui_cols, ui_vals, f_i[cur], f_u[nxt], NE_UI);
            spmm_edges<<<(NE_UU + 3) / 4, blk, 0, stream>>>(uu_rows, uu_cols, uu_vals, f_u[cur], f_u[nxt], NE_UU);
            spmm_edges<<<(NE_UI + 3) / 4, blk, 0, stream>>>(iu_rows, iu_cols, iu_vals, f_u[cur], f_i[nxt], NE_UI);
            spmm_edges<<<(NE_IC + 3) / 4, blk, 0, stream>>>(ic_rows, ic_cols, ic_vals, f_c[cur], f_i[nxt], NE_IC);
            spmm_edges<<<(NE_IC + 3) / 4, blk, 0, stream>>>(ci_rows, ci_cols, ci_vals, f_i[cur], f_c[nxt], NE_IC);
            accum_kernel<<<ew_grid, blk, 0, stream>>>(sum_u, f_u[nxt], (int)NU);
            accum_kernel<<<ew_grid, blk, 0, stream>>>(sum_i, f_i[nxt], (int)NI);
            cur = nxt;
        }
        scale_kernel<<<ew_grid, blk, 0, stream>>>(sum_u, (int)NU, inv);
        scale_kernel<<<ew_grid, blk, 0, stream>>>(sum_i, (int)NI, inv);
        hipMemcpyAsync(out_c, f_c[cur], NC * sizeof(float), hipMemcpyDeviceToDevice, stream);
    }
}

// Round 9
// 541.951 us; speedup vs baseline: 2.8506x; 1.3954x over previous
//
#include <hip/hip_runtime.h>

typedef unsigned int uint;
typedef unsigned short ushort;

// Problem constants (from reference)
constexpr int DIM      = 64;
constexpr int N_USERS  = 100000;
constexpr int N_ITEMS  = 50000;
constexpr int N_CATS   = 1000;
constexpr int NE_UI    = 2000000;
constexpr int NE_UU    = 1000000;
constexpr int NE_IC    = 150000;
constexpr int N_LAYERS = 3;

// Unified row space: items [0,50K), users [50K,150K), cats [150K,151K)
constexpr int ROW_U0    = N_ITEMS;            // 50000
constexpr int ROW_C0    = N_ITEMS + N_USERS;  // 150000
constexpr int TOT_ROWS  = ROW_C0 + N_CATS;    // 151000
constexpr size_t TOT_EL = (size_t)TOT_ROWS * DIM;  // 9,664,000

constexpr int NE_USERS = NE_UI + NE_UU;  // 3,000,000 (ui + uu)
constexpr int NE_ITEMS = NE_UI + NE_IC;  // 2,150,000 (iu + ic)
constexpr int NE_CATS  = NE_IC;          //   150,000 (ci)

constexpr int SH_U = 9, SH_I = 8, SH_C = 2;             // bucket shifts
constexpr int NB_U = (N_USERS + 511) / 512;             // 196 buckets
constexpr int NB_I = (N_ITEMS + 255) / 256;             // 196
constexpr int NB_C = (N_CATS + 3) / 4;                  // 250
constexpr int CHUNK = 8192;
constexpr int CH_U = (NE_USERS + CHUNK - 1) / CHUNK;    // 367
constexpr int CH_I = (NE_ITEMS + CHUNK - 1) / CHUNK;    // 263
constexpr int CH_C = (NE_CATS  + CHUNK - 1) / CHUNK;    // 19

constexpr int COLSHIFT = 18;         // pack: (local_row << 18) | global_col
constexpr int COLMASK  = 0x3FFFF;    // global_col < 151000 < 2^18; lr < 512

// ---------------- bf16 helpers ----------------

__device__ __forceinline__ ushort f2bf(float f) {  // round-to-nearest-even
    uint u = __float_as_uint(f);
    u += 0x7FFFu + ((u >> 16) & 1u);
    return (ushort)(u >> 16);
}
__device__ __forceinline__ float bfl(uint u) { return __uint_as_float(u << 16); }
__device__ __forceinline__ float bfh(uint u) { return __uint_as_float(u & 0xFFFF0000u); }

// one kernel casts all three embeddings into the unified bf16 table
__global__ void fused_cast(const float* __restrict__ ue, const float* __restrict__ ie,
                           const float* __restrict__ ce, ushort* __restrict__ H) {
    constexpr int NI8 = (N_ITEMS * DIM) / 8;            // 400,000
    constexpr int NU8 = (N_USERS * DIM) / 8;            // 800,000
    constexpr int NC8 = (N_CATS  * DIM) / 8;            //   8,000
    constexpr int TOT8 = NI8 + NU8 + NC8;
    int i = blockIdx.x * blockDim.x + threadIdx.x;
    int st = gridDim.x * blockDim.x;
    for (; i < TOT8; i += st) {
        const float* src; int s8;
        if (i < NI8)            { src = ie; s8 = i; }
        else if (i < NI8 + NU8) { src = ue; s8 = i - NI8; }
        else                    { src = ce; s8 = i - NI8 - NU8; }
        float4 a = reinterpret_cast<const float4*>(src)[2 * s8];
        float4 b = reinterpret_cast<const float4*>(src)[2 * s8 + 1];
        uint4 v;
        v.x = (uint)f2bf(a.x) | ((uint)f2bf(a.y) << 16);
        v.y = (uint)f2bf(a.z) | ((uint)f2bf(a.w) << 16);
        v.z = (uint)f2bf(b.x) | ((uint)f2bf(b.y) << 16);
        v.w = (uint)f2bf(b.z) | ((uint)f2bf(b.w) << 16);
        reinterpret_cast<uint4*>(H)[i] = v;
    }
}

// ---------------- fused CSR build (3 relations in one pass each) ----------------

struct RelSrc {
    const int* rowsA; const int* colsA; const float* valsA; int neA; int offA;
    const int* rowsB; const int* colsB; const float* valsB; int neB; int offB;
    int shift; int n_out;
};

struct BuildParams {
    RelSrc rel[3];          // 0=users, 1=items, 2=cats
    int* bcnt;              // 3*256
    int* boffs;             // 3*257
    int* cursor;            // 3*256
    int2* bucketed[3];
    int* ptr[3];
    int2* edges[3];
};

__global__ __launch_bounds__(256) void fused_hist(BuildParams P) {
    int rel = blockIdx.x >> 8;
    int lbk = blockIdx.x & 255;
    RelSrc R = P.rel[rel];
    __shared__ int lb[256];
    lb[threadIdx.x] = 0;
    __syncthreads();
    int ne = R.neA + R.neB;
    for (int i = lbk * 256 + threadIdx.x; i < ne; i += 256 * 256) {
        int r = (i < R.neA) ? R.rowsA[i] : R.rowsB[i - R.neA];
        atomicAdd(&lb[r >> R.shift], 1);
    }
    __syncthreads();
    if (lb[threadIdx.x]) atomicAdd(&P.bcnt[rel * 256 + threadIdx.x], lb[threadIdx.x]);
}

__global__ void fused_scan(const int* __restrict__ bcnt, int* __restrict__ boffs,
                           int* __restrict__ cursor) {
    __shared__ int lds[256];
    int rel = blockIdx.x, tid = threadIdx.x;
    int v = bcnt[rel * 256 + tid];
    lds[tid] = v;
    __syncthreads();
    for (int off = 1; off < 256; off <<= 1) {
        int t = (tid >= off) ? lds[tid - off] : 0;
        __syncthreads();
        lds[tid] += t;
        __syncthreads();
    }
    int excl = lds[tid] - v;
    boffs[rel * 257 + tid] = excl;
    cursor[rel * 256 + tid] = excl;
    if (tid == 255) boffs[rel * 257 + 256] = lds[255];
}

// Level 1: LDS-staged multisplit into <=256 coarse buckets per relation.
__global__ __launch_bounds__(256) void fused_scatter(BuildParams P, int c0, int c01) {
    __shared__ int2 stage[CHUNK];
    __shared__ unsigned char sb[CHUNK];
    __shared__ int hist[256], lbase[256], gbase[256], cnt[256];
    int bid = blockIdx.x, tid = threadIdx.x;
    int rel = (bid < c0) ? 0 : ((bid < c01) ? 1 : 2);
    int ch  = bid - ((rel == 0) ? 0 : ((rel == 1) ? c0 : c01));
    RelSrc R = P.rel[rel];
    int ne = R.neA + R.neB;
    int base = ch * CHUNK;
    int nedge = min(CHUNK, ne - base);
    int* cursor = P.cursor + rel * 256;
    int2* out = P.bucketed[rel];

    hist[tid] = 0;
    __syncthreads();
    for (int k = tid; k < nedge; k += 256) {
        int gi = base + k;
        int r = (gi < R.neA) ? R.rowsA[gi] : R.rowsB[gi - R.neA];
        atomicAdd(&hist[r >> R.shift], 1);
    }
    __syncthreads();
    lbase[tid] = hist[tid];
    __syncthreads();
    for (int off = 1; off < 256; off <<= 1) {
        int t = (tid >= off) ? lbase[tid - off] : 0;
        __syncthreads();
        lbase[tid] += t;
        __syncthreads();
    }
    int excl = lbase[tid] - hist[tid];
    cnt[tid] = excl;
    gbase[tid] = hist[tid] ? atomicAdd(&cursor[tid], hist[tid]) : 0;
    lbase[tid] = excl;  // own-slot rewrite, safe
    __syncthreads();
    for (int k = tid; k < nedge; k += 256) {
        int gi = base + k;
        int r, c; float v;
        if (gi < R.neA) { r = R.rowsA[gi]; c = R.colsA[gi] + R.offA; v = R.valsA[gi]; }
        else { int q = gi - R.neA; r = R.rowsB[q]; c = R.colsB[q] + R.offB; v = R.valsB[q]; }
        int b = r >> R.shift;
        int slot = atomicAdd(&cnt[b], 1);
        int lr = r - (b << R.shift);
        stage[slot] = make_int2((lr << COLSHIFT) | c, __float_as_int(v));
        sb[slot] = (unsigned char)b;
    }
    __syncthreads();
    for (int j = tid; j < nedge; j += 256) {
        int b = sb[j];
        out[gbase[b] + (j - lbase[b])] = stage[j];
    }
}

// Level 2: one block per bucket; hist + scan + ptr write + scatter, all L2-local.
__global__ __launch_bounds__(256) void fused_finalize(BuildParams P, int nb0, int nb01,
                                                      int nbu, int nbi, int nbc) {
    __shared__ int h[512], psum[256], cur[512];
    int bg = blockIdx.x, tid = threadIdx.x;
    int rel = (bg < nb0) ? 0 : ((bg < nb01) ? 1 : 2);
    int lb  = bg - ((rel == 0) ? 0 : ((rel == 1) ? nb0 : nb01));
    int nb  = (rel == 0) ? nbu : ((rel == 1) ? nbi : nbc);
    RelSrc R = P.rel[rel];
    const int* boffs = P.boffs + rel * 257;
    const int2* bucketed = P.bucketed[rel];
    int* ptr = P.ptr[rel];
    int2* edges = P.edges[rel];

    int s = boffs[lb], e = boffs[lb + 1];
    int base_row = lb << R.shift;
    int nrows_b = min(1 << R.shift, R.n_out - base_row);
    h[tid] = 0; h[tid + 256] = 0;
    __syncthreads();
    for (int j = s + tid; j < e; j += 256)
        atomicAdd(&h[(unsigned)bucketed[j].x >> COLSHIFT], 1);
    __syncthreads();
    int a0 = h[2 * tid], a1 = h[2 * tid + 1];
    psum[tid] = a0 + a1;
    __syncthreads();
    for (int off = 1; off < 256; off <<= 1) {
        int t = (tid >= off) ? psum[tid - off] : 0;
        __syncthreads();
        psum[tid] += t;
        __syncthreads();
    }
    int pex = (tid == 0) ? 0 : psum[tid - 1];
    cur[2 * tid] = pex;
    cur[2 * tid + 1] = pex + a0;
    if (2 * tid < nrows_b)     ptr[base_row + 2 * tid]     = s + pex;
    if (2 * tid + 1 < nrows_b) ptr[base_row + 2 * tid + 1] = s + pex + a0;
    if (lb == nb - 1 && tid == 0) ptr[R.n_out] = boffs[nb];
    __syncthreads();
    for (int j = s + tid; j < e; j += 256) {
        int2 w = bucketed[j];
        int lr = (unsigned)w.x >> COLSHIFT;
        int slot = atomicAdd(&cur[lr], 1);
        edges[s + slot] = make_int2(w.x & COLMASK, w.y);
    }
}

// ---------------- fused layer kernel (all 3 node types, bf16 H) ----------------
// Wave: 8 edge-groups (grp=lane>>3) x 8 lanes (sub=lane&7) x 16B (8 bf16).

__device__ __forceinline__ void gather8(const int* __restrict__ ptr,
                                        const int2* __restrict__ edges,
                                        const ushort* __restrict__ H,
                                        int r, int grp, int sub, float* acc) {
    int s = ptr[r], e = ptr[r + 1];
    for (int j = s + grp; j < e; j += 8) {
        int2 ed = edges[j];
        uint4 hv = *reinterpret_cast<const uint4*>(H + (size_t)ed.x * DIM + sub * 8);
        float w = __int_as_float(ed.y);
        acc[0] = fmaf(w, bfl(hv.x), acc[0]);
        acc[1] = fmaf(w, bfh(hv.x), acc[1]);
        acc[2] = fmaf(w, bfl(hv.y), acc[2]);
        acc[3] = fmaf(w, bfh(hv.y), acc[3]);
        acc[4] = fmaf(w, bfl(hv.z), acc[4]);
        acc[5] = fmaf(w, bfh(hv.z), acc[5]);
        acc[6] = fmaf(w, bfl(hv.w), acc[6]);
        acc[7] = fmaf(w, bfh(hv.w), acc[7]);
    }
}

__device__ __forceinline__ void xreduce8(float* a) {
#pragma unroll
    for (int m = 8; m <= 32; m <<= 1)
#pragma unroll
        for (int k = 0; k < 8; ++k)
            a[k] += __shfl_xor(a[k], m);
}

__device__ __forceinline__ uint4 pack_bf8(const float* a) {
    uint4 v;
    v.x = (uint)f2bf(a[0]) | ((uint)f2bf(a[1]) << 16);
    v.y = (uint)f2bf(a[2]) | ((uint)f2bf(a[3]) << 16);
    v.z = (uint)f2bf(a[4]) | ((uint)f2bf(a[5]) << 16);
    v.w = (uint)f2bf(a[6]) | ((uint)f2bf(a[7]) << 16);
    return v;
}

__global__ void fused_layer(const int* __restrict__ u_ptr, const int2* __restrict__ u_e,
                            const int* __restrict__ i_ptr, const int2* __restrict__ i_e,
                            const int* __restrict__ c_ptr, const int2* __restrict__ c_e,
                            const ushort* __restrict__ Hcur, ushort* __restrict__ Hnxt,
                            float* __restrict__ sum_u, float* __restrict__ sum_i,
                            float* __restrict__ out_c,
                            const float* __restrict__ user_emb, const float* __restrict__ item_emb,
                            float scale, int first, int last) {
    int wid  = (blockIdx.x * blockDim.x + threadIdx.x) >> 6;  // global row
    int lane = threadIdx.x & 63;
    if (wid >= TOT_ROWS) return;
    int grp = lane >> 3, sub = lane & 7;
    float acc[8] = {0.f, 0.f, 0.f, 0.f, 0.f, 0.f, 0.f, 0.f};
    const int* ptr; const int2* eg; int lr;
    if (wid < ROW_U0)      { ptr = i_ptr; eg = i_e; lr = wid; }            // items
    else if (wid < ROW_C0) { ptr = u_ptr; eg = u_e; lr = wid - ROW_U0; }   // users
    else                   { ptr = c_ptr; eg = c_e; lr = wid - ROW_C0; }   // cats
    gather8(ptr, eg, Hcur, lr, grp, sub, acc);
    xreduce8(acc);  // all lanes hold final acc for their 8 dims
    size_t o = (size_t)wid * DIM + sub * 8;
    if (wid < ROW_C0) {
        float* sum; const float* emb; size_t so;
        if (wid < ROW_U0) { sum = sum_i; emb = item_emb; so = o; }
        else { sum = sum_u; emb = user_emb; so = (size_t)lr * DIM + sub * 8; }
        const float4* bp = reinterpret_cast<const float4*>((first ? emb : (const float*)sum) + so);
        if (last) {
            if (grp == 0) {
                float4 s0 = bp[0], s1 = bp[1];
                s0.x = (s0.x + acc[0]) * scale; s0.y = (s0.y + acc[1]) * scale;
                s0.z = (s0.z + acc[2]) * scale; s0.w = (s0.w + acc[3]) * scale;
                s1.x = (s1.x + acc[4]) * scale; s1.y = (s1.y + acc[5]) * scale;
                s1.z = (s1.z + acc[6]) * scale; s1.w = (s1.w + acc[7]) * scale;
                float4* sp = reinterpret_cast<float4*>(sum + so);
                sp[0] = s0; sp[1] = s1;
            }
        } else {
            if (grp == 0) {
                *reinterpret_cast<uint4*>(Hnxt + o) = pack_bf8(acc);
            } else if (grp == 1) {
                float4 s0 = bp[0], s1 = bp[1];
                s0.x += acc[0]; s0.y += acc[1]; s0.z += acc[2]; s0.w += acc[3];
                s1.x += acc[4]; s1.y += acc[5]; s1.z += acc[6]; s1.w += acc[7];
                float4* sp = reinterpret_cast<float4*>(sum + so);
                sp[0] = s0; sp[1] = s1;
            }
        }
    } else {
        if (grp != 0) return;
        if (last) {
            float4* op = reinterpret_cast<float4*>(out_c + (size_t)lr * DIM + sub * 8);
            op[0] = make_float4(acc[0], acc[1], acc[2], acc[3]);
            op[1] = make_float4(acc[4], acc[5], acc[6], acc[7]);
        } else {
            *reinterpret_cast<uint4*>(Hnxt + o) = pack_bf8(acc);
        }
    }
}

// ---------------- fallback (push-atomic fp32 path) ----------------

__global__ void spmm_edges(const int* __restrict__ rows, const int* __restrict__ cols,
                           const float* __restrict__ vals, const float* __restrict__ H,
                           float* __restrict__ out, int ne) {
    int tid  = blockIdx.x * blockDim.x + threadIdx.x;
    int e    = tid >> 6;
    int lane = threadIdx.x & 63;
    if (e >= ne) return;
    float x = vals[e] * H[(size_t)cols[e] * DIM + lane];
    unsafeAtomicAdd(&out[(size_t)rows[e] * DIM + lane], x);
}

__global__ void accum_kernel(float* __restrict__ sum, const float* __restrict__ h, int n) {
    int i = blockIdx.x * blockDim.x + threadIdx.x;
    int st = gridDim.x * blockDim.x;
    for (; i < n; i += st) sum[i] += h[i];
}

__global__ void scale_kernel(float* __restrict__ p, int n, float s) {
    int i = blockIdx.x * blockDim.x + threadIdx.x;
    int st = gridDim.x * blockDim.x;
    for (; i < n; i += st) p[i] *= s;
}

// ---------------- host ----------------

extern "C" void kernel_launch(void* const* d_in, const int* in_sizes, int n_in,
                              void* d_out, int out_size, void* d_ws, size_t ws_size,
                              hipStream_t stream) {
    const float* user_emb = (const float*)d_in[0];
    const float* item_emb = (const float*)d_in[1];
    const float* cat_emb  = (const float*)d_in[2];
    const float* ui_vals  = (const float*)d_in[3];
    const float* iu_vals  = (const float*)d_in[4];
    const float* uu_vals  = (const float*)d_in[5];
    const float* ic_vals  = (const float*)d_in[6];
    const float* ci_vals  = (const float*)d_in[7];
    const int*   ui_rows  = (const int*)d_in[8];
    const int*   ui_cols  = (const int*)d_in[9];
    const int*   iu_rows  = (const int*)d_in[10];
    const int*   iu_cols  = (const int*)d_in[11];
    const int*   uu_rows  = (const int*)d_in[12];
    const int*   uu_cols  = (const int*)d_in[13];
    const int*   ic_rows  = (const int*)d_in[14];
    const int*   ic_cols  = (const int*)d_in[15];
    const int*   ci_rows  = (const int*)d_in[16];
    const int*   ci_cols  = (const int*)d_in[17];

    constexpr size_t NU = (size_t)N_USERS * DIM;
    constexpr size_t NI = (size_t)N_ITEMS * DIM;
    constexpr size_t NC = (size_t)N_CATS  * DIM;

    float* sum_u = (float*)d_out;
    float* sum_i = sum_u + NU;
    float* out_c = sum_i + NI;

    const int blk = 256;
    const float inv = 1.0f / (N_LAYERS + 1);

    // ---- workspace bump allocator (bytes, 16B-aligned) ----
    unsigned char* wb = (unsigned char*)d_ws;
    size_t woff = 0;
    auto take = [&](size_t bytes) -> void* {
        void* p = wb + woff;
        woff = (woff + bytes + 15) & ~(size_t)15;
        return p;
    };
    ushort* Hbuf[2] = { (ushort*)take(TOT_EL * 2), (ushort*)take(TOT_EL * 2) };
    int* u_ptr = (int*)take(((size_t)N_USERS + 1) * 4);
    int* i_ptr = (int*)take(((size_t)N_ITEMS + 1) * 4);
    int* c_ptr = (int*)take(((size_t)N_CATS  + 1) * 4);
    int2* u_e = (int2*)take((size_t)NE_USERS * 8);
    int2* i_e = (int2*)take((size_t)NE_ITEMS * 8);
    int2* c_e = (int2*)take((size_t)NE_CATS  * 8);
    int2* bk_i = (int2*)take((size_t)NE_ITEMS * 8);   // items bucketed scratch
    int2* bk_c = (int2*)take((size_t)NE_CATS  * 8);   // cats bucketed scratch
    int* bcnt   = (int*)take(3 * 256 * 4);
    int* boffs  = (int*)take(3 * 257 * 4);
    int* cursor = (int*)take(3 * 256 * 4);
    size_t needed_bytes = woff;  // ~100 MB
    // users bucketed scratch (24 MB) lives in d_out (38.6 MB): written before
    // any layer kernel writes sums; every d_out element is overwritten later.
    int2* bk_u = (int2*)d_out;

    if (ws_size >= needed_bytes) {
        BuildParams P;
        P.rel[0] = { ui_rows, ui_cols, ui_vals, NE_UI, 0,
                     uu_rows, uu_cols, uu_vals, NE_UU, ROW_U0, SH_U, N_USERS };
        P.rel[1] = { iu_rows, iu_cols, iu_vals, NE_UI, ROW_U0,
                     ic_rows, ic_cols, ic_vals, NE_IC, ROW_C0, SH_I, N_ITEMS };
        P.rel[2] = { ci_rows, ci_cols, ci_vals, NE_IC, 0,
                     nullptr, nullptr, nullptr, 0, 0, SH_C, N_CATS };
        P.bcnt = bcnt; P.boffs = boffs; P.cursor = cursor;
        P.bucketed[0] = bk_u; P.bucketed[1] = bk_i; P.bucketed[2] = bk_c;
        P.ptr[0] = u_ptr; P.ptr[1] = i_ptr; P.ptr[2] = c_ptr;
        P.edges[0] = u_e; P.edges[1] = i_e; P.edges[2] = c_e;

        fused_cast<<<2048, blk, 0, stream>>>(user_emb, item_emb, cat_emb, Hbuf[0]);
        hipMemsetAsync(bcnt, 0, 3 * 256 * sizeof(int), stream);
        fused_hist<<<3 * 256, blk, 0, stream>>>(P);
        fused_scan<<<3, blk, 0, stream>>>(bcnt, boffs, cursor);
        fused_scatter<<<CH_U + CH_I + CH_C, blk, 0, stream>>>(P, CH_U, CH_U + CH_I);
        fused_finalize<<<NB_U + NB_I + NB_C, blk, 0, stream>>>(P, NB_U, NB_U + NB_I,
                                                               NB_U, NB_I, NB_C);

        int grid = (TOT_ROWS * 64 + blk - 1) / blk;  // 4 rows (waves) per block
        int cur = 0;
        for (int l = 0; l < N_LAYERS; ++l) {
            int nxt = cur ^ 1;
            fused_layer<<<grid, blk, 0, stream>>>(u_ptr, u_e, i_ptr, i_e, c_ptr, c_e,
                                                  Hbuf[cur], Hbuf[nxt],
                                                  sum_u, sum_i, out_c,
                                                  user_emb, item_emb,
                                                  inv, l == 0, l == N_LAYERS - 1);
            cur = nxt;
        }
    } else {
        // ---- fallback: push-atomic fp32 path (own layout at front of ws) ----
        float* ws = (float*)d_ws;
        float* f_u[2] = { ws,               ws + NU };
        float* f_i[2] = { ws + 2 * NU,      ws + 2 * NU + NI };
        float* f_c[2] = { ws + 2 * NU + 2 * NI, ws + 2 * NU + 2 * NI + NC };
        hipMemcpyAsync(f_u[0], user_emb, NU * sizeof(float), hipMemcpyDeviceToDevice, stream);
        hipMemcpyAsync(f_i[0], item_emb, NI * sizeof(float), hipMemcpyDeviceToDevice, stream);
        hipMemcpyAsync(f_c[0], cat_emb,  NC * sizeof(float), hipMemcpyDeviceToDevice, stream);
        hipMemcpyAsync(sum_u,  user_emb, NU * sizeof(float), hipMemcpyDeviceToDevice, stream);
        hipMemcpyAsync(sum_i,  item_emb, NI * sizeof(float), hipMemcpyDeviceToDevice, stream);
        const int ew_grid = 2048;
        int cur = 0;
        for (int l = 0; l < N_LAYERS; ++l) {
            int nxt = cur ^ 1;
            hipMemsetAsync(f_u[nxt], 0, NU * sizeof(float), stream);
            hipMemsetAsync(f_i[nxt], 0, NI * sizeof(float), stream);
            hipMemsetAsync(f_c[nxt], 0, NC * sizeof(float), stream);
            spmm_edges<<<(NE_UI + 3) / 4, blk, 0, stream>>>(ui_rows, ui_cols, ui_vals, f_i[cur], f_u[nxt], NE_UI);
            spmm_edges<<<(NE_UU + 3) / 4, blk, 0, stream>>>(uu_rows, uu_cols, uu_vals, f_u[cur], f_u[nxt], NE_UU);
            spmm_edges<<<(NE_UI + 3) / 4, blk, 0, stream>>>(iu_rows, iu_cols, iu_vals, f_u[cur], f_i[nxt], NE_UI);
            spmm_edges<<<(NE_IC + 3) / 4, blk, 0, stream>>>(ic_rows, ic_cols, ic_vals, f_c[cur], f_i[nxt], NE_IC);
            spmm_edges<<<(NE_IC + 3) / 4, blk, 0, stream>>>(ci_rows, ci_cols, ci_vals, f_i[cur], f_c[nxt], NE_IC);
            accum_kernel<<<ew_grid, blk, 0, stream>>>(sum_u, f_u[nxt], (int)NU);
            accum_kernel<<<ew_grid, blk, 0, stream>>>(sum_i, f_i[nxt], (int)NI);
            cur = nxt;
        }
        scale_kernel<<<ew_grid, blk, 0, stream>>>(sum_u, (int)NU, inv);
        scale_kernel<<<ew_grid, blk, 0, stream>>>(sum_i, (int)NI, inv);
        hipMemcpyAsync(out_c, f_c[cur], NC * sizeof(float), hipMemcpyDeviceToDevice, stream);
    }
}

// Round 10
// 471.905 us; speedup vs baseline: 3.2737x; 1.1484x over previous
//
#include <hip/hip_runtime.h>

typedef unsigned int uint;
typedef unsigned short ushort;

// Problem constants (from reference)
constexpr int DIM      = 64;
constexpr int N_USERS  = 100000;
constexpr int N_ITEMS  = 50000;
constexpr int N_CATS   = 1000;
constexpr int NE_UI    = 2000000;
constexpr int NE_UU    = 1000000;
constexpr int NE_IC    = 150000;
constexpr int N_LAYERS = 3;

// Unified row space: items [0,50K), users [50K,150K), cats [150K,151K)
constexpr int ROW_U0    = N_ITEMS;            // 50000
constexpr int ROW_C0    = N_ITEMS + N_USERS;  // 150000
constexpr int TOT_ROWS  = ROW_C0 + N_CATS;    // 151000
constexpr size_t TOT_EL = (size_t)TOT_ROWS * DIM;  // 9,664,000

constexpr int NE_USERS = NE_UI + NE_UU;  // 3,000,000 (ui + uu)
constexpr int NE_ITEMS = NE_UI + NE_IC;  // 2,150,000 (iu + ic)
constexpr int NE_CATS  = NE_IC;          //   150,000 (ci)

constexpr int SH_U = 9, SH_I = 8, SH_C = 2;             // bucket shifts
constexpr int NB_U = (N_USERS + 511) / 512;             // 196 buckets
constexpr int NB_I = (N_ITEMS + 255) / 256;             // 196
constexpr int NB_C = (N_CATS + 3) / 4;                  // 250
constexpr int CHUNK = 8192;
constexpr int CH_U = (NE_USERS + CHUNK - 1) / CHUNK;    // 367
constexpr int CH_I = (NE_ITEMS + CHUNK - 1) / CHUNK;    // 263
constexpr int CH_C = (NE_CATS  + CHUNK - 1) / CHUNK;    // 19

constexpr int COLSHIFT = 18;         // pack: (local_row << 18) | global_col
constexpr int COLMASK  = 0x3FFFF;    // global_col < 151000 < 2^18; lr < 512

constexpr int CAST_BLKS = 1024;      // blocks of fused_cast_hist doing the cast

// ---------------- bf16 helpers ----------------

__device__ __forceinline__ ushort f2bf(float f) {  // round-to-nearest-even
    uint u = __float_as_uint(f);
    u += 0x7FFFu + ((u >> 16) & 1u);
    return (ushort)(u >> 16);
}
__device__ __forceinline__ float bfl(uint u) { return __uint_as_float(u << 16); }
__device__ __forceinline__ float bfh(uint u) { return __uint_as_float(u & 0xFFFF0000u); }

// ---------------- fused CSR build (3 relations in one pass each) ----------------

struct RelSrc {
    const int* rowsA; const int* colsA; const float* valsA; int neA; int offA;
    const int* rowsB; const int* colsB; const float* valsB; int neB; int offB;
    int shift; int n_out;
};

struct BuildParams {
    RelSrc rel[3];          // 0=users, 1=items, 2=cats
    int* bcnt;              // 3*256
    int* boffs;             // 3*257
    int* cursor;            // 3*256
    int2* bucketed[3];
    int* ptr[3];
    int2* edges[3];
};

// blocks [0,CAST_BLKS): cast embeddings -> unified bf16 table
// blocks [CAST_BLKS, CAST_BLKS+3*256): 256-bin bucket histogram per relation
__global__ __launch_bounds__(256) void fused_cast_hist(BuildParams P,
                                                       const float* __restrict__ ue,
                                                       const float* __restrict__ ie,
                                                       const float* __restrict__ ce,
                                                       ushort* __restrict__ H) {
    int bid = blockIdx.x;
    if (bid < CAST_BLKS) {
        constexpr int NI8 = (N_ITEMS * DIM) / 8;
        constexpr int NU8 = (N_USERS * DIM) / 8;
        constexpr int NC8 = (N_CATS  * DIM) / 8;
        constexpr int TOT8 = NI8 + NU8 + NC8;
        int st = CAST_BLKS * 256;
        for (int i = bid * 256 + threadIdx.x; i < TOT8; i += st) {
            const float* src; int s8;
            if (i < NI8)            { src = ie; s8 = i; }
            else if (i < NI8 + NU8) { src = ue; s8 = i - NI8; }
            else                    { src = ce; s8 = i - NI8 - NU8; }
            float4 a = reinterpret_cast<const float4*>(src)[2 * s8];
            float4 b = reinterpret_cast<const float4*>(src)[2 * s8 + 1];
            uint4 v;
            v.x = (uint)f2bf(a.x) | ((uint)f2bf(a.y) << 16);
            v.y = (uint)f2bf(a.z) | ((uint)f2bf(a.w) << 16);
            v.z = (uint)f2bf(b.x) | ((uint)f2bf(b.y) << 16);
            v.w = (uint)f2bf(b.z) | ((uint)f2bf(b.w) << 16);
            reinterpret_cast<uint4*>(H)[i] = v;
        }
    } else {
        int b2 = bid - CAST_BLKS;
        int rel = b2 >> 8;
        int lbk = b2 & 255;
        RelSrc R = P.rel[rel];
        __shared__ int lb[256];
        lb[threadIdx.x] = 0;
        __syncthreads();
        int ne = R.neA + R.neB;
        for (int i = lbk * 256 + threadIdx.x; i < ne; i += 256 * 256) {
            int r = (i < R.neA) ? R.rowsA[i] : R.rowsB[i - R.neA];
            atomicAdd(&lb[r >> R.shift], 1);
        }
        __syncthreads();
        if (lb[threadIdx.x]) atomicAdd(&P.bcnt[rel * 256 + threadIdx.x], lb[threadIdx.x]);
    }
}

__global__ void fused_scan(const int* __restrict__ bcnt, int* __restrict__ boffs,
                           int* __restrict__ cursor) {
    __shared__ int lds[256];
    int rel = blockIdx.x, tid = threadIdx.x;
    int v = bcnt[rel * 256 + tid];
    lds[tid] = v;
    __syncthreads();
    for (int off = 1; off < 256; off <<= 1) {
        int t = (tid >= off) ? lds[tid - off] : 0;
        __syncthreads();
        lds[tid] += t;
        __syncthreads();
    }
    int excl = lds[tid] - v;
    boffs[rel * 257 + tid] = excl;
    cursor[rel * 256 + tid] = excl;
    if (tid == 255) boffs[rel * 257 + 256] = lds[255];
}

// Level 1: LDS-staged multisplit into <=256 coarse buckets per relation.
__global__ __launch_bounds__(256) void fused_scatter(BuildParams P, int c0, int c01) {
    __shared__ int2 stage[CHUNK];
    __shared__ unsigned char sb[CHUNK];
    __shared__ int hist[256], lbase[256], gbase[256], cnt[256];
    int bid = blockIdx.x, tid = threadIdx.x;
    int rel = (bid < c0) ? 0 : ((bid < c01) ? 1 : 2);
    int ch  = bid - ((rel == 0) ? 0 : ((rel == 1) ? c0 : c01));
    RelSrc R = P.rel[rel];
    int ne = R.neA + R.neB;
    int base = ch * CHUNK;
    int nedge = min(CHUNK, ne - base);
    int* cursor = P.cursor + rel * 256;
    int2* out = P.bucketed[rel];

    hist[tid] = 0;
    __syncthreads();
    for (int k = tid; k < nedge; k += 256) {
        int gi = base + k;
        int r = (gi < R.neA) ? R.rowsA[gi] : R.rowsB[gi - R.neA];
        atomicAdd(&hist[r >> R.shift], 1);
    }
    __syncthreads();
    lbase[tid] = hist[tid];
    __syncthreads();
    for (int off = 1; off < 256; off <<= 1) {
        int t = (tid >= off) ? lbase[tid - off] : 0;
        __syncthreads();
        lbase[tid] += t;
        __syncthreads();
    }
    int excl = lbase[tid] - hist[tid];
    cnt[tid] = excl;
    gbase[tid] = hist[tid] ? atomicAdd(&cursor[tid], hist[tid]) : 0;
    lbase[tid] = excl;  // own-slot rewrite, safe
    __syncthreads();
    for (int k = tid; k < nedge; k += 256) {
        int gi = base + k;
        int r, c; float v;
        if (gi < R.neA) { r = R.rowsA[gi]; c = R.colsA[gi] + R.offA; v = R.valsA[gi]; }
        else { int q = gi - R.neA; r = R.rowsB[q]; c = R.colsB[q] + R.offB; v = R.valsB[q]; }
        int b = r >> R.shift;
        int slot = atomicAdd(&cnt[b], 1);
        int lr = r - (b << R.shift);
        stage[slot] = make_int2((lr << COLSHIFT) | c, __float_as_int(v));
        sb[slot] = (unsigned char)b;
    }
    __syncthreads();
    for (int j = tid; j < nedge; j += 256) {
        int b = sb[j];
        out[gbase[b] + (j - lbase[b])] = stage[j];
    }
}

// Level 2: one block per bucket; hist + scan + ptr write + scatter, all L2-local.
__global__ __launch_bounds__(256) void fused_finalize(BuildParams P, int nb0, int nb01,
                                                      int nbu, int nbi, int nbc) {
    __shared__ int h[512], psum[256], cur[512];
    int bg = blockIdx.x, tid = threadIdx.x;
    int rel = (bg < nb0) ? 0 : ((bg < nb01) ? 1 : 2);
    int lb  = bg - ((rel == 0) ? 0 : ((rel == 1) ? nb0 : nb01));
    int nb  = (rel == 0) ? nbu : ((rel == 1) ? nbi : nbc);
    RelSrc R = P.rel[rel];
    const int* boffs = P.boffs + rel * 257;
    const int2* bucketed = P.bucketed[rel];
    int* ptr = P.ptr[rel];
    int2* edges = P.edges[rel];

    int s = boffs[lb], e = boffs[lb + 1];
    int base_row = lb << R.shift;
    int nrows_b = min(1 << R.shift, R.n_out - base_row);
    h[tid] = 0; h[tid + 256] = 0;
    __syncthreads();
    for (int j = s + tid; j < e; j += 256)
        atomicAdd(&h[(unsigned)bucketed[j].x >> COLSHIFT], 1);
    __syncthreads();
    int a0 = h[2 * tid], a1 = h[2 * tid + 1];
    psum[tid] = a0 + a1;
    __syncthreads();
    for (int off = 1; off < 256; off <<= 1) {
        int t = (tid >= off) ? psum[tid - off] : 0;
        __syncthreads();
        psum[tid] += t;
        __syncthreads();
    }
    int pex = (tid == 0) ? 0 : psum[tid - 1];
    cur[2 * tid] = pex;
    cur[2 * tid + 1] = pex + a0;
    if (2 * tid < nrows_b)     ptr[base_row + 2 * tid]     = s + pex;
    if (2 * tid + 1 < nrows_b) ptr[base_row + 2 * tid + 1] = s + pex + a0;
    if (lb == nb - 1 && tid == 0) ptr[R.n_out] = boffs[nb];
    __syncthreads();
    for (int j = s + tid; j < e; j += 256) {
        int2 w = bucketed[j];
        int lr = (unsigned)w.x >> COLSHIFT;
        int slot = atomicAdd(&cur[lr], 1);
        edges[s + slot] = make_int2(w.x & COLMASK, w.y);
    }
}

// ---------------- fused layer kernel (all 3 node types, bf16 H) ----------------
// Wave: 8 edge-groups (grp=lane>>3) x 8 lanes (sub=lane&7) x 16B (8 bf16).
// Inner loop unrolled x2: two independent H-gathers in flight per group
// (16 streams/wave) to hide L2-miss/L3 latency.

__device__ __forceinline__ void fma8(uint4 hv, float w, float* acc) {
    acc[0] = fmaf(w, bfl(hv.x), acc[0]);
    acc[1] = fmaf(w, bfh(hv.x), acc[1]);
    acc[2] = fmaf(w, bfl(hv.y), acc[2]);
    acc[3] = fmaf(w, bfh(hv.y), acc[3]);
    acc[4] = fmaf(w, bfl(hv.z), acc[4]);
    acc[5] = fmaf(w, bfh(hv.z), acc[5]);
    acc[6] = fmaf(w, bfl(hv.w), acc[6]);
    acc[7] = fmaf(w, bfh(hv.w), acc[7]);
}

__device__ __forceinline__ void gather8(const int* __restrict__ ptr,
                                        const int2* __restrict__ edges,
                                        const ushort* __restrict__ H,
                                        int r, int grp, int sub, float* acc) {
    int s = ptr[r], e = ptr[r + 1];
    int j = s + grp;
    for (; j + 8 < e; j += 16) {  // pair (j, j+8): both gathers issued before FMAs
        int2 e0 = edges[j];
        int2 e1 = edges[j + 8];
        uint4 h0 = *reinterpret_cast<const uint4*>(H + (size_t)e0.x * DIM + sub * 8);
        uint4 h1 = *reinterpret_cast<const uint4*>(H + (size_t)e1.x * DIM + sub * 8);
        fma8(h0, __int_as_float(e0.y), acc);
        fma8(h1, __int_as_float(e1.y), acc);
    }
    if (j < e) {
        int2 e0 = edges[j];
        uint4 h0 = *reinterpret_cast<const uint4*>(H + (size_t)e0.x * DIM + sub * 8);
        fma8(h0, __int_as_float(e0.y), acc);
    }
}

__device__ __forceinline__ void xreduce8(float* a) {
#pragma unroll
    for (int m = 8; m <= 32; m <<= 1)
#pragma unroll
        for (int k = 0; k < 8; ++k)
            a[k] += __shfl_xor(a[k], m);
}

__device__ __forceinline__ uint4 pack_bf8(const float* a) {
    uint4 v;
    v.x = (uint)f2bf(a[0]) | ((uint)f2bf(a[1]) << 16);
    v.y = (uint)f2bf(a[2]) | ((uint)f2bf(a[3]) << 16);
    v.z = (uint)f2bf(a[4]) | ((uint)f2bf(a[5]) << 16);
    v.w = (uint)f2bf(a[6]) | ((uint)f2bf(a[7]) << 16);
    return v;
}

__global__ void fused_layer(const int* __restrict__ u_ptr, const int2* __restrict__ u_e,
                            const int* __restrict__ i_ptr, const int2* __restrict__ i_e,
                            const int* __restrict__ c_ptr, const int2* __restrict__ c_e,
                            const ushort* __restrict__ Hcur, ushort* __restrict__ Hnxt,
                            float* __restrict__ sum_u, float* __restrict__ sum_i,
                            float* __restrict__ out_c,
                            const float* __restrict__ user_emb, const float* __restrict__ item_emb,
                            float scale, int first, int last) {
    int wid  = (blockIdx.x * blockDim.x + threadIdx.x) >> 6;  // global row
    int lane = threadIdx.x & 63;
    if (wid >= TOT_ROWS) return;
    int grp = lane >> 3, sub = lane & 7;
    float acc[8] = {0.f, 0.f, 0.f, 0.f, 0.f, 0.f, 0.f, 0.f};
    const int* ptr; const int2* eg; int lr;
    if (wid < ROW_U0)      { ptr = i_ptr; eg = i_e; lr = wid; }            // items
    else if (wid < ROW_C0) { ptr = u_ptr; eg = u_e; lr = wid - ROW_U0; }   // users
    else                   { ptr = c_ptr; eg = c_e; lr = wid - ROW_C0; }   // cats
    gather8(ptr, eg, Hcur, lr, grp, sub, acc);
    xreduce8(acc);  // all lanes hold final acc for their 8 dims
    size_t o = (size_t)wid * DIM + sub * 8;
    if (wid < ROW_C0) {
        float* sum; const float* emb; size_t so;
        if (wid < ROW_U0) { sum = sum_i; emb = item_emb; so = o; }
        else { sum = sum_u; emb = user_emb; so = (size_t)lr * DIM + sub * 8; }
        const float4* bp = reinterpret_cast<const float4*>((first ? emb : (const float*)sum) + so);
        if (last) {
            if (grp == 0) {
                float4 s0 = bp[0], s1 = bp[1];
                s0.x = (s0.x + acc[0]) * scale; s0.y = (s0.y + acc[1]) * scale;
                s0.z = (s0.z + acc[2]) * scale; s0.w = (s0.w + acc[3]) * scale;
                s1.x = (s1.x + acc[4]) * scale; s1.y = (s1.y + acc[5]) * scale;
                s1.z = (s1.z + acc[6]) * scale; s1.w = (s1.w + acc[7]) * scale;
                float4* sp = reinterpret_cast<float4*>(sum + so);
                sp[0] = s0; sp[1] = s1;
            }
        } else {
            if (grp == 0) {
                *reinterpret_cast<uint4*>(Hnxt + o) = pack_bf8(acc);
            } else if (grp == 1) {
                float4 s0 = bp[0], s1 = bp[1];
                s0.x += acc[0]; s0.y += acc[1]; s0.z += acc[2]; s0.w += acc[3];
                s1.x += acc[4]; s1.y += acc[5]; s1.z += acc[6]; s1.w += acc[7];
                float4* sp = reinterpret_cast<float4*>(sum + so);
                sp[0] = s0; sp[1] = s1;
            }
        }
    } else {
        if (grp != 0) return;
        if (last) {
            float4* op = reinterpret_cast<float4*>(out_c + (size_t)lr * DIM + sub * 8);
            op[0] = make_float4(acc[0], acc[1], acc[2], acc[3]);
            op[1] = make_float4(acc[4], acc[5], acc[6], acc[7]);
        } else {
            *reinterpret_cast<uint4*>(Hnxt + o) = pack_bf8(acc);
        }
    }
}

// ---------------- fallback (push-atomic fp32 path) ----------------

__global__ void spmm_edges(const int* __restrict__ rows, const int* __restrict__ cols,
                           const float* __restrict__ vals, const float* __restrict__ H,
                           float* __restrict__ out, int ne) {
    int tid  = blockIdx.x * blockDim.x + threadIdx.x;
    int e    = tid >> 6;
    int lane = threadIdx.x & 63;
    if (e >= ne) return;
    float x = vals[e] * H[(size_t)cols[e] * DIM + lane];
    unsafeAtomicAdd(&out[(size_t)rows[e] * DIM + lane], x);
}

__global__ void accum_kernel(float* __restrict__ sum, const float* __restrict__ h, int n) {
    int i = blockIdx.x * blockDim.x + threadIdx.x;
    int st = gridDim.x * blockDim.x;
    for (; i < n; i += st) sum[i] += h[i];
}

__global__ void scale_kernel(float* __restrict__ p, int n, float s) {
    int i = blockIdx.x * blockDim.x + threadIdx.x;
    int st = gridDim.x * blockDim.x;
    for (; i < n; i += st) p[i] *= s;
}

// ---------------- host ----------------

extern "C" void kernel_launch(void* const* d_in, const int* in_sizes, int n_in,
                              void* d_out, int out_size, void* d_ws, size_t ws_size,
                              hipStream_t stream) {
    const float* user_emb = (const float*)d_in[0];
    const float* item_emb = (const float*)d_in[1];
    const float* cat_emb  = (const float*)d_in[2];
    const float* ui_vals  = (const float*)d_in[3];
    const float* iu_vals  = (const float*)d_in[4];
    const float* uu_vals  = (const float*)d_in[5];
    const float* ic_vals  = (const float*)d_in[6];
    const float* ci_vals  = (const float*)d_in[7];
    const int*   ui_rows  = (const int*)d_in[8];
    const int*   ui_cols  = (const int*)d_in[9];
    const int*   iu_rows  = (const int*)d_in[10];
    const int*   iu_cols  = (const int*)d_in[11];
    const int*   uu_rows  = (const int*)d_in[12];
    const int*   uu_cols  = (const int*)d_in[13];
    const int*   ic_rows  = (const int*)d_in[14];
    const int*   ic_cols  = (const int*)d_in[15];
    const int*   ci_rows  = (const int*)d_in[16];
    const int*   ci_cols  = (const int*)d_in[17];

    constexpr size_t NU = (size_t)N_USERS * DIM;
    constexpr size_t NI = (size_t)N_ITEMS * DIM;
    constexpr size_t NC = (size_t)N_CATS  * DIM;

    float* sum_u = (float*)d_out;
    float* sum_i = sum_u + NU;
    float* out_c = sum_i + NI;

    const int blk = 256;
    const float inv = 1.0f / (N_LAYERS + 1);

    // ---- workspace bump allocator (bytes, 16B-aligned) ----
    unsigned char* wb = (unsigned char*)d_ws;
    size_t woff = 0;
    auto take = [&](size_t bytes) -> void* {
        void* p = wb + woff;
        woff = (woff + bytes + 15) & ~(size_t)15;
        return p;
    };
    ushort* Hbuf[2] = { (ushort*)take(TOT_EL * 2), (ushort*)take(TOT_EL * 2) };
    int* u_ptr = (int*)take(((size_t)N_USERS + 1) * 4);
    int* i_ptr = (int*)take(((size_t)N_ITEMS + 1) * 4);
    int* c_ptr = (int*)take(((size_t)N_CATS  + 1) * 4);
    int2* u_e = (int2*)take((size_t)NE_USERS * 8);
    int2* i_e = (int2*)take((size_t)NE_ITEMS * 8);
    int2* c_e = (int2*)take((size_t)NE_CATS  * 8);
    int2* bk_i = (int2*)take((size_t)NE_ITEMS * 8);   // items bucketed scratch
    int2* bk_c = (int2*)take((size_t)NE_CATS  * 8);   // cats bucketed scratch
    int* bcnt   = (int*)take(3 * 256 * 4);
    int* boffs  = (int*)take(3 * 257 * 4);
    int* cursor = (int*)take(3 * 256 * 4);
    size_t needed_bytes = woff;  // ~100 MB
    // users bucketed scratch (24 MB) lives in d_out (38.6 MB): written before
    // any layer kernel writes sums; every d_out element is overwritten later.
    int2* bk_u = (int2*)d_out;

    if (ws_size >= needed_bytes) {
        BuildParams P;
        P.rel[0] = { ui_rows, ui_cols, ui_vals, NE_UI, 0,
                     uu_rows, uu_cols, uu_vals, NE_UU, ROW_U0, SH_U, N_USERS };
        P.rel[1] = { iu_rows, iu_cols, iu_vals, NE_UI, ROW_U0,
                     ic_rows, ic_cols, ic_vals, NE_IC, ROW_C0, SH_I, N_ITEMS };
        P.rel[2] = { ci_rows, ci_cols, ci_vals, NE_IC, 0,
                     nullptr, nullptr, nullptr, 0, 0, SH_C, N_CATS };
        P.bcnt = bcnt; P.boffs = boffs; P.cursor = cursor;
        P.bucketed[0] = bk_u; P.bucketed[1] = bk_i; P.bucketed[2] = bk_c;
        P.ptr[0] = u_ptr; P.ptr[1] = i_ptr; P.ptr[2] = c_ptr;
        P.edges[0] = u_e; P.edges[1] = i_e; P.edges[2] = c_e;

        hipMemsetAsync(bcnt, 0, 3 * 256 * sizeof(int), stream);
        fused_cast_hist<<<CAST_BLKS + 3 * 256, blk, 0, stream>>>(P, user_emb, item_emb,
                                                                 cat_emb, Hbuf[0]);
        fused_scan<<<3, blk, 0, stream>>>(bcnt, boffs, cursor);
        fused_scatter<<<CH_U + CH_I + CH_C, blk, 0, stream>>>(P, CH_U, CH_U + CH_I);
        fused_finalize<<<NB_U + NB_I + NB_C, blk, 0, stream>>>(P, NB_U, NB_U + NB_I,
                                                               NB_U, NB_I, NB_C);

        int grid = (TOT_ROWS * 64 + blk - 1) / blk;  // 4 rows (waves) per block
        int cur = 0;
        for (int l = 0; l < N_LAYERS; ++l) {
            int nxt = cur ^ 1;
            fused_layer<<<grid, blk, 0, stream>>>(u_ptr, u_e, i_ptr, i_e, c_ptr, c_e,
                                                  Hbuf[cur], Hbuf[nxt],
                                                  sum_u, sum_i, out_c,
                                                  user_emb, item_emb,
                                                  inv, l == 0, l == N_LAYERS - 1);
            cur = nxt;
        }
    } else {
        // ---- fallback: push-atomic fp32 path (own layout at front of ws) ----
        float* ws = (float*)d_ws;
        float* f_u[2] = { ws,               ws + NU };
        float* f_i[2] = { ws + 2 * NU,      ws + 2 * NU + NI };
        float* f_c[2] = { ws + 2 * NU + 2 * NI, ws + 2 * NU + 2 * NI + NC };
        hipMemcpyAsync(f_u[0], user_emb, NU * sizeof(float), hipMemcpyDeviceToDevice, stream);
        hipMemcpyAsync(f_i[0], item_emb, NI * sizeof(float), hipMemcpyDeviceToDevice, stream);
        hipMemcpyAsync(f_c[0], cat_emb,  NC * sizeof(float), hipMemcpyDeviceToDevice, stream);
        hipMemcpyAsync(sum_u,  user_emb, NU * sizeof(float), hipMemcpyDeviceToDevice, stream);
        hipMemcpyAsync(sum_i,  item_emb, NI * sizeof(float), hipMemcpyDeviceToDevice, stream);
        const int ew_grid = 2048;
        int cur = 0;
        for (int l = 0; l < N_LAYERS; ++l) {
            int nxt = cur ^ 1;
            hipMemsetAsync(f_u[nxt], 0, NU * sizeof(float), stream);
            hipMemsetAsync(f_i[nxt], 0, NI * sizeof(float), stream);
            hipMemsetAsync(f_c[nxt], 0, NC * sizeof(float), stream);
            spmm_edges<<<(NE_UI + 3) / 4, blk, 0, stream>>>(ui_rows, ui_cols, ui_vals, f_i[cur], f_u[nxt], NE_UI);
            spmm_edges<<<(NE_UU + 3) / 4, blk, 0, stream>>>(uu_rows, uu_cols, uu_vals, f_u[cur], f_u[nxt], NE_UU);
            spmm_edges<<<(NE_UI + 3) / 4, blk, 0, stream>>>(iu_rows, iu_cols, iu_vals, f_u[cur], f_i[nxt], NE_UI);
            spmm_edges<<<(NE_IC + 3) / 4, blk, 0, stream>>>(ic_rows, ic_cols, ic_vals, f_c[cur], f_i[nxt], NE_IC);
            spmm_edges<<<(NE_IC + 3) / 4, blk, 0, stream>>>(ci_rows, ci_cols, ci_vals, f_i[cur], f_c[nxt], NE_IC);
            accum_kernel<<<ew_grid, blk, 0, stream>>>(sum_u, f_u[nxt], (int)NU);
            accum_kernel<<<ew_grid, blk, 0, stream>>>(sum_i, f_i[nxt], (int)NI);
            cur = nxt;
        }
        scale_kernel<<<ew_grid, blk, 0, stream>>>(sum_u, (int)NU, inv);
        scale_kernel<<<ew_grid, blk, 0, stream>>>(sum_i, (int)NI, inv);
        hipMemcpyAsync(out_c, f_c[cur], NC * sizeof(float), hipMemcpyDeviceToDevice, stream);
    }
}

// Round 11
// 433.004 us; speedup vs baseline: 3.5678x; 1.0898x over previous
//
#include <hip/hip_runtime.h>

typedef unsigned int uint;
typedef unsigned short ushort;

// Problem constants (from reference)
constexpr int DIM      = 64;
constexpr int N_USERS  = 100000;
constexpr int N_ITEMS  = 50000;
constexpr int N_CATS   = 1000;
constexpr int NE_UI    = 2000000;
constexpr int NE_UU    = 1000000;
constexpr int NE_IC    = 150000;
constexpr int N_LAYERS = 3;

// Unified row space: items [0,50K), users [50K,150K), cats [150K,151K)
constexpr int ROW_U0    = N_ITEMS;            // 50000
constexpr int ROW_C0    = N_ITEMS + N_USERS;  // 150000
constexpr int TOT_ROWS  = ROW_C0 + N_CATS;    // 151000
constexpr size_t TOT_EL = (size_t)TOT_ROWS * DIM;  // 9,664,000

constexpr int NE_USERS = NE_UI + NE_UU;  // 3,000,000 (ui + uu)
constexpr int NE_ITEMS = NE_UI + NE_IC;  // 2,150,000 (iu + ic)
constexpr int NE_CATS  = NE_IC;          //   150,000 (ci)

constexpr int SH_U = 9, SH_I = 8, SH_C = 2;             // bucket shifts
constexpr int NB_U = (N_USERS + 511) / 512;             // 196 buckets
constexpr int NB_I = (N_ITEMS + 255) / 256;             // 196
constexpr int NB_C = (N_CATS + 3) / 4;                  // 250
constexpr int CHUNK = 8192;
constexpr int CH_U = (NE_USERS + CHUNK - 1) / CHUNK;    // 367
constexpr int CH_I = (NE_ITEMS + CHUNK - 1) / CHUNK;    // 263
constexpr int CH_C = (NE_CATS  + CHUNK - 1) / CHUNK;    // 19

constexpr int COLSHIFT = 18;         // pack: (local_row << 18) | global_col
constexpr int COLMASK  = 0x3FFFF;    // global_col < 151000 < 2^18; lr < 512

constexpr int CAST_BLKS = 1024;      // blocks of fused_cast_hist doing the cast

// ---------------- bf16 helpers ----------------

__device__ __forceinline__ ushort f2bf(float f) {  // round-to-nearest-even
    uint u = __float_as_uint(f);
    u += 0x7FFFu + ((u >> 16) & 1u);
    return (ushort)(u >> 16);
}
__device__ __forceinline__ float bfl(uint u) { return __uint_as_float(u << 16); }
__device__ __forceinline__ float bfh(uint u) { return __uint_as_float(u & 0xFFFF0000u); }

// ---------------- fused CSR build (3 relations in one pass each) ----------------

struct RelSrc {
    const int* rowsA; const int* colsA; const float* valsA; int neA; int offA;
    const int* rowsB; const int* colsB; const float* valsB; int neB; int offB;
    int shift; int n_out;
};

struct BuildParams {
    RelSrc rel[3];          // 0=users, 1=items, 2=cats
    int* bcnt;              // 3*256
    int* boffs;             // 3*257
    int* cursor;            // 3*256
    int2* bucketed[3];
    int* ptr[3];
    int2* edges[3];
};

// blocks [0,CAST_BLKS): cast embeddings -> unified bf16 table
// blocks [CAST_BLKS, CAST_BLKS+3*256): 256-bin bucket histogram per relation
__global__ __launch_bounds__(256) void fused_cast_hist(BuildParams P,
                                                       const float* __restrict__ ue,
                                                       const float* __restrict__ ie,
                                                       const float* __restrict__ ce,
                                                       ushort* __restrict__ H) {
    int bid = blockIdx.x;
    if (bid < CAST_BLKS) {
        constexpr int NI8 = (N_ITEMS * DIM) / 8;
        constexpr int NU8 = (N_USERS * DIM) / 8;
        constexpr int NC8 = (N_CATS  * DIM) / 8;
        constexpr int TOT8 = NI8 + NU8 + NC8;
        int st = CAST_BLKS * 256;
        for (int i = bid * 256 + threadIdx.x; i < TOT8; i += st) {
            const float* src; int s8;
            if (i < NI8)            { src = ie; s8 = i; }
            else if (i < NI8 + NU8) { src = ue; s8 = i - NI8; }
            else                    { src = ce; s8 = i - NI8 - NU8; }
            float4 a = reinterpret_cast<const float4*>(src)[2 * s8];
            float4 b = reinterpret_cast<const float4*>(src)[2 * s8 + 1];
            uint4 v;
            v.x = (uint)f2bf(a.x) | ((uint)f2bf(a.y) << 16);
            v.y = (uint)f2bf(a.z) | ((uint)f2bf(a.w) << 16);
            v.z = (uint)f2bf(b.x) | ((uint)f2bf(b.y) << 16);
            v.w = (uint)f2bf(b.z) | ((uint)f2bf(b.w) << 16);
            reinterpret_cast<uint4*>(H)[i] = v;
        }
    } else {
        int b2 = bid - CAST_BLKS;
        int rel = b2 >> 8;
        int lbk = b2 & 255;
        RelSrc R = P.rel[rel];
        __shared__ int lb[256];
        lb[threadIdx.x] = 0;
        __syncthreads();
        int ne = R.neA + R.neB;
        for (int i = lbk * 256 + threadIdx.x; i < ne; i += 256 * 256) {
            int r = (i < R.neA) ? R.rowsA[i] : R.rowsB[i - R.neA];
            atomicAdd(&lb[r >> R.shift], 1);
        }
        __syncthreads();
        if (lb[threadIdx.x]) atomicAdd(&P.bcnt[rel * 256 + threadIdx.x], lb[threadIdx.x]);
    }
}

__global__ void fused_scan(const int* __restrict__ bcnt, int* __restrict__ boffs,
                           int* __restrict__ cursor) {
    __shared__ int lds[256];
    int rel = blockIdx.x, tid = threadIdx.x;
    int v = bcnt[rel * 256 + tid];
    lds[tid] = v;
    __syncthreads();
    for (int off = 1; off < 256; off <<= 1) {
        int t = (tid >= off) ? lds[tid - off] : 0;
        __syncthreads();
        lds[tid] += t;
        __syncthreads();
    }
    int excl = lds[tid] - v;
    boffs[rel * 257 + tid] = excl;
    cursor[rel * 256 + tid] = excl;
    if (tid == 255) boffs[rel * 257 + 256] = lds[255];
}

// Level 1: LDS-staged multisplit into <=256 coarse buckets per relation.
// 1024 threads x 76KB LDS: 2 blocks/CU x 16 waves = 32 waves/CU (full occupancy;
// was 256 threads -> 8 waves/CU -> 14% occupancy and 110us, round-10 lesson).
__global__ __launch_bounds__(1024) void fused_scatter(BuildParams P, int c0, int c01) {
    __shared__ int2 stage[CHUNK];
    __shared__ unsigned char sb[CHUNK];
    __shared__ int hist[256], lbase[256], gbase[256], cnt[256];
    int bid = blockIdx.x, tid = threadIdx.x;
    int rel = (bid < c0) ? 0 : ((bid < c01) ? 1 : 2);
    int ch  = bid - ((rel == 0) ? 0 : ((rel == 1) ? c0 : c01));
    RelSrc R = P.rel[rel];
    int ne = R.neA + R.neB;
    int base = ch * CHUNK;
    int nedge = min(CHUNK, ne - base);
    int* cursor = P.cursor + rel * 256;
    int2* out = P.bucketed[rel];

    if (tid < 256) hist[tid] = 0;
    __syncthreads();
    for (int k = tid; k < nedge; k += 1024) {
        int gi = base + k;
        int r = (gi < R.neA) ? R.rowsA[gi] : R.rowsB[gi - R.neA];
        atomicAdd(&hist[r >> R.shift], 1);
    }
    __syncthreads();
    if (tid < 256) lbase[tid] = hist[tid];
    __syncthreads();
    for (int off = 1; off < 256; off <<= 1) {
        int t = (tid < 256 && tid >= off) ? lbase[tid - off] : 0;
        __syncthreads();
        if (tid < 256) lbase[tid] += t;
        __syncthreads();
    }
    if (tid < 256) {
        int excl = lbase[tid] - hist[tid];
        cnt[tid] = excl;
        gbase[tid] = hist[tid] ? atomicAdd(&cursor[tid], hist[tid]) : 0;
        lbase[tid] = excl;  // own-slot rewrite, safe
    }
    __syncthreads();
    for (int k = tid; k < nedge; k += 1024) {
        int gi = base + k;
        int r, c; float v;
        if (gi < R.neA) { r = R.rowsA[gi]; c = R.colsA[gi] + R.offA; v = R.valsA[gi]; }
        else { int q = gi - R.neA; r = R.rowsB[q]; c = R.colsB[q] + R.offB; v = R.valsB[q]; }
        int b = r >> R.shift;
        int slot = atomicAdd(&cnt[b], 1);
        int lr = r - (b << R.shift);
        stage[slot] = make_int2((lr << COLSHIFT) | c, __float_as_int(v));
        sb[slot] = (unsigned char)b;
    }
    __syncthreads();
    for (int j = tid; j < nedge; j += 1024) {
        int b = sb[j];
        out[gbase[b] + (j - lbase[b])] = stage[j];
    }
}

// Level 2: one block per bucket; hist + scan + ptr write + scatter, all L2-local.
__global__ __launch_bounds__(256) void fused_finalize(BuildParams P, int nb0, int nb01,
                                                      int nbu, int nbi, int nbc) {
    __shared__ int h[512], psum[256], cur[512];
    int bg = blockIdx.x, tid = threadIdx.x;
    int rel = (bg < nb0) ? 0 : ((bg < nb01) ? 1 : 2);
    int lb  = bg - ((rel == 0) ? 0 : ((rel == 1) ? nb0 : nb01));
    int nb  = (rel == 0) ? nbu : ((rel == 1) ? nbi : nbc);
    RelSrc R = P.rel[rel];
    const int* boffs = P.boffs + rel * 257;
    const int2* bucketed = P.bucketed[rel];
    int* ptr = P.ptr[rel];
    int2* edges = P.edges[rel];

    int s = boffs[lb], e = boffs[lb + 1];
    int base_row = lb << R.shift;
    int nrows_b = min(1 << R.shift, R.n_out - base_row);
    h[tid] = 0; h[tid + 256] = 0;
    __syncthreads();
    for (int j = s + tid; j < e; j += 256)
        atomicAdd(&h[(unsigned)bucketed[j].x >> COLSHIFT], 1);
    __syncthreads();
    int a0 = h[2 * tid], a1 = h[2 * tid + 1];
    psum[tid] = a0 + a1;
    __syncthreads();
    for (int off = 1; off < 256; off <<= 1) {
        int t = (tid >= off) ? psum[tid - off] : 0;
        __syncthreads();
        psum[tid] += t;
        __syncthreads();
    }
    int pex = (tid == 0) ? 0 : psum[tid - 1];
    cur[2 * tid] = pex;
    cur[2 * tid + 1] = pex + a0;
    if (2 * tid < nrows_b)     ptr[base_row + 2 * tid]     = s + pex;
    if (2 * tid + 1 < nrows_b) ptr[base_row + 2 * tid + 1] = s + pex + a0;
    if (lb == nb - 1 && tid == 0) ptr[R.n_out] = boffs[nb];
    __syncthreads();
    for (int j = s + tid; j < e; j += 256) {
        int2 w = bucketed[j];
        int lr = (unsigned)w.x >> COLSHIFT;
        int slot = atomicAdd(&cur[lr], 1);
        edges[s + slot] = make_int2(w.x & COLMASK, w.y);
    }
}

// ---------------- fused layer kernel (all 3 node types, bf16 H) ----------------
// Wave: 8 edge-groups (grp=lane>>3) x 8 lanes (sub=lane&7) x 16B (8 bf16).
// Inner loop unrolled x2: two independent H-gathers in flight per group
// (16 streams/wave) to hide L2-miss/L3 latency.

__device__ __forceinline__ void fma8(uint4 hv, float w, float* acc) {
    acc[0] = fmaf(w, bfl(hv.x), acc[0]);
    acc[1] = fmaf(w, bfh(hv.x), acc[1]);
    acc[2] = fmaf(w, bfl(hv.y), acc[2]);
    acc[3] = fmaf(w, bfh(hv.y), acc[3]);
    acc[4] = fmaf(w, bfl(hv.z), acc[4]);
    acc[5] = fmaf(w, bfh(hv.z), acc[5]);
    acc[6] = fmaf(w, bfl(hv.w), acc[6]);
    acc[7] = fmaf(w, bfh(hv.w), acc[7]);
}

__device__ __forceinline__ void gather8(const int* __restrict__ ptr,
                                        const int2* __restrict__ edges,
                                        const ushort* __restrict__ H,
                                        int r, int grp, int sub, float* acc) {
    int s = ptr[r], e = ptr[r + 1];
    int j = s + grp;
    for (; j + 8 < e; j += 16) {  // pair (j, j+8): both gathers issued before FMAs
        int2 e0 = edges[j];
        int2 e1 = edges[j + 8];
        uint4 h0 = *reinterpret_cast<const uint4*>(H + (size_t)e0.x * DIM + sub * 8);
        uint4 h1 = *reinterpret_cast<const uint4*>(H + (size_t)e1.x * DIM + sub * 8);
        fma8(h0, __int_as_float(e0.y), acc);
        fma8(h1, __int_as_float(e1.y), acc);
    }
    if (j < e) {
        int2 e0 = edges[j];
        uint4 h0 = *reinterpret_cast<const uint4*>(H + (size_t)e0.x * DIM + sub * 8);
        fma8(h0, __int_as_float(e0.y), acc);
    }
}

__device__ __forceinline__ void xreduce8(float* a) {
#pragma unroll
    for (int m = 8; m <= 32; m <<= 1)
#pragma unroll
        for (int k = 0; k < 8; ++k)
            a[k] += __shfl_xor(a[k], m);
}

__device__ __forceinline__ uint4 pack_bf8(const float* a) {
    uint4 v;
    v.x = (uint)f2bf(a[0]) | ((uint)f2bf(a[1]) << 16);
    v.y = (uint)f2bf(a[2]) | ((uint)f2bf(a[3]) << 16);
    v.z = (uint)f2bf(a[4]) | ((uint)f2bf(a[5]) << 16);
    v.w = (uint)f2bf(a[6]) | ((uint)f2bf(a[7]) << 16);
    return v;
}

__global__ void fused_layer(const int* __restrict__ u_ptr, const int2* __restrict__ u_e,
                            const int* __restrict__ i_ptr, const int2* __restrict__ i_e,
                            const int* __restrict__ c_ptr, const int2* __restrict__ c_e,
                            const ushort* __restrict__ Hcur, ushort* __restrict__ Hnxt,
                            float* __restrict__ sum_u, float* __restrict__ sum_i,
                            float* __restrict__ out_c,
                            const float* __restrict__ user_emb, const float* __restrict__ item_emb,
                            float scale, int first, int last) {
    int wid  = (blockIdx.x * blockDim.x + threadIdx.x) >> 6;  // global row
    int lane = threadIdx.x & 63;
    if (wid >= TOT_ROWS) return;
    int grp = lane >> 3, sub = lane & 7;
    float acc[8] = {0.f, 0.f, 0.f, 0.f, 0.f, 0.f, 0.f, 0.f};
    const int* ptr; const int2* eg; int lr;
    if (wid < ROW_U0)      { ptr = i_ptr; eg = i_e; lr = wid; }            // items
    else if (wid < ROW_C0) { ptr = u_ptr; eg = u_e; lr = wid - ROW_U0; }   // users
    else                   { ptr = c_ptr; eg = c_e; lr = wid - ROW_C0; }   // cats
    gather8(ptr, eg, Hcur, lr, grp, sub, acc);
    xreduce8(acc);  // all lanes hold final acc for their 8 dims
    size_t o = (size_t)wid * DIM + sub * 8;
    if (wid < ROW_C0) {
        float* sum; const float* emb; size_t so;
        if (wid < ROW_U0) { sum = sum_i; emb = item_emb; so = o; }
        else { sum = sum_u; emb = user_emb; so = (size_t)lr * DIM + sub * 8; }
        const float4* bp = reinterpret_cast<const float4*>((first ? emb : (const float*)sum) + so);
        if (last) {
            if (grp == 0) {
                float4 s0 = bp[0], s1 = bp[1];
                s0.x = (s0.x + acc[0]) * scale; s0.y = (s0.y + acc[1]) * scale;
                s0.z = (s0.z + acc[2]) * scale; s0.w = (s0.w + acc[3]) * scale;
                s1.x = (s1.x + acc[4]) * scale; s1.y = (s1.y + acc[5]) * scale;
                s1.z = (s1.z + acc[6]) * scale; s1.w = (s1.w + acc[7]) * scale;
                float4* sp = reinterpret_cast<float4*>(sum + so);
                sp[0] = s0; sp[1] = s1;
            }
        } else {
            if (grp == 0) {
                *reinterpret_cast<uint4*>(Hnxt + o) = pack_bf8(acc);
            } else if (grp == 1) {
                float4 s0 = bp[0], s1 = bp[1];
                s0.x += acc[0]; s0.y += acc[1]; s0.z += acc[2]; s0.w += acc[3];
                s1.x += acc[4]; s1.y += acc[5]; s1.z += acc[6]; s1.w += acc[7];
                float4* sp = reinterpret_cast<float4*>(sum + so);
                sp[0] = s0; sp[1] = s1;
            }
        }
    } else {
        if (grp != 0) return;
        if (last) {
            float4* op = reinterpret_cast<float4*>(out_c + (size_t)lr * DIM + sub * 8);
            op[0] = make_float4(acc[0], acc[1], acc[2], acc[3]);
            op[1] = make_float4(acc[4], acc[5], acc[6], acc[7]);
        } else {
            *reinterpret_cast<uint4*>(Hnxt + o) = pack_bf8(acc);
        }
    }
}

// ---------------- fallback (push-atomic fp32 path) ----------------

__global__ void spmm_edges(const int* __restrict__ rows, const int* __restrict__ cols,
                           const float* __restrict__ vals, const float* __restrict__ H,
                           float* __restrict__ out, int ne) {
    int tid  = blockIdx.x * blockDim.x + threadIdx.x;
    int e    = tid >> 6;
    int lane = threadIdx.x & 63;
    if (e >= ne) return;
    float x = vals[e] * H[(size_t)cols[e] * DIM + lane];
    unsafeAtomicAdd(&out[(size_t)rows[e] * DIM + lane], x);
}

__global__ void accum_kernel(float* __restrict__ sum, const float* __restrict__ h, int n) {
    int i = blockIdx.x * blockDim.x + threadIdx.x;
    int st = gridDim.x * blockDim.x;
    for (; i < n; i += st) sum[i] += h[i];
}

__global__ void scale_kernel(float* __restrict__ p, int n, float s) {
    int i = blockIdx.x * blockDim.x + threadIdx.x;
    int st = gridDim.x * blockDim.x;
    for (; i < n; i += st) p[i] *= s;
}

// ---------------- host ----------------

extern "C" void kernel_launch(void* const* d_in, const int* in_sizes, int n_in,
                              void* d_out, int out_size, void* d_ws, size_t ws_size,
                              hipStream_t stream) {
    const float* user_emb = (const float*)d_in[0];
    const float* item_emb = (const float*)d_in[1];
    const float* cat_emb  = (const float*)d_in[2];
    const float* ui_vals  = (const float*)d_in[3];
    const float* iu_vals  = (const float*)d_in[4];
    const float* uu_vals  = (const float*)d_in[5];
    const float* ic_vals  = (const float*)d_in[6];
    const float* ci_vals  = (const float*)d_in[7];
    const int*   ui_rows  = (const int*)d_in[8];
    const int*   ui_cols  = (const int*)d_in[9];
    const int*   iu_rows  = (const int*)d_in[10];
    const int*   iu_cols  = (const int*)d_in[11];
    const int*   uu_rows  = (const int*)d_in[12];
    const int*   uu_cols  = (const int*)d_in[13];
    const int*   ic_rows  = (const int*)d_in[14];
    const int*   ic_cols  = (const int*)d_in[15];
    const int*   ci_rows  = (const int*)d_in[16];
    const int*   ci_cols  = (const int*)d_in[17];

    constexpr size_t NU = (size_t)N_USERS * DIM;
    constexpr size_t NI = (size_t)N_ITEMS * DIM;
    constexpr size_t NC = (size_t)N_CATS  * DIM;

    float* sum_u = (float*)d_out;
    float* sum_i = sum_u + NU;
    float* out_c = sum_i + NI;

    const int blk = 256;
    const float inv = 1.0f / (N_LAYERS + 1);

    // ---- workspace bump allocator (bytes, 16B-aligned) ----
    unsigned char* wb = (unsigned char*)d_ws;
    size_t woff = 0;
    auto take = [&](size_t bytes) -> void* {
        void* p = wb + woff;
        woff = (woff + bytes + 15) & ~(size_t)15;
        return p;
    };
    ushort* Hbuf[2] = { (ushort*)take(TOT_EL * 2), (ushort*)take(TOT_EL * 2) };
    int* u_ptr = (int*)take(((size_t)N_USERS + 1) * 4);
    int* i_ptr = (int*)take(((size_t)N_ITEMS + 1) * 4);
    int* c_ptr = (int*)take(((size_t)N_CATS  + 1) * 4);
    int2* u_e = (int2*)take((size_t)NE_USERS * 8);
    int2* i_e = (int2*)take((size_t)NE_ITEMS * 8);
    int2* c_e = (int2*)take((size_t)NE_CATS  * 8);
    int2* bk_i = (int2*)take((size_t)NE_ITEMS * 8);   // items bucketed scratch
    int2* bk_c = (int2*)take((size_t)NE_CATS  * 8);   // cats bucketed scratch
    int* bcnt   = (int*)take(3 * 256 * 4);
    int* boffs  = (int*)take(3 * 257 * 4);
    int* cursor = (int*)take(3 * 256 * 4);
    size_t needed_bytes = woff;  // ~100 MB
    // users bucketed scratch (24 MB) lives in d_out (38.6 MB): written before
    // any layer kernel writes sums; every d_out element is overwritten later.
    int2* bk_u = (int2*)d_out;

    if (ws_size >= needed_bytes) {
        BuildParams P;
        P.rel[0] = { ui_rows, ui_cols, ui_vals, NE_UI, 0,
                     uu_rows, uu_cols, uu_vals, NE_UU, ROW_U0, SH_U, N_USERS };
        P.rel[1] = { iu_rows, iu_cols, iu_vals, NE_UI, ROW_U0,
                     ic_rows, ic_cols, ic_vals, NE_IC, ROW_C0, SH_I, N_ITEMS };
        P.rel[2] = { ci_rows, ci_cols, ci_vals, NE_IC, 0,
                     nullptr, nullptr, nullptr, 0, 0, SH_C, N_CATS };
        P.bcnt = bcnt; P.boffs = boffs; P.cursor = cursor;
        P.bucketed[0] = bk_u; P.bucketed[1] = bk_i; P.bucketed[2] = bk_c;
        P.ptr[0] = u_ptr; P.ptr[1] = i_ptr; P.ptr[2] = c_ptr;
        P.edges[0] = u_e; P.edges[1] = i_e; P.edges[2] = c_e;

        hipMemsetAsync(bcnt, 0, 3 * 256 * sizeof(int), stream);
        fused_cast_hist<<<CAST_BLKS + 3 * 256, blk, 0, stream>>>(P, user_emb, item_emb,
                                                                 cat_emb, Hbuf[0]);
        fused_scan<<<3, blk, 0, stream>>>(bcnt, boffs, cursor);
        fused_scatter<<<CH_U + CH_I + CH_C, 1024, 0, stream>>>(P, CH_U, CH_U + CH_I);
        fused_finalize<<<NB_U + NB_I + NB_C, blk, 0, stream>>>(P, NB_U, NB_U + NB_I,
                                                               NB_U, NB_I, NB_C);

        int grid = (TOT_ROWS * 64 + blk - 1) / blk;  // 4 rows (waves) per block
        int cur = 0;
        for (int l = 0; l < N_LAYERS; ++l) {
            int nxt = cur ^ 1;
            fused_layer<<<grid, blk, 0, stream>>>(u_ptr, u_e, i_ptr, i_e, c_ptr, c_e,
                                                  Hbuf[cur], Hbuf[nxt],
                                                  sum_u, sum_i, out_c,
                                                  user_emb, item_emb,
                                                  inv, l == 0, l == N_LAYERS - 1);
            cur = nxt;
        }
    } else {
        // ---- fallback: push-atomic fp32 path (own layout at front of ws) ----
        float* ws = (float*)d_ws;
        float* f_u[2] = { ws,               ws + NU };
        float* f_i[2] = { ws + 2 * NU,      ws + 2 * NU + NI };
        float* f_c[2] = { ws + 2 * NU + 2 * NI, ws + 2 * NU + 2 * NI + NC };
        hipMemcpyAsync(f_u[0], user_emb, NU * sizeof(float), hipMemcpyDeviceToDevice, stream);
        hipMemcpyAsync(f_i[0], item_emb, NI * sizeof(float), hipMemcpyDeviceToDevice, stream);
        hipMemcpyAsync(f_c[0], cat_emb,  NC * sizeof(float), hipMemcpyDeviceToDevice, stream);
        hipMemcpyAsync(sum_u,  user_emb, NU * sizeof(float), hipMemcpyDeviceToDevice, stream);
        hipMemcpyAsync(sum_i,  item_emb, NI * sizeof(float), hipMemcpyDeviceToDevice, stream);
        const int ew_grid = 2048;
        int cur = 0;
        for (int l = 0; l < N_LAYERS; ++l) {
            int nxt = cur ^ 1;
            hipMemsetAsync(f_u[nxt], 0, NU * sizeof(float), stream);
            hipMemsetAsync(f_i[nxt], 0, NI * sizeof(float), stream);
            hipMemsetAsync(f_c[nxt], 0, NC * sizeof(float), stream);
            spmm_edges<<<(NE_UI + 3) / 4, blk, 0, stream>>>(ui_rows, ui_cols, ui_vals, f_i[cur], f_u[nxt], NE_UI);
            spmm_edges<<<(NE_UU + 3) / 4, blk, 0, stream>>>(uu_rows, uu_cols, uu_vals, f_u[cur], f_u[nxt], NE_UU);
            spmm_edges<<<(NE_UI + 3) / 4, blk, 0, stream>>>(iu_rows, iu_cols, iu_vals, f_u[cur], f_i[nxt], NE_UI);
            spmm_edges<<<(NE_IC + 3) / 4, blk, 0, stream>>>(ic_rows, ic_cols, ic_vals, f_c[cur], f_i[nxt], NE_IC);
            spmm_edges<<<(NE_IC + 3) / 4, blk, 0, stream>>>(ci_rows, ci_cols, ci_vals, f_i[cur], f_c[nxt], NE_IC);
            accum_kernel<<<ew_grid, blk, 0, stream>>>(sum_u, f_u[nxt], (int)NU);
            accum_kernel<<<ew_grid, blk, 0, stream>>>(sum_i, f_i[nxt], (int)NI);
            cur = nxt;
        }
        scale_kernel<<<ew_grid, blk, 0, stream>>>(sum_u, (int)NU, inv);
        scale_kernel<<<ew_grid, blk, 0, stream>>>(sum_i, (int)NI, inv);
        hipMemcpyAsync(out_c, f_c[cur], NC * sizeof(float), hipMemcpyDeviceToDevice, stream);
    }
}

// Round 12
// 412.891 us; speedup vs baseline: 3.7416x; 1.0487x over previous
//
#include <hip/hip_runtime.h>

typedef unsigned int uint;
typedef unsigned short ushort;

// Problem constants (from reference)
constexpr int DIM      = 64;
constexpr int N_USERS  = 100000;
constexpr int N_ITEMS  = 50000;
constexpr int N_CATS   = 1000;
constexpr int NE_UI    = 2000000;
constexpr int NE_UU    = 1000000;
constexpr int NE_IC    = 150000;
constexpr int N_LAYERS = 3;

// Unified row space: items [0,50K), users [50K,150K), cats [150K,151K)
constexpr int ROW_U0    = N_ITEMS;            // 50000
constexpr int ROW_C0    = N_ITEMS + N_USERS;  // 150000
constexpr int TOT_ROWS  = ROW_C0 + N_CATS;    // 151000
constexpr size_t TOT_EL = (size_t)TOT_ROWS * DIM;  // 9,664,000

constexpr int NE_USERS = NE_UI + NE_UU;  // 3,000,000 (ui + uu)
constexpr int NE_ITEMS = NE_UI + NE_IC;  // 2,150,000 (iu + ic)
constexpr int NE_CATS  = NE_IC;          //   150,000 (ci)

constexpr int SH_U = 9, SH_I = 8, SH_C = 2;             // bucket shifts
constexpr int NB_U = (N_USERS + 511) / 512;             // 196 buckets
constexpr int NB_I = (N_ITEMS + 255) / 256;             // 196
constexpr int NB_C = (N_CATS + 3) / 4;                  // 250
constexpr int CHUNK = 8192;
constexpr int CH_U = (NE_USERS + CHUNK - 1) / CHUNK;    // 367
constexpr int CH_I = (NE_ITEMS + CHUNK - 1) / CHUNK;    // 263
constexpr int CH_C = (NE_CATS  + CHUNK - 1) / CHUNK;    // 19

constexpr int COLSHIFT = 18;         // pack: (local_row << 18) | global_col
constexpr int COLMASK  = 0x3FFFF;    // global_col < 151000 < 2^18; lr < 512

constexpr int CAST_BLKS = 1024;      // blocks of fused_cast_hist doing the cast

// ---------------- bf16 helpers ----------------

__device__ __forceinline__ ushort f2bf(float f) {  // round-to-nearest-even
    uint u = __float_as_uint(f);
    u += 0x7FFFu + ((u >> 16) & 1u);
    return (ushort)(u >> 16);
}
__device__ __forceinline__ float bfl(uint u) { return __uint_as_float(u << 16); }
__device__ __forceinline__ float bfh(uint u) { return __uint_as_float(u & 0xFFFF0000u); }

// ---------------- fused CSR build (3 relations in one pass each) ----------------

struct RelSrc {
    const int* rowsA; const int* colsA; const float* valsA; int neA; int offA;
    const int* rowsB; const int* colsB; const float* valsB; int neB; int offB;
    int shift; int n_out;
};

struct BuildParams {
    RelSrc rel[3];          // 0=users, 1=items, 2=cats
    int* bcnt;              // 3*256
    int* boffs;             // 3*257
    int* cursor;            // 3*256
    int2* bucketed[3];
    int* ptr[3];
    int2* edges[3];
};

// blocks [0,CAST_BLKS): cast embeddings -> unified bf16 table
// blocks [CAST_BLKS, CAST_BLKS+3*256): 256-bin bucket histogram per relation
__global__ __launch_bounds__(256) void fused_cast_hist(BuildParams P,
                                                       const float* __restrict__ ue,
                                                       const float* __restrict__ ie,
                                                       const float* __restrict__ ce,
                                                       ushort* __restrict__ H) {
    int bid = blockIdx.x;
    if (bid < CAST_BLKS) {
        constexpr int NI8 = (N_ITEMS * DIM) / 8;
        constexpr int NU8 = (N_USERS * DIM) / 8;
        constexpr int NC8 = (N_CATS  * DIM) / 8;
        constexpr int TOT8 = NI8 + NU8 + NC8;
        int st = CAST_BLKS * 256;
        for (int i = bid * 256 + threadIdx.x; i < TOT8; i += st) {
            const float* src; int s8;
            if (i < NI8)            { src = ie; s8 = i; }
            else if (i < NI8 + NU8) { src = ue; s8 = i - NI8; }
            else                    { src = ce; s8 = i - NI8 - NU8; }
            float4 a = reinterpret_cast<const float4*>(src)[2 * s8];
            float4 b = reinterpret_cast<const float4*>(src)[2 * s8 + 1];
            uint4 v;
            v.x = (uint)f2bf(a.x) | ((uint)f2bf(a.y) << 16);
            v.y = (uint)f2bf(a.z) | ((uint)f2bf(a.w) << 16);
            v.z = (uint)f2bf(b.x) | ((uint)f2bf(b.y) << 16);
            v.w = (uint)f2bf(b.z) | ((uint)f2bf(b.w) << 16);
            reinterpret_cast<uint4*>(H)[i] = v;
        }
    } else {
        int b2 = bid - CAST_BLKS;
        int rel = b2 >> 8;
        int lbk = b2 & 255;
        RelSrc R = P.rel[rel];
        __shared__ int lb[256];
        lb[threadIdx.x] = 0;
        __syncthreads();
        int ne = R.neA + R.neB;
        for (int i = lbk * 256 + threadIdx.x; i < ne; i += 256 * 256) {
            int r = (i < R.neA) ? R.rowsA[i] : R.rowsB[i - R.neA];
            atomicAdd(&lb[r >> R.shift], 1);
        }
        __syncthreads();
        if (lb[threadIdx.x]) atomicAdd(&P.bcnt[rel * 256 + threadIdx.x], lb[threadIdx.x]);
    }
}

__global__ void fused_scan(const int* __restrict__ bcnt, int* __restrict__ boffs,
                           int* __restrict__ cursor) {
    __shared__ int lds[256];
    int rel = blockIdx.x, tid = threadIdx.x;
    int v = bcnt[rel * 256 + tid];
    lds[tid] = v;
    __syncthreads();
    for (int off = 1; off < 256; off <<= 1) {
        int t = (tid >= off) ? lds[tid - off] : 0;
        __syncthreads();
        lds[tid] += t;
        __syncthreads();
    }
    int excl = lds[tid] - v;
    boffs[rel * 257 + tid] = excl;
    cursor[rel * 256 + tid] = excl;
    if (tid == 255) boffs[rel * 257 + 256] = lds[255];
}

// Level 1: LDS-staged multisplit into <=256 coarse buckets per relation.
// 1024 threads x 76KB LDS: 2 blocks/CU x 16 waves = 32 waves/CU (round-10 lesson).
__global__ __launch_bounds__(1024) void fused_scatter(BuildParams P, int c0, int c01) {
    __shared__ int2 stage[CHUNK];
    __shared__ unsigned char sb[CHUNK];
    __shared__ int hist[256], lbase[256], gbase[256], cnt[256];
    int bid = blockIdx.x, tid = threadIdx.x;
    int rel = (bid < c0) ? 0 : ((bid < c01) ? 1 : 2);
    int ch  = bid - ((rel == 0) ? 0 : ((rel == 1) ? c0 : c01));
    RelSrc R = P.rel[rel];
    int ne = R.neA + R.neB;
    int base = ch * CHUNK;
    int nedge = min(CHUNK, ne - base);
    int* cursor = P.cursor + rel * 256;
    int2* out = P.bucketed[rel];

    if (tid < 256) hist[tid] = 0;
    __syncthreads();
    for (int k = tid; k < nedge; k += 1024) {
        int gi = base + k;
        int r = (gi < R.neA) ? R.rowsA[gi] : R.rowsB[gi - R.neA];
        atomicAdd(&hist[r >> R.shift], 1);
    }
    __syncthreads();
    if (tid < 256) lbase[tid] = hist[tid];
    __syncthreads();
    for (int off = 1; off < 256; off <<= 1) {
        int t = (tid < 256 && tid >= off) ? lbase[tid - off] : 0;
        __syncthreads();
        if (tid < 256) lbase[tid] += t;
        __syncthreads();
    }
    if (tid < 256) {
        int excl = lbase[tid] - hist[tid];
        cnt[tid] = excl;
        gbase[tid] = hist[tid] ? atomicAdd(&cursor[tid], hist[tid]) : 0;
        lbase[tid] = excl;  // own-slot rewrite, safe
    }
    __syncthreads();
    for (int k = tid; k < nedge; k += 1024) {
        int gi = base + k;
        int r, c; float v;
        if (gi < R.neA) { r = R.rowsA[gi]; c = R.colsA[gi] + R.offA; v = R.valsA[gi]; }
        else { int q = gi - R.neA; r = R.rowsB[q]; c = R.colsB[q] + R.offB; v = R.valsB[q]; }
        int b = r >> R.shift;
        int slot = atomicAdd(&cnt[b], 1);
        int lr = r - (b << R.shift);
        stage[slot] = make_int2((lr << COLSHIFT) | c, __float_as_int(v));
        sb[slot] = (unsigned char)b;
    }
    __syncthreads();
    for (int j = tid; j < nedge; j += 1024) {
        int b = sb[j];
        out[gbase[b] + (j - lbase[b])] = stage[j];
    }
}

// Level 2: one block per bucket; hist + scan + ptr write + scatter, all L2-local.
// Final edges store .x = col * 128 (byte offset into bf16 H row) — saves the
// per-edge 64-bit address mul in the layer gather loop.
__global__ __launch_bounds__(256) void fused_finalize(BuildParams P, int nb0, int nb01,
                                                      int nbu, int nbi, int nbc) {
    __shared__ int h[512], psum[256], cur[512];
    int bg = blockIdx.x, tid = threadIdx.x;
    int rel = (bg < nb0) ? 0 : ((bg < nb01) ? 1 : 2);
    int lb  = bg - ((rel == 0) ? 0 : ((rel == 1) ? nb0 : nb01));
    int nb  = (rel == 0) ? nbu : ((rel == 1) ? nbi : nbc);
    RelSrc R = P.rel[rel];
    const int* boffs = P.boffs + rel * 257;
    const int2* bucketed = P.bucketed[rel];
    int* ptr = P.ptr[rel];
    int2* edges = P.edges[rel];

    int s = boffs[lb], e = boffs[lb + 1];
    int base_row = lb << R.shift;
    int nrows_b = min(1 << R.shift, R.n_out - base_row);
    h[tid] = 0; h[tid + 256] = 0;
    __syncthreads();
    for (int j = s + tid; j < e; j += 256)
        atomicAdd(&h[(unsigned)bucketed[j].x >> COLSHIFT], 1);
    __syncthreads();
    int a0 = h[2 * tid], a1 = h[2 * tid + 1];
    psum[tid] = a0 + a1;
    __syncthreads();
    for (int off = 1; off < 256; off <<= 1) {
        int t = (tid >= off) ? psum[tid - off] : 0;
        __syncthreads();
        psum[tid] += t;
        __syncthreads();
    }
    int pex = (tid == 0) ? 0 : psum[tid - 1];
    cur[2 * tid] = pex;
    cur[2 * tid + 1] = pex + a0;
    if (2 * tid < nrows_b)     ptr[base_row + 2 * tid]     = s + pex;
    if (2 * tid + 1 < nrows_b) ptr[base_row + 2 * tid + 1] = s + pex + a0;
    if (lb == nb - 1 && tid == 0) ptr[R.n_out] = boffs[nb];
    __syncthreads();
    for (int j = s + tid; j < e; j += 256) {
        int2 w = bucketed[j];
        int lr = (unsigned)w.x >> COLSHIFT;
        int slot = atomicAdd(&cur[lr], 1);
        edges[s + slot] = make_int2((w.x & COLMASK) << 7, w.y);
    }
}

// ---------------- fused layer kernel (all 3 node types, bf16 H) ----------------
// Wave: 8 edge-groups (grp=lane>>3) x 8 lanes (sub=lane&7) x 16B (8 bf16).
// Batched clamped gather x4: all of {j0, j0+8, j0+16, j0+24} issued at once,
// OOB slots clamped to j0 with weight 0 (exact). For the typical ~3.75
// edges/group this is straight-line code with every gather in flight.

__device__ __forceinline__ void fma8(uint4 hv, float w, float* acc) {
    acc[0] = fmaf(w, bfl(hv.x), acc[0]);
    acc[1] = fmaf(w, bfh(hv.x), acc[1]);
    acc[2] = fmaf(w, bfl(hv.y), acc[2]);
    acc[3] = fmaf(w, bfh(hv.y), acc[3]);
    acc[4] = fmaf(w, bfl(hv.z), acc[4]);
    acc[5] = fmaf(w, bfh(hv.z), acc[5]);
    acc[6] = fmaf(w, bfl(hv.w), acc[6]);
    acc[7] = fmaf(w, bfh(hv.w), acc[7]);
}

__device__ __forceinline__ void gather8(const int* __restrict__ ptr,
                                        const int2* __restrict__ edges,
                                        const ushort* __restrict__ H,
                                        int r, int grp, int sub, float* acc) {
    int s = ptr[r], e = ptr[r + 1];
    const char* Hb = (const char*)H + sub * 16;   // edges[].x is a byte offset
    for (int j0 = s + grp; j0 < e; j0 += 32) {
        int j1 = j0 + 8, j2 = j0 + 16, j3 = j0 + 24;
        int2 e0 = edges[j0];
        int2 e1 = edges[j1 < e ? j1 : j0];
        int2 e2 = edges[j2 < e ? j2 : j0];
        int2 e3 = edges[j3 < e ? j3 : j0];
        uint4 h0 = *reinterpret_cast<const uint4*>(Hb + e0.x);
        uint4 h1 = *reinterpret_cast<const uint4*>(Hb + e1.x);
        uint4 h2 = *reinterpret_cast<const uint4*>(Hb + e2.x);
        uint4 h3 = *reinterpret_cast<const uint4*>(Hb + e3.x);
        float w1 = (j1 < e) ? __int_as_float(e1.y) : 0.f;
        float w2 = (j2 < e) ? __int_as_float(e2.y) : 0.f;
        float w3 = (j3 < e) ? __int_as_float(e3.y) : 0.f;
        fma8(h0, __int_as_float(e0.y), acc);
        fma8(h1, w1, acc);
        fma8(h2, w2, acc);
        fma8(h3, w3, acc);
    }
}

__device__ __forceinline__ void xreduce8(float* a) {
#pragma unroll
    for (int m = 8; m <= 32; m <<= 1)
#pragma unroll
        for (int k = 0; k < 8; ++k)
            a[k] += __shfl_xor(a[k], m);
}

__device__ __forceinline__ uint4 pack_bf8(const float* a) {
    uint4 v;
    v.x = (uint)f2bf(a[0]) | ((uint)f2bf(a[1]) << 16);
    v.y = (uint)f2bf(a[2]) | ((uint)f2bf(a[3]) << 16);
    v.z = (uint)f2bf(a[4]) | ((uint)f2bf(a[5]) << 16);
    v.w = (uint)f2bf(a[6]) | ((uint)f2bf(a[7]) << 16);
    return v;
}

__global__ void fused_layer(const int* __restrict__ u_ptr, const int2* __restrict__ u_e,
                            const int* __restrict__ i_ptr, const int2* __restrict__ i_e,
                            const int* __restrict__ c_ptr, const int2* __restrict__ c_e,
                            const ushort* __restrict__ Hcur, ushort* __restrict__ Hnxt,
                            float* __restrict__ sum_u, float* __restrict__ sum_i,
                            float* __restrict__ out_c,
                            const float* __restrict__ user_emb, const float* __restrict__ item_emb,
                            float scale, int first, int last) {
    int wid  = (blockIdx.x * blockDim.x + threadIdx.x) >> 6;  // global row
    int lane = threadIdx.x & 63;
    if (wid >= TOT_ROWS) return;
    int grp = lane >> 3, sub = lane & 7;
    float acc[8] = {0.f, 0.f, 0.f, 0.f, 0.f, 0.f, 0.f, 0.f};
    const int* ptr; const int2* eg; int lr;
    if (wid < ROW_U0)      { ptr = i_ptr; eg = i_e; lr = wid; }            // items
    else if (wid < ROW_C0) { ptr = u_ptr; eg = u_e; lr = wid - ROW_U0; }   // users
    else                   { ptr = c_ptr; eg = c_e; lr = wid - ROW_C0; }   // cats
    gather8(ptr, eg, Hcur, lr, grp, sub, acc);
    xreduce8(acc);  // all lanes hold final acc for their 8 dims
    size_t o = (size_t)wid * DIM + sub * 8;
    if (wid < ROW_C0) {
        float* sum; const float* emb; size_t so;
        if (wid < ROW_U0) { sum = sum_i; emb = item_emb; so = o; }
        else { sum = sum_u; emb = user_emb; so = (size_t)lr * DIM + sub * 8; }
        const float4* bp = reinterpret_cast<const float4*>((first ? emb : (const float*)sum) + so);
        if (last) {
            if (grp == 0) {
                float4 s0 = bp[0], s1 = bp[1];
                s0.x = (s0.x + acc[0]) * scale; s0.y = (s0.y + acc[1]) * scale;
                s0.z = (s0.z + acc[2]) * scale; s0.w = (s0.w + acc[3]) * scale;
                s1.x = (s1.x + acc[4]) * scale; s1.y = (s1.y + acc[5]) * scale;
                s1.z = (s1.z + acc[6]) * scale; s1.w = (s1.w + acc[7]) * scale;
                float4* sp = reinterpret_cast<float4*>(sum + so);
                sp[0] = s0; sp[1] = s1;
            }
        } else {
            if (grp == 0) {
                *reinterpret_cast<uint4*>(Hnxt + o) = pack_bf8(acc);
            } else if (grp == 1) {
                float4 s0 = bp[0], s1 = bp[1];
                s0.x += acc[0]; s0.y += acc[1]; s0.z += acc[2]; s0.w += acc[3];
                s1.x += acc[4]; s1.y += acc[5]; s1.z += acc[6]; s1.w += acc[7];
                float4* sp = reinterpret_cast<float4*>(sum + so);
                sp[0] = s0; sp[1] = s1;
            }
        }
    } else {
        if (grp != 0) return;
        if (last) {
            float4* op = reinterpret_cast<float4*>(out_c + (size_t)lr * DIM + sub * 8);
            op[0] = make_float4(acc[0], acc[1], acc[2], acc[3]);
            op[1] = make_float4(acc[4], acc[5], acc[6], acc[7]);
        } else {
            *reinterpret_cast<uint4*>(Hnxt + o) = pack_bf8(acc);
        }
    }
}

// ---------------- fallback (push-atomic fp32 path) ----------------

__global__ void spmm_edges(const int* __restrict__ rows, const int* __restrict__ cols,
                           const float* __restrict__ vals, const float* __restrict__ H,
                           float* __restrict__ out, int ne) {
    int tid  = blockIdx.x * blockDim.x + threadIdx.x;
    int e    = tid >> 6;
    int lane = threadIdx.x & 63;
    if (e >= ne) return;
    float x = vals[e] * H[(size_t)cols[e] * DIM + lane];
    unsafeAtomicAdd(&out[(size_t)rows[e] * DIM + lane], x);
}

__global__ void accum_kernel(float* __restrict__ sum, const float* __restrict__ h, int n) {
    int i = blockIdx.x * blockDim.x + threadIdx.x;
    int st = gridDim.x * blockDim.x;
    for (; i < n; i += st) sum[i] += h[i];
}

__global__ void scale_kernel(float* __restrict__ p, int n, float s) {
    int i = blockIdx.x * blockDim.x + threadIdx.x;
    int st = gridDim.x * blockDim.x;
    for (; i < n; i += st) p[i] *= s;
}

// ---------------- host ----------------

extern "C" void kernel_launch(void* const* d_in, const int* in_sizes, int n_in,
                              void* d_out, int out_size, void* d_ws, size_t ws_size,
                              hipStream_t stream) {
    const float* user_emb = (const float*)d_in[0];
    const float* item_emb = (const float*)d_in[1];
    const float* cat_emb  = (const float*)d_in[2];
    const float* ui_vals  = (const float*)d_in[3];
    const float* iu_vals  = (const float*)d_in[4];
    const float* uu_vals  = (const float*)d_in[5];
    const float* ic_vals  = (const float*)d_in[6];
    const float* ci_vals  = (const float*)d_in[7];
    const int*   ui_rows  = (const int*)d_in[8];
    const int*   ui_cols  = (const int*)d_in[9];
    const int*   iu_rows  = (const int*)d_in[10];
    const int*   iu_cols  = (const int*)d_in[11];
    const int*   uu_rows  = (const int*)d_in[12];
    const int*   uu_cols  = (const int*)d_in[13];
    const int*   ic_rows  = (const int*)d_in[14];
    const int*   ic_cols  = (const int*)d_in[15];
    const int*   ci_rows  = (const int*)d_in[16];
    const int*   ci_cols  = (const int*)d_in[17];

    constexpr size_t NU = (size_t)N_USERS * DIM;
    constexpr size_t NI = (size_t)N_ITEMS * DIM;
    constexpr size_t NC = (size_t)N_CATS  * DIM;

    float* sum_u = (float*)d_out;
    float* sum_i = sum_u + NU;
    float* out_c = sum_i + NI;

    const int blk = 256;
    const float inv = 1.0f / (N_LAYERS + 1);

    // ---- workspace bump allocator (bytes, 16B-aligned) ----
    unsigned char* wb = (unsigned char*)d_ws;
    size_t woff = 0;
    auto take = [&](size_t bytes) -> void* {
        void* p = wb + woff;
        woff = (woff + bytes + 15) & ~(size_t)15;
        return p;
    };
    ushort* Hbuf[2] = { (ushort*)take(TOT_EL * 2), (ushort*)take(TOT_EL * 2) };
    int* u_ptr = (int*)take(((size_t)N_USERS + 1) * 4);
    int* i_ptr = (int*)take(((size_t)N_ITEMS + 1) * 4);
    int* c_ptr = (int*)take(((size_t)N_CATS  + 1) * 4);
    int2* u_e = (int2*)take((size_t)NE_USERS * 8);
    int2* i_e = (int2*)take((size_t)NE_ITEMS * 8);
    int2* c_e = (int2*)take((size_t)NE_CATS  * 8);
    int2* bk_i = (int2*)take((size_t)NE_ITEMS * 8);   // items bucketed scratch
    int2* bk_c = (int2*)take((size_t)NE_CATS  * 8);   // cats bucketed scratch
    int* bcnt   = (int*)take(3 * 256 * 4);
    int* boffs  = (int*)take(3 * 257 * 4);
    int* cursor = (int*)take(3 * 256 * 4);
    size_t needed_bytes = woff;  // ~100 MB
    // users bucketed scratch (24 MB) lives in d_out (38.6 MB): written before
    // any layer kernel writes sums; every d_out element is overwritten later.
    int2* bk_u = (int2*)d_out;

    if (ws_size >= needed_bytes) {
        BuildParams P;
        P.rel[0] = { ui_rows, ui_cols, ui_vals, NE_UI, 0,
                     uu_rows, uu_cols, uu_vals, NE_UU, ROW_U0, SH_U, N_USERS };
        P.rel[1] = { iu_rows, iu_cols, iu_vals, NE_UI, ROW_U0,
                     ic_rows, ic_cols, ic_vals, NE_IC, ROW_C0, SH_I, N_ITEMS };
        P.rel[2] = { ci_rows, ci_cols, ci_vals, NE_IC, 0,
                     nullptr, nullptr, nullptr, 0, 0, SH_C, N_CATS };
        P.bcnt = bcnt; P.boffs = boffs; P.cursor = cursor;
        P.bucketed[0] = bk_u; P.bucketed[1] = bk_i; P.bucketed[2] = bk_c;
        P.ptr[0] = u_ptr; P.ptr[1] = i_ptr; P.ptr[2] = c_ptr;
        P.edges[0] = u_e; P.edges[1] = i_e; P.edges[2] = c_e;

        hipMemsetAsync(bcnt, 0, 3 * 256 * sizeof(int), stream);
        fused_cast_hist<<<CAST_BLKS + 3 * 256, blk, 0, stream>>>(P, user_emb, item_emb,
                                                                 cat_emb, Hbuf[0]);
        fused_scan<<<3, blk, 0, stream>>>(bcnt, boffs, cursor);
        fused_scatter<<<CH_U + CH_I + CH_C, 1024, 0, stream>>>(P, CH_U, CH_U + CH_I);
        fused_finalize<<<NB_U + NB_I + NB_C, blk, 0, stream>>>(P, NB_U, NB_U + NB_I,
                                                               NB_U, NB_I, NB_C);

        int grid = (TOT_ROWS * 64 + blk - 1) / blk;  // 4 rows (waves) per block
        int cur = 0;
        for (int l = 0; l < N_LAYERS; ++l) {
            int nxt = cur ^ 1;
            fused_layer<<<grid, blk, 0, stream>>>(u_ptr, u_e, i_ptr, i_e, c_ptr, c_e,
                                                  Hbuf[cur], Hbuf[nxt],
                                                  sum_u, sum_i, out_c,
                                                  user_emb, item_emb,
                                                  inv, l == 0, l == N_LAYERS - 1);
            cur = nxt;
        }
    } else {
        // ---- fallback: push-atomic fp32 path (own layout at front of ws) ----
        float* ws = (float*)d_ws;
        float* f_u[2] = { ws,               ws + NU };
        float* f_i[2] = { ws + 2 * NU,      ws + 2 * NU + NI };
        float* f_c[2] = { ws + 2 * NU + 2 * NI, ws + 2 * NU + 2 * NI + NC };
        hipMemcpyAsync(f_u[0], user_emb, NU * sizeof(float), hipMemcpyDeviceToDevice, stream);
        hipMemcpyAsync(f_i[0], item_emb, NI * sizeof(float), hipMemcpyDeviceToDevice, stream);
        hipMemcpyAsync(f_c[0], cat_emb,  NC * sizeof(float), hipMemcpyDeviceToDevice, stream);
        hipMemcpyAsync(sum_u,  user_emb, NU * sizeof(float), hipMemcpyDeviceToDevice, stream);
        hipMemcpyAsync(sum_i,  item_emb, NI * sizeof(float), hipMemcpyDeviceToDevice, stream);
        const int ew_grid = 2048;
        int cur = 0;
        for (int l = 0; l < N_LAYERS; ++l) {
            int nxt = cur ^ 1;
            hipMemsetAsync(f_u[nxt], 0, NU * sizeof(float), stream);
            hipMemsetAsync(f_i[nxt], 0, NI * sizeof(float), stream);
            hipMemsetAsync(f_c[nxt], 0, NC * sizeof(float), stream);
            spmm_edges<<<(NE_UI + 3) / 4, blk, 0, stream>>>(ui_rows, ui_cols, ui_vals, f_i[cur], f_u[nxt], NE_UI);
            spmm_edges<<<(NE_UU + 3) / 4, blk, 0, stream>>>(uu_rows, uu_cols, uu_vals, f_u[cur], f_u[nxt], NE_UU);
            spmm_edges<<<(NE_UI + 3) / 4, blk, 0, stream>>>(iu_rows, iu_cols, iu_vals, f_u[cur], f_i[nxt], NE_UI);
            spmm_edges<<<(NE_IC + 3) / 4, blk, 0, stream>>>(ic_rows, ic_cols, ic_vals, f_c[cur], f_i[nxt], NE_IC);
            spmm_edges<<<(NE_IC + 3) / 4, blk, 0, stream>>>(ci_rows, ci_cols, ci_vals, f_i[cur], f_c[nxt], NE_IC);
            accum_kernel<<<ew_grid, blk, 0, stream>>>(sum_u, f_u[nxt], (int)NU);
            accum_kernel<<<ew_grid, blk, 0, stream>>>(sum_i, f_i[nxt], (int)NI);
            cur = nxt;
        }
        scale_kernel<<<ew_grid, blk, 0, stream>>>(sum_u, (int)NU, inv);
        scale_kernel<<<ew_grid, blk, 0, stream>>>(sum_i, (int)NI, inv);
        hipMemcpyAsync(out_c, f_c[cur], NC * sizeof(float), hipMemcpyDeviceToDevice, stream);
    }
}

// Round 13
// 386.572 us; speedup vs baseline: 3.9964x; 1.0681x over previous
//
#include <hip/hip_runtime.h>

typedef unsigned int uint;
typedef unsigned short ushort;

// Problem constants (from reference)
constexpr int DIM      = 64;
constexpr int N_USERS  = 100000;
constexpr int N_ITEMS  = 50000;
constexpr int N_CATS   = 1000;
constexpr int NE_UI    = 2000000;
constexpr int NE_UU    = 1000000;
constexpr int NE_IC    = 150000;
constexpr int N_LAYERS = 3;

// Unified row space: items [0,50K), users [50K,150K), cats [150K,151K)
constexpr int ROW_U0    = N_ITEMS;            // 50000
constexpr int ROW_C0    = N_ITEMS + N_USERS;  // 150000
constexpr int TOT_ROWS  = ROW_C0 + N_CATS;    // 151000
constexpr size_t TOT_EL = (size_t)TOT_ROWS * DIM;  // 9,664,000

constexpr int NE_USERS = NE_UI + NE_UU;  // 3,000,000 (ui + uu)
constexpr int NE_ITEMS = NE_UI + NE_IC;  // 2,150,000 (iu + ic)
constexpr int NE_CATS  = NE_IC;          //   150,000 (ci)

constexpr int SH_U = 9, SH_I = 8, SH_C = 2;             // bucket shifts
constexpr int NB_U = (N_USERS + 511) / 512;             // 196 buckets
constexpr int NB_I = (N_ITEMS + 255) / 256;             // 196
constexpr int NB_C = (N_CATS + 3) / 4;                  // 250
constexpr int CHUNK = 8192;
constexpr int CH_U = (NE_USERS + CHUNK - 1) / CHUNK;    // 367
constexpr int CH_I = (NE_ITEMS + CHUNK - 1) / CHUNK;    // 263
constexpr int CH_C = (NE_CATS  + CHUNK - 1) / CHUNK;    // 19

constexpr int COLSHIFT = 18;         // pack: (local_row << 18) | global_col
constexpr int COLMASK  = 0x3FFFF;    // global_col < 151000 < 2^18; lr < 512

constexpr int CAST_BLKS = 1024;      // blocks of fused_cast_hist doing the cast

// ---------------- bf16 helpers ----------------

__device__ __forceinline__ ushort f2bf(float f) {  // round-to-nearest-even
    uint u = __float_as_uint(f);
    u += 0x7FFFu + ((u >> 16) & 1u);
    return (ushort)(u >> 16);
}
__device__ __forceinline__ float bfl(uint u) { return __uint_as_float(u << 16); }
__device__ __forceinline__ float bfh(uint u) { return __uint_as_float(u & 0xFFFF0000u); }

// ---------------- fused CSR build (3 relations in one pass each) ----------------

struct RelSrc {
    const int* rowsA; const int* colsA; const float* valsA; int neA; int offA;
    const int* rowsB; const int* colsB; const float* valsB; int neB; int offB;
    int shift; int n_out;
};

struct BuildParams {
    RelSrc rel[3];          // 0=users, 1=items, 2=cats
    int* bcnt;              // 3*256
    int* boffs;             // 3*257
    int* cursor;            // 3*256
    int2* bucketed[3];
    int* ptr[3];
    int2* edges[3];
};

// blocks [0,CAST_BLKS): cast embeddings -> unified bf16 table
// blocks [CAST_BLKS, CAST_BLKS+3*256): 256-bin bucket histogram per relation
__global__ __launch_bounds__(256) void fused_cast_hist(BuildParams P,
                                                       const float* __restrict__ ue,
                                                       const float* __restrict__ ie,
                                                       const float* __restrict__ ce,
                                                       ushort* __restrict__ H) {
    int bid = blockIdx.x;
    if (bid < CAST_BLKS) {
        constexpr int NI8 = (N_ITEMS * DIM) / 8;
        constexpr int NU8 = (N_USERS * DIM) / 8;
        constexpr int NC8 = (N_CATS  * DIM) / 8;
        constexpr int TOT8 = NI8 + NU8 + NC8;
        int st = CAST_BLKS * 256;
        for (int i = bid * 256 + threadIdx.x; i < TOT8; i += st) {
            const float* src; int s8;
            if (i < NI8)            { src = ie; s8 = i; }
            else if (i < NI8 + NU8) { src = ue; s8 = i - NI8; }
            else                    { src = ce; s8 = i - NI8 - NU8; }
            float4 a = reinterpret_cast<const float4*>(src)[2 * s8];
            float4 b = reinterpret_cast<const float4*>(src)[2 * s8 + 1];
            uint4 v;
            v.x = (uint)f2bf(a.x) | ((uint)f2bf(a.y) << 16);
            v.y = (uint)f2bf(a.z) | ((uint)f2bf(a.w) << 16);
            v.z = (uint)f2bf(b.x) | ((uint)f2bf(b.y) << 16);
            v.w = (uint)f2bf(b.z) | ((uint)f2bf(b.w) << 16);
            reinterpret_cast<uint4*>(H)[i] = v;
        }
    } else {
        int b2 = bid - CAST_BLKS;
        int rel = b2 >> 8;
        int lbk = b2 & 255;
        RelSrc R = P.rel[rel];
        __shared__ int lb[256];
        lb[threadIdx.x] = 0;
        __syncthreads();
        int ne = R.neA + R.neB;
        for (int i = lbk * 256 + threadIdx.x; i < ne; i += 256 * 256) {
            int r = (i < R.neA) ? R.rowsA[i] : R.rowsB[i - R.neA];
            atomicAdd(&lb[r >> R.shift], 1);
        }
        __syncthreads();
        if (lb[threadIdx.x]) atomicAdd(&P.bcnt[rel * 256 + threadIdx.x], lb[threadIdx.x]);
    }
}

__global__ void fused_scan(const int* __restrict__ bcnt, int* __restrict__ boffs,
                           int* __restrict__ cursor) {
    __shared__ int lds[256];
    int rel = blockIdx.x, tid = threadIdx.x;
    int v = bcnt[rel * 256 + tid];
    lds[tid] = v;
    __syncthreads();
    for (int off = 1; off < 256; off <<= 1) {
        int t = (tid >= off) ? lds[tid - off] : 0;
        __syncthreads();
        lds[tid] += t;
        __syncthreads();
    }
    int excl = lds[tid] - v;
    boffs[rel * 257 + tid] = excl;
    cursor[rel * 256 + tid] = excl;
    if (tid == 255) boffs[rel * 257 + 256] = lds[255];
}

// Level 1: LDS-staged multisplit into <=256 coarse buckets per relation.
// 1024 threads x 76KB LDS: 2 blocks/CU x 16 waves = 32 waves/CU (round-10 lesson).
__global__ __launch_bounds__(1024) void fused_scatter(BuildParams P, int c0, int c01) {
    __shared__ int2 stage[CHUNK];
    __shared__ unsigned char sb[CHUNK];
    __shared__ int hist[256], lbase[256], gbase[256], cnt[256];
    int bid = blockIdx.x, tid = threadIdx.x;
    int rel = (bid < c0) ? 0 : ((bid < c01) ? 1 : 2);
    int ch  = bid - ((rel == 0) ? 0 : ((rel == 1) ? c0 : c01));
    RelSrc R = P.rel[rel];
    int ne = R.neA + R.neB;
    int base = ch * CHUNK;
    int nedge = min(CHUNK, ne - base);
    int* cursor = P.cursor + rel * 256;
    int2* out = P.bucketed[rel];

    if (tid < 256) hist[tid] = 0;
    __syncthreads();
    for (int k = tid; k < nedge; k += 1024) {
        int gi = base + k;
        int r = (gi < R.neA) ? R.rowsA[gi] : R.rowsB[gi - R.neA];
        atomicAdd(&hist[r >> R.shift], 1);
    }
    __syncthreads();
    if (tid < 256) lbase[tid] = hist[tid];
    __syncthreads();
    for (int off = 1; off < 256; off <<= 1) {
        int t = (tid < 256 && tid >= off) ? lbase[tid - off] : 0;
        __syncthreads();
        if (tid < 256) lbase[tid] += t;
        __syncthreads();
    }
    if (tid < 256) {
        int excl = lbase[tid] - hist[tid];
        cnt[tid] = excl;
        gbase[tid] = hist[tid] ? atomicAdd(&cursor[tid], hist[tid]) : 0;
        lbase[tid] = excl;  // own-slot rewrite, safe
    }
    __syncthreads();
    for (int k = tid; k < nedge; k += 1024) {
        int gi = base + k;
        int r, c; float v;
        if (gi < R.neA) { r = R.rowsA[gi]; c = R.colsA[gi] + R.offA; v = R.valsA[gi]; }
        else { int q = gi - R.neA; r = R.rowsB[q]; c = R.colsB[q] + R.offB; v = R.valsB[q]; }
        int b = r >> R.shift;
        int slot = atomicAdd(&cnt[b], 1);
        int lr = r - (b << R.shift);
        stage[slot] = make_int2((lr << COLSHIFT) | c, __float_as_int(v));
        sb[slot] = (unsigned char)b;
    }
    __syncthreads();
    for (int j = tid; j < nedge; j += 1024) {
        int b = sb[j];
        out[gbase[b] + (j - lbase[b])] = stage[j];
    }
}

// Level 2: one block per bucket; hist + scan + ptr write + scatter, all L2-local.
// Final edges store .x = col * 128 (byte offset into bf16 H row).
__global__ __launch_bounds__(256) void fused_finalize(BuildParams P, int nb0, int nb01,
                                                      int nbu, int nbi, int nbc) {
    __shared__ int h[512], psum[256], cur[512];
    int bg = blockIdx.x, tid = threadIdx.x;
    int rel = (bg < nb0) ? 0 : ((bg < nb01) ? 1 : 2);
    int lb  = bg - ((rel == 0) ? 0 : ((rel == 1) ? nb0 : nb01));
    int nb  = (rel == 0) ? nbu : ((rel == 1) ? nbi : nbc);
    RelSrc R = P.rel[rel];
    const int* boffs = P.boffs + rel * 257;
    const int2* bucketed = P.bucketed[rel];
    int* ptr = P.ptr[rel];
    int2* edges = P.edges[rel];

    int s = boffs[lb], e = boffs[lb + 1];
    int base_row = lb << R.shift;
    int nrows_b = min(1 << R.shift, R.n_out - base_row);
    h[tid] = 0; h[tid + 256] = 0;
    __syncthreads();
    for (int j = s + tid; j < e; j += 256)
        atomicAdd(&h[(unsigned)bucketed[j].x >> COLSHIFT], 1);
    __syncthreads();
    int a0 = h[2 * tid], a1 = h[2 * tid + 1];
    psum[tid] = a0 + a1;
    __syncthreads();
    for (int off = 1; off < 256; off <<= 1) {
        int t = (tid >= off) ? psum[tid - off] : 0;
        __syncthreads();
        psum[tid] += t;
        __syncthreads();
    }
    int pex = (tid == 0) ? 0 : psum[tid - 1];
    cur[2 * tid] = pex;
    cur[2 * tid + 1] = pex + a0;
    if (2 * tid < nrows_b)     ptr[base_row + 2 * tid]     = s + pex;
    if (2 * tid + 1 < nrows_b) ptr[base_row + 2 * tid + 1] = s + pex + a0;
    if (lb == nb - 1 && tid == 0) ptr[R.n_out] = boffs[nb];
    __syncthreads();
    for (int j = s + tid; j < e; j += 256) {
        int2 w = bucketed[j];
        int lr = (unsigned)w.x >> COLSHIFT;
        int slot = atomicAdd(&cur[lr], 1);
        edges[s + slot] = make_int2((w.x & COLMASK) << 7, w.y);
    }
}

// ---------------- fused layer kernel (all 3 node types, bf16 H) ----------------
// Wave: 8 edge-groups (grp=lane>>3) x 8 lanes (sub=lane&7) x 16B (8 bf16).
// Contiguous per-group ranges (L=ceil(deg/8)): the x4 clamped batch loads 32
// contiguous bytes of edges (2x dwordx4); all 4 H-gathers in flight at once.
// No running sums: layers 0/1 write only bf16 Hnxt; last layer assembles
// out = (emb + h1 + h2 + acc) * 0.25 from the retained H buffers.

__device__ __forceinline__ void fma8(uint4 hv, float w, float* acc) {
    acc[0] = fmaf(w, bfl(hv.x), acc[0]);
    acc[1] = fmaf(w, bfh(hv.x), acc[1]);
    acc[2] = fmaf(w, bfl(hv.y), acc[2]);
    acc[3] = fmaf(w, bfh(hv.y), acc[3]);
    acc[4] = fmaf(w, bfl(hv.z), acc[4]);
    acc[5] = fmaf(w, bfh(hv.z), acc[5]);
    acc[6] = fmaf(w, bfl(hv.w), acc[6]);
    acc[7] = fmaf(w, bfh(hv.w), acc[7]);
}

__device__ __forceinline__ void gather8(const int* __restrict__ ptr,
                                        const int2* __restrict__ edges,
                                        const ushort* __restrict__ H,
                                        int r, int grp, int sub, float* acc) {
    int s = ptr[r], e = ptr[r + 1];
    int L = (e - s + 7) >> 3;          // edges per group (contiguous range)
    int gs = s + grp * L;
    int ge = min(gs + L, e);
    const char* Hb = (const char*)H + sub * 16;   // edges[].x is a byte offset
    for (int j0 = gs; j0 < ge; j0 += 4) {
        int j1 = j0 + 1, j2 = j0 + 2, j3 = j0 + 3;
        int2 e0 = edges[j0];
        int2 e1 = edges[j1 < ge ? j1 : j0];
        int2 e2 = edges[j2 < ge ? j2 : j0];
        int2 e3 = edges[j3 < ge ? j3 : j0];
        uint4 h0 = *reinterpret_cast<const uint4*>(Hb + e0.x);
        uint4 h1 = *reinterpret_cast<const uint4*>(Hb + e1.x);
        uint4 h2 = *reinterpret_cast<const uint4*>(Hb + e2.x);
        uint4 h3 = *reinterpret_cast<const uint4*>(Hb + e3.x);
        float w1 = (j1 < ge) ? __int_as_float(e1.y) : 0.f;
        float w2 = (j2 < ge) ? __int_as_float(e2.y) : 0.f;
        float w3 = (j3 < ge) ? __int_as_float(e3.y) : 0.f;
        fma8(h0, __int_as_float(e0.y), acc);
        fma8(h1, w1, acc);
        fma8(h2, w2, acc);
        fma8(h3, w3, acc);
    }
}

__device__ __forceinline__ void xreduce8(float* a) {
#pragma unroll
    for (int m = 8; m <= 32; m <<= 1)
#pragma unroll
        for (int k = 0; k < 8; ++k)
            a[k] += __shfl_xor(a[k], m);
}

__device__ __forceinline__ uint4 pack_bf8(const float* a) {
    uint4 v;
    v.x = (uint)f2bf(a[0]) | ((uint)f2bf(a[1]) << 16);
    v.y = (uint)f2bf(a[2]) | ((uint)f2bf(a[3]) << 16);
    v.z = (uint)f2bf(a[4]) | ((uint)f2bf(a[5]) << 16);
    v.w = (uint)f2bf(a[6]) | ((uint)f2bf(a[7]) << 16);
    return v;
}

__global__ void fused_layer(const int* __restrict__ u_ptr, const int2* __restrict__ u_e,
                            const int* __restrict__ i_ptr, const int2* __restrict__ i_e,
                            const int* __restrict__ c_ptr, const int2* __restrict__ c_e,
                            const ushort* __restrict__ Hcur, ushort* __restrict__ Hnxt,
                            const ushort* __restrict__ H1, const ushort* __restrict__ H2,
                            float* __restrict__ sum_u, float* __restrict__ sum_i,
                            float* __restrict__ out_c,
                            const float* __restrict__ user_emb, const float* __restrict__ item_emb,
                            float scale, int last) {
    int wid  = (blockIdx.x * blockDim.x + threadIdx.x) >> 6;  // global row
    int lane = threadIdx.x & 63;
    if (wid >= TOT_ROWS) return;
    int grp = lane >> 3, sub = lane & 7;
    float acc[8] = {0.f, 0.f, 0.f, 0.f, 0.f, 0.f, 0.f, 0.f};
    const int* ptr; const int2* eg; int lr;
    if (wid < ROW_U0)      { ptr = i_ptr; eg = i_e; lr = wid; }            // items
    else if (wid < ROW_C0) { ptr = u_ptr; eg = u_e; lr = wid - ROW_U0; }   // users
    else                   { ptr = c_ptr; eg = c_e; lr = wid - ROW_C0; }   // cats
    gather8(ptr, eg, Hcur, lr, grp, sub, acc);
    xreduce8(acc);  // all lanes hold final acc for their 8 dims
    if (grp != 0) return;
    size_t o = (size_t)wid * DIM + sub * 8;
    if (!last) {
        *reinterpret_cast<uint4*>(Hnxt + o) = pack_bf8(acc);
    } else if (wid < ROW_C0) {
        const float* emb; float* dst; size_t so;
        if (wid < ROW_U0) { emb = item_emb; dst = sum_i; so = o; }
        else { emb = user_emb; dst = sum_u; so = (size_t)lr * DIM + sub * 8; }
        uint4 a1 = *reinterpret_cast<const uint4*>(H1 + o);
        uint4 a2 = *reinterpret_cast<const uint4*>(H2 + o);
        const float4* ep = reinterpret_cast<const float4*>(emb + so);
        float4 b0 = ep[0], b1 = ep[1];
        float4 r0, r1;
        r0.x = (b0.x + bfl(a1.x) + bfl(a2.x) + acc[0]) * scale;
        r0.y = (b0.y + bfh(a1.x) + bfh(a2.x) + acc[1]) * scale;
        r0.z = (b0.z + bfl(a1.y) + bfl(a2.y) + acc[2]) * scale;
        r0.w = (b0.w + bfh(a1.y) + bfh(a2.y) + acc[3]) * scale;
        r1.x = (b1.x + bfl(a1.z) + bfl(a2.z) + acc[4]) * scale;
        r1.y = (b1.y + bfh(a1.z) + bfh(a2.z) + acc[5]) * scale;
        r1.z = (b1.z + bfl(a1.w) + bfl(a2.w) + acc[6]) * scale;
        r1.w = (b1.w + bfh(a1.w) + bfh(a2.w) + acc[7]) * scale;
        float4* dp = reinterpret_cast<float4*>(dst + so);
        dp[0] = r0; dp[1] = r1;
    } else {
        float4* op = reinterpret_cast<float4*>(out_c + (size_t)lr * DIM + sub * 8);
        op[0] = make_float4(acc[0], acc[1], acc[2], acc[3]);
        op[1] = make_float4(acc[4], acc[5], acc[6], acc[7]);
    }
}

// ---------------- fallback (push-atomic fp32 path) ----------------

__global__ void spmm_edges(const int* __restrict__ rows, const int* __restrict__ cols,
                           const float* __restrict__ vals, const float* __restrict__ H,
                           float* __restrict__ out, int ne) {
    int tid  = blockIdx.x * blockDim.x + threadIdx.x;
    int e    = tid >> 6;
    int lane = threadIdx.x & 63;
    if (e >= ne) return;
    float x = vals[e] * H[(size_t)cols[e] * DIM + lane];
    unsafeAtomicAdd(&out[(size_t)rows[e] * DIM + lane], x);
}

__global__ void accum_kernel(float* __restrict__ sum, const float* __restrict__ h, int n) {
    int i = blockIdx.x * blockDim.x + threadIdx.x;
    int st = gridDim.x * blockDim.x;
    for (; i < n; i += st) sum[i] += h[i];
}

__global__ void scale_kernel(float* __restrict__ p, int n, float s) {
    int i = blockIdx.x * blockDim.x + threadIdx.x;
    int st = gridDim.x * blockDim.x;
    for (; i < n; i += st) p[i] *= s;
}

// ---------------- host ----------------

extern "C" void kernel_launch(void* const* d_in, const int* in_sizes, int n_in,
                              void* d_out, int out_size, void* d_ws, size_t ws_size,
                              hipStream_t stream) {
    const float* user_emb = (const float*)d_in[0];
    const float* item_emb = (const float*)d_in[1];
    const float* cat_emb  = (const float*)d_in[2];
    const float* ui_vals  = (const float*)d_in[3];
    const float* iu_vals  = (const float*)d_in[4];
    const float* uu_vals  = (const float*)d_in[5];
    const float* ic_vals  = (const float*)d_in[6];
    const float* ci_vals  = (const float*)d_in[7];
    const int*   ui_rows  = (const int*)d_in[8];
    const int*   ui_cols  = (const int*)d_in[9];
    const int*   iu_rows  = (const int*)d_in[10];
    const int*   iu_cols  = (const int*)d_in[11];
    const int*   uu_rows  = (const int*)d_in[12];
    const int*   uu_cols  = (const int*)d_in[13];
    const int*   ic_rows  = (const int*)d_in[14];
    const int*   ic_cols  = (const int*)d_in[15];
    const int*   ci_rows  = (const int*)d_in[16];
    const int*   ci_cols  = (const int*)d_in[17];

    constexpr size_t NU = (size_t)N_USERS * DIM;
    constexpr size_t NI = (size_t)N_ITEMS * DIM;
    constexpr size_t NC = (size_t)N_CATS  * DIM;

    float* sum_u = (float*)d_out;
    float* sum_i = sum_u + NU;
    float* out_c = sum_i + NI;

    const int blk = 256;
    const float inv = 1.0f / (N_LAYERS + 1);

    // ---- workspace bump allocator (bytes, 16B-aligned) ----
    unsigned char* wb = (unsigned char*)d_ws;
    size_t woff = 0;
    auto take = [&](size_t bytes) -> void* {
        void* p = wb + woff;
        woff = (woff + bytes + 15) & ~(size_t)15;
        return p;
    };
    ushort* Hbuf[3] = { (ushort*)take(TOT_EL * 2), (ushort*)take(TOT_EL * 2),
                        (ushort*)take(TOT_EL * 2) };
    int* u_ptr = (int*)take(((size_t)N_USERS + 1) * 4);
    int* i_ptr = (int*)take(((size_t)N_ITEMS + 1) * 4);
    int* c_ptr = (int*)take(((size_t)N_CATS  + 1) * 4);
    int2* u_e = (int2*)take((size_t)NE_USERS * 8);
    int2* i_e = (int2*)take((size_t)NE_ITEMS * 8);
    int2* c_e = (int2*)take((size_t)NE_CATS  * 8);
    int* bcnt   = (int*)take(3 * 256 * 4);
    int* boffs  = (int*)take(3 * 257 * 4);
    int* cursor = (int*)take(3 * 256 * 4);
    size_t needed_bytes = woff;  // ~101 MB
    // bucketed scratch overlays: items -> Hbuf[1] (17.2 < 19.3 MB, dead until
    // layer 0 writes it), cats -> Hbuf[2], users -> d_out (24 < 38.6 MB, every
    // element overwritten by the last layer).
    int2* bk_u = (int2*)d_out;
    int2* bk_i = (int2*)Hbuf[1];
    int2* bk_c = (int2*)Hbuf[2];

    if (ws_size >= needed_bytes) {
        BuildParams P;
        P.rel[0] = { ui_rows, ui_cols, ui_vals, NE_UI, 0,
                     uu_rows, uu_cols, uu_vals, NE_UU, ROW_U0, SH_U, N_USERS };
        P.rel[1] = { iu_rows, iu_cols, iu_vals, NE_UI, ROW_U0,
                     ic_rows, ic_cols, ic_vals, NE_IC, ROW_C0, SH_I, N_ITEMS };
        P.rel[2] = { ci_rows, ci_cols, ci_vals, NE_IC, 0,
                     nullptr, nullptr, nullptr, 0, 0, SH_C, N_CATS };
        P.bcnt = bcnt; P.boffs = boffs; P.cursor = cursor;
        P.bucketed[0] = bk_u; P.bucketed[1] = bk_i; P.bucketed[2] = bk_c;
        P.ptr[0] = u_ptr; P.ptr[1] = i_ptr; P.ptr[2] = c_ptr;
        P.edges[0] = u_e; P.edges[1] = i_e; P.edges[2] = c_e;

        hipMemsetAsync(bcnt, 0, 3 * 256 * sizeof(int), stream);
        fused_cast_hist<<<CAST_BLKS + 3 * 256, blk, 0, stream>>>(P, user_emb, item_emb,
                                                                 cat_emb, Hbuf[0]);
        fused_scan<<<3, blk, 0, stream>>>(bcnt, boffs, cursor);
        fused_scatter<<<CH_U + CH_I + CH_C, 1024, 0, stream>>>(P, CH_U, CH_U + CH_I);
        fused_finalize<<<NB_U + NB_I + NB_C, blk, 0, stream>>>(P, NB_U, NB_U + NB_I,
                                                               NB_U, NB_I, NB_C);

        int grid = (TOT_ROWS * 64 + blk - 1) / blk;  // 4 rows (waves) per block
        for (int l = 0; l < N_LAYERS; ++l) {
            fused_layer<<<grid, blk, 0, stream>>>(u_ptr, u_e, i_ptr, i_e, c_ptr, c_e,
                                                  Hbuf[l], Hbuf[l + 1 < 3 ? l + 1 : 0],
                                                  Hbuf[1], Hbuf[2],
                                                  sum_u, sum_i, out_c,
                                                  user_emb, item_emb,
                                                  inv, l == N_LAYERS - 1);
        }
    } else {
        // ---- fallback: push-atomic fp32 path (own layout at front of ws) ----
        float* ws = (float*)d_ws;
        float* f_u[2] = { ws,               ws + NU };
        float* f_i[2] = { ws + 2 * NU,      ws + 2 * NU + NI };
        float* f_c[2] = { ws + 2 * NU + 2 * NI, ws + 2 * NU + 2 * NI + NC };
        hipMemcpyAsync(f_u[0], user_emb, NU * sizeof(float), hipMemcpyDeviceToDevice, stream);
        hipMemcpyAsync(f_i[0], item_emb, NI * sizeof(float), hipMemcpyDeviceToDevice, stream);
        hipMemcpyAsync(f_c[0], cat_emb,  NC * sizeof(float), hipMemcpyDeviceToDevice, stream);
        hipMemcpyAsync(sum_u,  user_emb, NU * sizeof(float), hipMemcpyDeviceToDevice, stream);
        hipMemcpyAsync(sum_i,  item_emb, NI * sizeof(float), hipMemcpyDeviceToDevice, stream);
        const int ew_grid = 2048;
        int cur = 0;
        for (int l = 0; l < N_LAYERS; ++l) {
            int nxt = cur ^ 1;
            hipMemsetAsync(f_u[nxt], 0, NU * sizeof(float), stream);
            hipMemsetAsync(f_i[nxt], 0, NI * sizeof(float), stream);
            hipMemsetAsync(f_c[nxt], 0, NC * sizeof(float), stream);
            spmm_edges<<<(NE_UI + 3) / 4, blk, 0, stream>>>(ui_rows, ui_cols, ui_vals, f_i[cur], f_u[nxt], NE_UI);
            spmm_edges<<<(NE_UU + 3) / 4, blk, 0, stream>>>(uu_rows, uu_cols, uu_vals, f_u[cur], f_u[nxt], NE_UU);
            spmm_edges<<<(NE_UI + 3) / 4, blk, 0, stream>>>(iu_rows, iu_cols, iu_vals, f_u[cur], f_i[nxt], NE_UI);
            spmm_edges<<<(NE_IC + 3) / 4, blk, 0, stream>>>(ic_rows, ic_cols, ic_vals, f_c[cur], f_i[nxt], NE_IC);
            spmm_edges<<<(NE_IC + 3) / 4, blk, 0, stream>>>(ci_rows, ci_cols, ci_vals, f_i[cur], f_c[nxt], NE_IC);
            accum_kernel<<<ew_grid, blk, 0, stream>>>(sum_u, f_u[nxt], (int)NU);
            accum_kernel<<<ew_grid, blk, 0, stream>>>(sum_i, f_i[nxt], (int)NI);
            cur = nxt;
        }
        scale_kernel<<<ew_grid, blk, 0, stream>>>(sum_u, (int)NU, inv);
        scale_kernel<<<ew_grid, blk, 0, stream>>>(sum_i, (int)NI, inv);
        hipMemcpyAsync(out_c, f_c[cur], NC * sizeof(float), hipMemcpyDeviceToDevice, stream);
    }
}